// Round 10
// baseline (1910.485 us; speedup 1.0000x reference)
//
#include <hip/hip_runtime.h>
#include <math.h>

#define BB 8
#define NN 2048
#define KNB 20

typedef __attribute__((ext_vector_type(8))) short bf16x8;
typedef __attribute__((ext_vector_type(4))) float f32x4;

__device__ inline unsigned short f2bf(float f) {
  union { float f; unsigned u; } v; v.f = f;
  unsigned r = v.u + 0x7FFF + ((v.u >> 16) & 1);  // RNE
  return (unsigned short)(r >> 16);
}

// ---------------------------------------------------------------- sq
__global__ __launch_bounds__(256) void sq_kernel(const float* __restrict__ x, int bs, int C,
                                                 float* __restrict__ sq) {
  int t = blockIdx.x * blockDim.x + threadIdx.x;
  int b = t / NN, n = t % NN;
  const float* xp = x + (size_t)b * bs + n;
  float s = 0.f;
  for (int c = 0; c < C; ++c) { float v = xp[c * NN]; s += v * v; }
  sq[t] = s;
}

// ---------------------------------------------------------------- M = wk^T wq
__global__ __launch_bounds__(256) void mprep_kernel(const float* __restrict__ wq,
                                                    const float* __restrict__ wk, int C,
                                                    float* __restrict__ M) {
  int T = blockIdx.x * 256 + threadIdx.x;
  if (T >= C * C) return;
  int c = T / C, cp = T % C;
  float a = 0.f;
  for (int e = 0; e < C; ++e) a += wk[e * C + c] * wq[e * C + cp];
  M[c * C + cp] = a;
}

// ---------------------------------------------------------------- wcv = wc @ wv
__global__ __launch_bounds__(256) void wcv_kernel(const float* __restrict__ wc,
                                                  const float* __restrict__ wv, int C,
                                                  float* __restrict__ out) {
  int T = blockIdx.x * 256 + threadIdx.x;
  if (T >= C * C) return;
  int o = T / C, c = T % C;
  float a = 0.f;
  for (int e = 0; e < C; ++e) a += wc[o * C + e] * wv[e * C + c];
  out[o * C + c] = a;
}

// ---------------------------------------------------------------- converts
__global__ __launch_bounds__(256) void convert_bf16_kernel(const float* __restrict__ in,
                                                           unsigned short* __restrict__ out,
                                                           int count) {
  int i = blockIdx.x * 256 + threadIdx.x;
  if (i < count) out[i] = f2bf(in[i]);
}

// ---------------------------------------------------------------- transpose (fp32)
__global__ __launch_bounds__(256) void transpose_kernel(const float* __restrict__ in, int inBS,
                                                        int R, int Cl, float* __restrict__ out) {
  __shared__ float tile[32][33];
  int b = blockIdx.z;
  const float* ip = in + (size_t)b * inBS;
  float* op = out + (size_t)b * R * Cl;
  int c0 = blockIdx.x * 32, r0 = blockIdx.y * 32;
  int tx = threadIdx.x & 31, ty = threadIdx.x >> 5;
  for (int yy = ty; yy < 32; yy += 8) {
    int r = r0 + yy, c = c0 + tx;
    tile[yy][tx] = (r < R && c < Cl) ? ip[(size_t)r * Cl + c] : 0.f;
  }
  __syncthreads();
  for (int yy = ty; yy < 32; yy += 8) {
    int c = c0 + yy, r = r0 + tx;
    if (c < Cl && r < R) op[(size_t)c * R + r] = tile[tx][yy];
  }
}

// ---------------------------------------------------------------- transpose + bf16 convert
__global__ __launch_bounds__(256) void transpose_bf16_kernel(const float* __restrict__ in, int inBS,
                                                             int R, int Cl,
                                                             unsigned short* __restrict__ out) {
  __shared__ float tile[32][33];
  int b = blockIdx.z;
  const float* ip = in + (size_t)b * inBS;
  unsigned short* op = out + (size_t)b * R * Cl;
  int c0 = blockIdx.x * 32, r0 = blockIdx.y * 32;
  int tx = threadIdx.x & 31, ty = threadIdx.x >> 5;
  for (int yy = ty; yy < 32; yy += 8) {
    int r = r0 + yy, c = c0 + tx;
    tile[yy][tx] = (r < R && c < Cl) ? ip[(size_t)r * Cl + c] : 0.f;
  }
  __syncthreads();
  for (int yy = ty; yy < 32; yy += 8) {
    int c = c0 + yy, r = r0 + tx;
    if (c < Cl && r < R) op[(size_t)c * R + r] = f2bf(tile[tx][yy]);
  }
}

// ---------------------------------------------------------------- MFMA GEMM, LDS double-buffered
// Z[b][o][n] = sum_k A[o][k] * B[b][n][k]; A,B bf16 K-contiguous, Z fp32.
__global__ __launch_bounds__(256, 2) void mfma_gemm_lds_kernel(
    const unsigned short* __restrict__ A, const unsigned short* __restrict__ B,
    float* __restrict__ Z, int O, int K) {
  const int b = blockIdx.z;
  const int n0 = blockIdx.x * 128, o0 = blockIdx.y * 128;
  const int tid = threadIdx.x;
  const int wave = tid >> 6, lane = tid & 63;
  const int wo = wave >> 1, wn = wave & 1;   // 64x64 quadrant per wave
  const int l16 = lane & 15, q = lane >> 4;
  __shared__ unsigned short Al[2][4096];     // 128 rows x 32 k (8 KB), frag order
  __shared__ unsigned short Bl[2][4096];
  const unsigned short* Ab = A + (size_t)o0 * K;
  const unsigned short* Bb = B + ((size_t)b * NN + n0) * K;

  const int p0 = tid, p1 = tid + 256;
  const int r0 = ((p0 >> 6) << 4) | (p0 & 15), c0 = ((p0 >> 4) & 3) * 8;
  const int r1 = ((p1 >> 6) << 4) | (p1 & 15), c1 = ((p1 >> 4) & 3) * 8;

  bf16x8 ar0, ar1, br0, br1;
  auto gload = [&](int k0) {
    ar0 = *(const bf16x8*)(Ab + (size_t)r0 * K + k0 + c0);
    ar1 = *(const bf16x8*)(Ab + (size_t)r1 * K + k0 + c1);
    br0 = *(const bf16x8*)(Bb + (size_t)r0 * K + k0 + c0);
    br1 = *(const bf16x8*)(Bb + (size_t)r1 * K + k0 + c1);
  };
  auto sstore = [&](int buf) {
    *(bf16x8*)&Al[buf][p0 * 8] = ar0;
    *(bf16x8*)&Al[buf][p1 * 8] = ar1;
    *(bf16x8*)&Bl[buf][p0 * 8] = br0;
    *(bf16x8*)&Bl[buf][p1 * 8] = br1;
  };

  f32x4 acc[4][4];
#pragma unroll
  for (int s = 0; s < 4; ++s)
#pragma unroll
    for (int t = 0; t < 4; ++t) acc[s][t] = (f32x4){0.f, 0.f, 0.f, 0.f};

  gload(0);
  sstore(0);
  int cur = 0;
  for (int k0 = 0; k0 < K; k0 += 32) {
    bool more = (k0 + 32) < K;
    if (more) gload(k0 + 32);
    __syncthreads();
    bf16x8 af[4], bfr[4];
#pragma unroll
    for (int s = 0; s < 4; ++s)
      af[s] = *(const bf16x8*)&Al[cur][((wo * 4 + s) * 64 + q * 16 + l16) * 8];
#pragma unroll
    for (int t = 0; t < 4; ++t)
      bfr[t] = *(const bf16x8*)&Bl[cur][((wn * 4 + t) * 64 + q * 16 + l16) * 8];
#pragma unroll
    for (int s = 0; s < 4; ++s)
#pragma unroll
      for (int t = 0; t < 4; ++t)
        acc[s][t] = __builtin_amdgcn_mfma_f32_16x16x32_bf16(af[s], bfr[t], acc[s][t], 0, 0, 0);
    if (more) sstore(cur ^ 1);
    cur ^= 1;
  }
#pragma unroll
  for (int s = 0; s < 4; ++s)
#pragma unroll
    for (int t = 0; t < 4; ++t) {
      float* zp = Z + ((size_t)b * O + o0 + wo * 64 + s * 16 + q * 4) * NN
                  + n0 + wn * 64 + t * 16 + l16;
#pragma unroll
      for (int r = 0; r < 4; ++r) zp[(size_t)r * NN] = acc[s][t][r];
    }
}

// ---------------------------------------------------------------- symmetric pd GEMM
// P[bl][n][m] = 2*dot(x_n,x_m) - sq[m]. Gram matrix is symmetric: compute only
// the 136 upper-triangle 128x128 tiles, mirror (i!=j) via LDS-staged coalesced
// writes (mirror value uses -sq[n]). Same fp32 arithmetic as before -> no
// precision change to kNN. blockIdx.x = triangle tile, blockIdx.y = batch.
__global__ __launch_bounds__(256, 2) void pd_sym_kernel(
    const float* __restrict__ x, int bs, int C, const float* __restrict__ sq,
    float* __restrict__ P, int b_base) {
  int tt = blockIdx.x, ti = 0;
  while (tt >= 16 - ti) { tt -= 16 - ti; ++ti; }
  const int tj = ti + tt;
  const int b = b_base + blockIdx.y;
  const int n0 = ti * 128, m0 = tj * 128;
  const int tid = threadIdx.x;
  const int tm = tid & 15, tn = tid >> 4;
  __shared__ float As[2][16][128], Bs[2][16][128];
  __shared__ float Lt[32][133];
  const float* xb = x + (size_t)b * bs;
  float acc[8][8];
#pragma unroll
  for (int i = 0; i < 8; ++i)
#pragma unroll
    for (int j = 0; j < 8; ++j) acc[i][j] = 0.f;

  float4 ara[2], arb[2];
  auto load_tile = [&](int k0) {
#pragma unroll
    for (int it = 0; it < 2; ++it) {
      int i = it * 256 + tid;
      int kc = i >> 5, c4 = i & 31;
      bool ok = (k0 + kc) < C;
      ara[it] = ok ? *(const float4*)&xb[(size_t)(k0 + kc) * NN + n0 + c4 * 4]
                   : make_float4(0.f, 0.f, 0.f, 0.f);
      arb[it] = ok ? *(const float4*)&xb[(size_t)(k0 + kc) * NN + m0 + c4 * 4]
                   : make_float4(0.f, 0.f, 0.f, 0.f);
    }
  };
  auto store_tile = [&](int buf) {
#pragma unroll
    for (int it = 0; it < 2; ++it) {
      int i = it * 256 + tid;
      int kc = i >> 5, c4 = i & 31;
      *(float4*)&As[buf][kc][c4 * 4] = ara[it];
      *(float4*)&Bs[buf][kc][c4 * 4] = arb[it];
    }
  };

  load_tile(0);
  store_tile(0);
  int cur = 0;
  for (int k0 = 0; k0 < C; k0 += 16) {
    bool more = (k0 + 16) < C;
    if (more) load_tile(k0 + 16);
    __syncthreads();
#pragma unroll
    for (int kc = 0; kc < 16; ++kc) {
      float4 a0 = *(const float4*)&As[cur][kc][tn * 4];
      float4 a1 = *(const float4*)&As[cur][kc][64 + tn * 4];
      float4 b0 = *(const float4*)&Bs[cur][kc][tm * 4];
      float4 b1 = *(const float4*)&Bs[cur][kc][64 + tm * 4];
      float ar[8] = {a0.x, a0.y, a0.z, a0.w, a1.x, a1.y, a1.z, a1.w};
      float br[8] = {b0.x, b0.y, b0.z, b0.w, b1.x, b1.y, b1.z, b1.w};
#pragma unroll
      for (int i = 0; i < 8; ++i)
#pragma unroll
        for (int j = 0; j < 8; ++j) acc[i][j] += ar[i] * br[j];
    }
    if (more) store_tile(cur ^ 1);
    cur ^= 1;
  }

  // direct tile: rows n (from n0), cols m (from m0), minus sq[m]
  float4 sqa = *(const float4*)&sq[b * NN + m0 + tm * 4];
  float4 sqb = *(const float4*)&sq[b * NN + m0 + 64 + tm * 4];
#pragma unroll
  for (int h = 0; h < 2; ++h)
#pragma unroll
    for (int i = 0; i < 4; ++i) {
      int r = h * 4 + i;
      int nn = n0 + h * 64 + tn * 4 + i;
      float* prow = &P[((size_t)blockIdx.y * NN + nn) * NN + m0];
      float4 o0, o1;
      o0.x = 2.f * acc[r][0] - sqa.x; o0.y = 2.f * acc[r][1] - sqa.y;
      o0.z = 2.f * acc[r][2] - sqa.z; o0.w = 2.f * acc[r][3] - sqa.w;
      o1.x = 2.f * acc[r][4] - sqb.x; o1.y = 2.f * acc[r][5] - sqb.y;
      o1.z = 2.f * acc[r][6] - sqb.z; o1.w = 2.f * acc[r][7] - sqb.w;
      *(float4*)&prow[tm * 4] = o0;
      *(float4*)&prow[64 + tm * 4] = o1;
    }

  if (ti == tj) return;

  // mirror tile: rows m (from m0), cols n (from n0), minus sq[n].
  // 4 chunks of 32 m-rows staged in LDS for coalesced global writes.
#pragma unroll
  for (int jh = 0; jh < 2; ++jh)
    for (int tphi = 0; tphi < 2; ++tphi) {
      if ((tm >> 3) == tphi) {
#pragma unroll
        for (int jq = 0; jq < 4; ++jq) {
          int mloc = (tm & 7) * 4 + jq;
          int j = jh * 4 + jq;
#pragma unroll
          for (int h = 0; h < 2; ++h) {
            float4 w;
            w.x = acc[h * 4 + 0][j]; w.y = acc[h * 4 + 1][j];
            w.z = acc[h * 4 + 2][j]; w.w = acc[h * 4 + 3][j];
            *(float4*)&Lt[mloc][h * 64 + tn * 4] = w;
          }
        }
      }
      __syncthreads();
      int rr = tid >> 3, cc = (tid & 7) * 16;
      int gm = m0 + jh * 64 + tphi * 32 + rr;
      float* prow = &P[((size_t)blockIdx.y * NN + gm) * NN + n0];
#pragma unroll
      for (int u = 0; u < 4; ++u) {
        float4 dv = *(float4*)&Lt[rr][cc + u * 4];
        float4 sv = *(const float4*)&sq[b * NN + n0 + cc + u * 4];
        float4 ov;
        ov.x = 2.f * dv.x - sv.x; ov.y = 2.f * dv.y - sv.y;
        ov.z = 2.f * dv.z - sv.z; ov.w = 2.f * dv.w - sv.w;
        *(float4*)&prow[cc + u * 4] = ov;
      }
      __syncthreads();
    }
}

// ---------------------------------------------------------------- top-20, two rows per wave
// Independent dependency chains of two rows interleave -> fills the shuffle-
// latency bubbles that held the one-row version at 61% VALUBusy.
__global__ __launch_bounds__(64) void topk2_kernel(const float* __restrict__ P,
                                                   int* __restrict__ idx, int b_base) {
  const int n0 = blockIdx.x * 2;
  const int bl = blockIdx.y;
  const int b = b_base + bl;
  const int lane = threadIdx.x;
  const float4* rpA = (const float4*)(P + ((size_t)bl * NN + n0) * NN);
  const float4* rpB = (const float4*)(P + ((size_t)bl * NN + n0 + 1) * NN);
  float va[32], vb[32];
#pragma unroll
  for (int q = 0; q < 8; ++q) {
    float4 a = rpA[q * 64 + lane];
    float4 c = rpB[q * 64 + lane];
    int mb = q * 256 + lane * 4;
    va[q * 4 + 0] = (mb + 0 == n0) ? -INFINITY : a.x;
    va[q * 4 + 1] = (mb + 1 == n0) ? -INFINITY : a.y;
    va[q * 4 + 2] = (mb + 2 == n0) ? -INFINITY : a.z;
    va[q * 4 + 3] = (mb + 3 == n0) ? -INFINITY : a.w;
    vb[q * 4 + 0] = (mb + 0 == n0 + 1) ? -INFINITY : c.x;
    vb[q * 4 + 1] = (mb + 1 == n0 + 1) ? -INFINITY : c.y;
    vb[q * 4 + 2] = (mb + 2 == n0 + 1) ? -INFINITY : c.z;
    vb[q * 4 + 3] = (mb + 3 == n0 + 1) ? -INFINITY : c.w;
  }
  int* opA = idx + (size_t)(b * NN + n0) * KNB;
  int* opB = opA + KNB;
  for (int k = 0; k < KNB; ++k) {
    float bvA = va[0]; int bjA = 0;
    float bvB = vb[0]; int bjB = 0;
#pragma unroll
    for (int j = 1; j < 32; ++j) {
      if (va[j] > bvA) { bvA = va[j]; bjA = j; }
      if (vb[j] > bvB) { bvB = vb[j]; bjB = j; }
    }
    int bmA = (bjA >> 2) * 256 + lane * 4 + (bjA & 3);
    int bmB = (bjB >> 2) * 256 + lane * 4 + (bjB & 3);
#pragma unroll
    for (int s = 32; s > 0; s >>= 1) {
      float ovA = __shfl_down(bvA, s); int omA = __shfl_down(bmA, s);
      float ovB = __shfl_down(bvB, s); int omB = __shfl_down(bmB, s);
      if (ovA > bvA) { bvA = ovA; bmA = omA; }
      if (ovB > bvB) { bvB = ovB; bmB = omB; }
    }
    bmA = __shfl(bmA, 0); bmB = __shfl(bmB, 0);
    if (lane == 0) { opA[k] = bmA; opB[k] = bmB; }
    if (((bmA >> 2) & 63) == lane) {
      int jj = ((bmA >> 8) << 2) | (bmA & 3);
#pragma unroll
      for (int j = 0; j < 32; ++j)
        if (j == jj) va[j] = -INFINITY;
    }
    if (((bmB >> 2) & 63) == lane) {
      int jj = ((bmB >> 8) << 2) | (bmB & 3);
#pragma unroll
      for (int j = 0; j < 32; ++j)
        if (j == jj) vb[j] = -INFINITY;
    }
  }
}

// ---------------------------------------------------------------- conv GEMM 64-tile (small O)
__global__ __launch_bounds__(256, 2) void conv_gemm_kernel(
    const float* __restrict__ in, int inBS, int C, int O,
    const float* __restrict__ w, float* __restrict__ z) {
  const int b = blockIdx.z;
  const int n0 = blockIdx.x * 64, o0 = blockIdx.y * 64;
  const int tid = threadIdx.x;
  const int tm = tid & 15, tn = tid >> 4;
  __shared__ float Ws[16][68];
  __shared__ float Xs[16][64];
  const float* ib = in + (size_t)b * inBS;
  float acc[4][4];
#pragma unroll
  for (int i = 0; i < 4; ++i)
#pragma unroll
    for (int j = 0; j < 4; ++j) acc[i][j] = 0.f;

  for (int k0 = 0; k0 < C; k0 += 16) {
    __syncthreads();
#pragma unroll
    for (int it = 0; it < 4; ++it) {
      int i = it * 256 + tid;
      int kc = i >> 6, nl = i & 63;
      Xs[kc][nl] = ((k0 + kc) < C) ? ib[(size_t)(k0 + kc) * NN + n0 + nl] : 0.f;
      int ol = i >> 4, kc2 = i & 15;
      Ws[kc2][ol] = ((o0 + ol) < O && (k0 + kc2) < C) ? w[(size_t)(o0 + ol) * C + k0 + kc2] : 0.f;
    }
    __syncthreads();
#pragma unroll
    for (int kc = 0; kc < 16; ++kc) {
      float4 a = *(const float4*)&Ws[kc][tn * 4];
      float4 bv = *(const float4*)&Xs[kc][tm * 4];
      acc[0][0] += a.x * bv.x; acc[0][1] += a.x * bv.y; acc[0][2] += a.x * bv.z; acc[0][3] += a.x * bv.w;
      acc[1][0] += a.y * bv.x; acc[1][1] += a.y * bv.y; acc[1][2] += a.y * bv.z; acc[1][3] += a.y * bv.w;
      acc[2][0] += a.z * bv.x; acc[2][1] += a.z * bv.y; acc[2][2] += a.z * bv.z; acc[2][3] += a.z * bv.w;
      acc[3][0] += a.w * bv.x; acc[3][1] += a.w * bv.y; acc[3][2] += a.w * bv.z; acc[3][3] += a.w * bv.w;
    }
  }
#pragma unroll
  for (int i = 0; i < 4; ++i) {
    int o = o0 + tn * 4 + i;
    if (o < O) {
      float4 ov;
      ov.x = acc[i][0]; ov.y = acc[i][1]; ov.z = acc[i][2]; ov.w = acc[i][3];
      *(float4*)&z[((size_t)b * O + o) * NN + n0 + tm * 4] = ov;
    }
  }
}

// ---------------------------------------------------------------- conv GEMM 128-tile, double-buffered (fp32)
__global__ __launch_bounds__(256, 2) void conv_gemm128_db_kernel(
    const float* __restrict__ in, int inBS, int C, int O,
    const float* __restrict__ w, float* __restrict__ z) {
  const int b = blockIdx.z;
  const int n0 = blockIdx.x * 128, o0 = blockIdx.y * 128;
  const int tid = threadIdx.x;
  const int tm = tid & 15, tn = tid >> 4;
  __shared__ float Xs[2][16][128];
  __shared__ float Ws[2][16][132];
  const float* ib = in + (size_t)b * inBS;
  float acc[8][8];
#pragma unroll
  for (int i = 0; i < 8; ++i)
#pragma unroll
    for (int j = 0; j < 8; ++j) acc[i][j] = 0.f;

  float4 xr[2], wr[2];
  auto load_tile = [&](int k0) {
#pragma unroll
    for (int it = 0; it < 2; ++it) {
      int i = it * 256 + tid;
      int kc = i >> 5, c4 = i & 31;
      xr[it] = ((k0 + kc) < C) ? *(const float4*)&ib[(size_t)(k0 + kc) * NN + n0 + c4 * 4]
                               : make_float4(0.f, 0.f, 0.f, 0.f);
      int ol = i >> 2, kq = i & 3;
      wr[it] = ((k0 + kq * 4) < C) ? *(const float4*)&w[(size_t)(o0 + ol) * C + k0 + kq * 4]
                                   : make_float4(0.f, 0.f, 0.f, 0.f);
    }
  };
  auto store_tile = [&](int buf) {
#pragma unroll
    for (int it = 0; it < 2; ++it) {
      int i = it * 256 + tid;
      int kc = i >> 5, c4 = i & 31;
      *(float4*)&Xs[buf][kc][c4 * 4] = xr[it];
      int ol = i >> 2, kq = i & 3;
      Ws[buf][kq * 4 + 0][ol] = wr[it].x;
      Ws[buf][kq * 4 + 1][ol] = wr[it].y;
      Ws[buf][kq * 4 + 2][ol] = wr[it].z;
      Ws[buf][kq * 4 + 3][ol] = wr[it].w;
    }
  };

  load_tile(0);
  store_tile(0);
  int cur = 0;
  for (int k0 = 0; k0 < C; k0 += 16) {
    bool more = (k0 + 16) < C;
    if (more) load_tile(k0 + 16);
    __syncthreads();
#pragma unroll
    for (int kc = 0; kc < 16; ++kc) {
      float4 a0 = *(const float4*)&Ws[cur][kc][tn * 4];
      float4 a1 = *(const float4*)&Ws[cur][kc][64 + tn * 4];
      float4 b0 = *(const float4*)&Xs[cur][kc][tm * 4];
      float4 b1 = *(const float4*)&Xs[cur][kc][64 + tm * 4];
      float ar[8] = {a0.x, a0.y, a0.z, a0.w, a1.x, a1.y, a1.z, a1.w};
      float br[8] = {b0.x, b0.y, b0.z, b0.w, b1.x, b1.y, b1.z, b1.w};
#pragma unroll
      for (int i = 0; i < 8; ++i)
#pragma unroll
        for (int j = 0; j < 8; ++j) acc[i][j] += ar[i] * br[j];
    }
    if (more) store_tile(cur ^ 1);
    cur ^= 1;
  }
#pragma unroll
  for (int h = 0; h < 2; ++h)
#pragma unroll
    for (int i = 0; i < 4; ++i) {
      int r = h * 4 + i;
      int o = o0 + h * 64 + tn * 4 + i;
      float* zrow = &z[((size_t)b * O + o) * NN + n0];
      float4 o0v, o1v;
      o0v.x = acc[r][0]; o0v.y = acc[r][1]; o0v.z = acc[r][2]; o0v.w = acc[r][3];
      o1v.x = acc[r][4]; o1v.y = acc[r][5]; o1v.z = acc[r][6]; o1v.w = acc[r][7];
      *(float4*)&zrow[tm * 4] = o0v;
      *(float4*)&zrow[64 + tm * 4] = o1v;
    }
}

// ---------------------------------------------------------------- attention (wave/point)
template <int C>
__global__ __launch_bounds__(64) void att_wave_kernel(
    const float* __restrict__ xT, const float* __restrict__ UT,
    const int* __restrict__ idx, float* __restrict__ AGGt) {
  const int n = blockIdx.x & (NN - 1);
  const int b = blockIdx.x >> 11;
  const int lane = threadIdx.x;
  constexpr int CP = C + 1;
  __shared__ float nb[KNB][CP];
  __shared__ float sl[KNB];
  __shared__ int nidx[KNB];
  __shared__ float ul[C];
  const float* xTb = xT + (size_t)b * NN * C;
  if (lane < KNB) nidx[lane] = idx[(size_t)(b * NN + n) * KNB + lane];
  for (int c = lane; c < C; c += 64) ul[c] = UT[((size_t)b * NN + n) * C + c];
  __syncthreads();
  for (int i = lane; i < KNB * C; i += 64) {
    int k = i / C, c = i - k * C;
    nb[k][c] = xTb[(size_t)nidx[k] * C + c];
  }
  __syncthreads();
  float sv = -INFINITY;
  if (lane < KNB) {
    float a = 0.f;
#pragma unroll
    for (int c = 0; c < C; ++c) a += nb[lane][c] * ul[c];
    sv = a / sqrtf((float)C);
  }
  float mx = sv;
#pragma unroll
  for (int s = 32; s > 0; s >>= 1) mx = fmaxf(mx, __shfl_xor(mx, s));
  float e = (lane < KNB) ? expf(sv - mx) : 0.f;
  float sum = e;
#pragma unroll
  for (int s = 32; s > 0; s >>= 1) sum += __shfl_xor(sum, s);
  if (lane < KNB) sl[lane] = e / sum;
  __syncthreads();
  const float* xTn = xTb + (size_t)n * C;
  float* op = AGGt + ((size_t)b * NN + n) * C;
  for (int c = lane; c < C; c += 64) {
    float a = 0.f;
#pragma unroll
    for (int k = 0; k < KNB; ++k) a += sl[k] * nb[k][c];
    op[c] = a - xTn[c];
  }
}

// ---------------------------------------------------------------- fused BN (+LReLU)
__global__ __launch_bounds__(256) void bn_fused_kernel(const float* __restrict__ z, int O,
                                                       float* __restrict__ out, int outBS, int c0) {
  int o = blockIdx.x;
  int tid = threadIdx.x;
  __shared__ float s1[256], s2[256];
  __shared__ float smv, srv;
  float a1 = 0.f, a2 = 0.f;
  for (int i = tid; i < BB * NN; i += 256) {
    int b = i >> 11, n = i & (NN - 1);
    float v = z[((size_t)b * O + o) * NN + n];
    a1 += v; a2 += v * v;
  }
  s1[tid] = a1; s2[tid] = a2;
  __syncthreads();
  for (int st = 128; st > 0; st >>= 1) {
    if (tid < st) { s1[tid] += s1[tid + st]; s2[tid] += s2[tid + st]; }
    __syncthreads();
  }
  if (tid == 0) {
    float m = s1[0] / (BB * NN);
    float var = s2[0] / (BB * NN) - m * m;
    smv = m; srv = rsqrtf(var + 1e-5f);
  }
  __syncthreads();
  float m = smv, r = srv;
  for (int i = tid; i < BB * NN; i += 256) {
    int b = i >> 11, n = i & (NN - 1);
    float v = (z[((size_t)b * O + o) * NN + n] - m) * r;
    out[(size_t)b * outBS + (c0 + o) * NN + n] = v >= 0.f ? v : 0.2f * v;
  }
}

// ---------------------------------------------------------------- BN+LReLU into h[:,0:O,:], copy xin into h[:,O:2O,:]
__global__ __launch_bounds__(256) void bn_copy_kernel(const float* __restrict__ z, int O,
                                                      const float* __restrict__ xin, int xbs,
                                                      float* __restrict__ out) {
  int o = blockIdx.x;  // 0..2O-1
  int tid = threadIdx.x;
  int outBS = 2 * O * NN;
  if (o >= O) {
    int c = o - O;
    for (int i = tid; i < BB * NN; i += 256) {
      int b = i >> 11, n = i & (NN - 1);
      out[(size_t)b * outBS + o * NN + n] = xin[(size_t)b * xbs + c * NN + n];
    }
    return;
  }
  __shared__ float s1[256], s2[256];
  __shared__ float smv, srv;
  float a1 = 0.f, a2 = 0.f;
  for (int i = tid; i < BB * NN; i += 256) {
    int b = i >> 11, n = i & (NN - 1);
    float v = z[((size_t)b * O + o) * NN + n];
    a1 += v; a2 += v * v;
  }
  s1[tid] = a1; s2[tid] = a2;
  __syncthreads();
  for (int st = 128; st > 0; st >>= 1) {
    if (tid < st) { s1[tid] += s1[tid + st]; s2[tid] += s2[tid + st]; }
    __syncthreads();
  }
  if (tid == 0) {
    float m = s1[0] / (BB * NN);
    float var = s2[0] / (BB * NN) - m * m;
    smv = m; srv = rsqrtf(var + 1e-5f);
  }
  __syncthreads();
  float m = smv, r = srv;
  for (int i = tid; i < BB * NN; i += 256) {
    int b = i >> 11, n = i & (NN - 1);
    float v = (z[((size_t)b * O + o) * NN + n] - m) * r;
    out[(size_t)b * outBS + o * NN + n] = v >= 0.f ? v : 0.2f * v;
  }
}

// ---------------------------------------------------------------- fused BN+LReLU+max/mean pool (conv5)
__global__ __launch_bounds__(256) void bn_pool_kernel(const float* __restrict__ z,
                                                      float* __restrict__ p) {
  int o = blockIdx.x;
  int tid = threadIdx.x;
  __shared__ float s1[256], s2[256];
  __shared__ float smv, srv;
  float a1 = 0.f, a2 = 0.f;
  for (int i = tid; i < BB * NN; i += 256) {
    int b = i >> 11, n = i & (NN - 1);
    float v = z[((size_t)b * 1024 + o) * NN + n];
    a1 += v; a2 += v * v;
  }
  s1[tid] = a1; s2[tid] = a2;
  __syncthreads();
  for (int st = 128; st > 0; st >>= 1) {
    if (tid < st) { s1[tid] += s1[tid + st]; s2[tid] += s2[tid + st]; }
    __syncthreads();
  }
  if (tid == 0) {
    float m = s1[0] / (BB * NN);
    float var = s2[0] / (BB * NN) - m * m;
    smv = m; srv = rsqrtf(var + 1e-5f);
  }
  __syncthreads();
  float m = smv, r = srv;
  int b = tid >> 5, l = tid & 31;
  const float* zp = z + ((size_t)b * 1024 + o) * NN;
  float mx = -INFINITY, sm = 0.f;
  for (int n = l; n < NN; n += 32) {
    float v = (zp[n] - m) * r;
    v = v >= 0.f ? v : 0.2f * v;
    mx = fmaxf(mx, v); sm += v;
  }
#pragma unroll
  for (int s = 16; s > 0; s >>= 1) {
    mx = fmaxf(mx, __shfl_xor(mx, s));
    sm += __shfl_xor(sm, s);
  }
  if (l == 0) {
    p[b * 2048 + o] = mx;
    p[b * 2048 + 1024 + o] = sm * (1.f / NN);
  }
}

__global__ __launch_bounds__(64) void linear_kernel(const float* __restrict__ in, int IN, int OUT,
                                                    const float* __restrict__ w,
                                                    const float* __restrict__ bias,
                                                    float* __restrict__ out) {
  int o = blockIdx.x;
  int b = o / OUT, f = o % OUT;
  const float* ip = in + (size_t)b * IN;
  const float* wp = w + (size_t)f * IN;
  float a = 0.f;
  for (int i = threadIdx.x; i < IN; i += 64) a += ip[i] * wp[i];
#pragma unroll
  for (int s = 32; s > 0; s >>= 1) a += __shfl_down(a, s);
  if (threadIdx.x == 0) out[o] = a + bias[f];
}

__global__ __launch_bounds__(256) void bnf_kernel(float* __restrict__ t, int F) {
  int f = blockIdx.x * blockDim.x + threadIdx.x;
  if (f >= F) return;
  float s = 0.f, s2 = 0.f;
  for (int b = 0; b < BB; ++b) { float v = t[b * F + f]; s += v; s2 += v * v; }
  float m = s * (1.f / BB);
  float var = s2 * (1.f / BB) - m * m;
  float r = rsqrtf(var + 1e-5f);
  for (int b = 0; b < BB; ++b) {
    float v = (t[b * F + f] - m) * r;
    t[b * F + f] = v >= 0.f ? v : 0.2f * v;
  }
}

// ---------------------------------------------------------------- host side

struct SAW { const float *wq, *wk, *wv, *wc; };

static inline void run_conv(const float* in, int inBS, int C, int O, const float* w,
                            float* z, hipStream_t st) {
  if (O % 128 == 0)
    conv_gemm128_db_kernel<<<dim3(NN / 128, O / 128, BB), 256, 0, st>>>(in, inBS, C, O, w, z);
  else
    conv_gemm_kernel<<<dim3(NN / 64, (O + 63) / 64, BB), 256, 0, st>>>(in, inBS, C, O, w, z);
}

// MFMA==true only valid for C multiple of 128.
template <int C, bool MFMA>
static inline void run_sa(const float* xin, int xbs, SAW w,
                          float* xT, float* U, float* UT, float* AGGt,
                          float* AGG, float* z, float* h, float* sq, int* idx,
                          float* M, float* WCV, unsigned short* Mb, unsigned short* wcvb,
                          unsigned short* xTb, unsigned short* AGGtb,
                          float* D, int nbatch, hipStream_t st) {
  sq_kernel<<<BB * NN / 256, 256, 0, st>>>(xin, xbs, C, sq);
  transpose_kernel<<<dim3(NN / 32, (C + 31) / 32, BB), 256, 0, st>>>(xin, xbs, C, NN, xT);
  mprep_kernel<<<(C * C + 255) / 256, 256, 0, st>>>(w.wq, w.wk, C, M);
  wcv_kernel<<<(C * C + 255) / 256, 256, 0, st>>>(w.wc, w.wv, C, WCV);
  if (MFMA) {
    convert_bf16_kernel<<<(C * C + 255) / 256, 256, 0, st>>>(M, Mb, C * C);
    convert_bf16_kernel<<<(C * C + 255) / 256, 256, 0, st>>>(WCV, wcvb, C * C);
    transpose_bf16_kernel<<<dim3(NN / 32, (C + 31) / 32, BB), 256, 0, st>>>(xin, xbs, C, NN, xTb);
  }
  for (int bb = 0; bb < BB; bb += nbatch) {
    int nbc = (BB - bb) < nbatch ? (BB - bb) : nbatch;
    pd_sym_kernel<<<dim3(136, nbc), 256, 0, st>>>(xin, xbs, C, sq, D, bb);
    topk2_kernel<<<dim3(NN / 2, nbc), 64, 0, st>>>(D, idx, bb);
  }
  if (MFMA)
    mfma_gemm_lds_kernel<<<dim3(NN / 128, C / 128, BB), 256, 0, st>>>(Mb, xTb, U, C, C);
  else
    run_conv(xin, xbs, C, C, M, U, st);                            // U = M . x  [C][N]
  transpose_kernel<<<dim3(NN / 32, (C + 31) / 32, BB), 256, 0, st>>>(U, C * NN, C, NN, UT);
  att_wave_kernel<C><<<BB * NN, 64, 0, st>>>(xT, UT, idx, AGGt);   // AGGt [N][C]
  if (MFMA) {
    convert_bf16_kernel<<<(BB * NN * C + 255) / 256, 256, 0, st>>>(AGGt, AGGtb, BB * NN * C);
    mfma_gemm_lds_kernel<<<dim3(NN / 128, C / 128, BB), 256, 0, st>>>(wcvb, AGGtb, z, C, C);
  } else {
    transpose_kernel<<<dim3((C + 31) / 32, NN / 32, BB), 256, 0, st>>>(AGGt, NN * C, NN, C, AGG);
    run_conv(AGG, C * NN, C, C, WCV, z, st);                       // Z = (wc.wv) . AGG
  }
  bn_copy_kernel<<<2 * C, 256, 0, st>>>(z, C, xin, xbs, h);
}

static inline void run_conv_bn(const float* in, int inBS, int Cin, int O, const float* w,
                               float* z, float* out, int outBS, int c0, hipStream_t st) {
  run_conv(in, inBS, Cin, O, w, z, st);
  bn_fused_kernel<<<O, 256, 0, st>>>(z, O, out, outBS, c0);
}

extern "C" void kernel_launch(void* const* d_in, const int* in_sizes, int n_in,
                              void* d_out, int out_size, void* d_ws, size_t ws_size,
                              hipStream_t stream) {
  const float* x = (const float*)d_in[0];
  SAW sa1{(const float*)d_in[1], (const float*)d_in[2], (const float*)d_in[3], (const float*)d_in[4]};
  SAW sa2{(const float*)d_in[5], (const float*)d_in[6], (const float*)d_in[7], (const float*)d_in[8]};
  SAW sa3{(const float*)d_in[9], (const float*)d_in[10], (const float*)d_in[11], (const float*)d_in[12]};
  SAW sa4{(const float*)d_in[13], (const float*)d_in[14], (const float*)d_in[15], (const float*)d_in[16]};
  const float* conv1_w = (const float*)d_in[17];
  const float* conv2_w = (const float*)d_in[18];
  const float* conv3_w = (const float*)d_in[19];
  const float* conv4_w = (const float*)d_in[20];
  const float* conv5_w = (const float*)d_in[21];
  const float* lin1_w = (const float*)d_in[22];
  const float* lin1_b = (const float*)d_in[23];
  const float* lin2_w = (const float*)d_in[24];
  const float* lin2_b = (const float*)d_in[25];
  const float* lin3_w = (const float*)d_in[26];
  const float* lin3_b = (const float*)d_in[27];

  char* ws = (char*)d_ws;
  size_t off = 0;
  auto take = [&](size_t bytes) -> void* {
    void* p = ws + off;
    off += (bytes + 255) & ~(size_t)255;
    return p;
  };
  float* sq   = (float*)take((size_t)BB * NN * 4);
  int*   idx  = (int*)take((size_t)BB * NN * KNB * 4);
  float* M    = (float*)take((size_t)128 * 128 * 4);
  float* WCV  = (float*)take((size_t)128 * 128 * 4);
  unsigned short* Mb   = (unsigned short*)take((size_t)128 * 128 * 2);
  unsigned short* wcvb = (unsigned short*)take((size_t)128 * 128 * 2);
  unsigned short* w4b  = (unsigned short*)take((size_t)256 * 256 * 2);
  unsigned short* w5b  = (unsigned short*)take((size_t)1024 * 512 * 2);
  float* U    = (float*)take((size_t)BB * 128 * NN * 4);  // contiguous with AGG
  float* AGG  = (float*)take((size_t)BB * 128 * NN * 4);  // also hosts xT
  float* h    = (float*)take((size_t)BB * 256 * NN * 4);  // first half hosts UT
  float* z    = (float*)take((size_t)BB * 1024 * NN * 4); // hosts AGGt, AGGtb(+16MB), D-chunks
  float* xc   = (float*)take((size_t)BB * 512 * NN * 4);
  float* p    = (float*)take((size_t)BB * 2048 * 4);
  float* t1   = (float*)take((size_t)BB * 512 * 4);
  float* t2   = (float*)take((size_t)BB * 256 * 4);
  (void)n_in; (void)in_sizes; (void)out_size;

  // Overlays (phase-ordered lifetimes):
  float* xT = AGG;                                          // dead before AGG written
  float* UT = h;                                            // consumed before h written
  float* AGGt = z;                                          // first 8.4 MB of z
  unsigned short* xTb   = (unsigned short*)((char*)h + (size_t)BB * 128 * NN * 4);  // h 2nd half
  unsigned short* AGGtb = (unsigned short*)((char*)z + (size_t)16 * 1024 * 1024);   // z + 16 MB
  unsigned short* hTb   = (unsigned short*)U;               // conv4 phase (U dead)
  unsigned short* xcTb  = (unsigned short*)U;               // conv5 phase (U+AGG dead, 16.8 MB)

  size_t dfull = (size_t)BB * NN * NN * 4;
  bool fullD = (ws_size > off + dfull + 4096);
  float* D = fullD ? (float*)take(dfull) : z;               // !fullD: 4-batch chunks fill z exactly
  int nbatch = fullD ? BB : 4;

  // SA1 (C=3) -> h [B,6,N]
  run_sa<3, false>(x, 3 * NN, sa1, xT, U, UT, AGGt, AGG, z, h, sq, idx,
                   M, WCV, Mb, wcvb, xTb, AGGtb, D, nbatch, stream);
  run_conv_bn(h, 6 * NN, 6, 64, conv1_w, z, xc, 512 * NN, 0, stream);
  // SA2 (C=64) on x1
  run_sa<64, false>(xc + 0 * NN, 512 * NN, sa2, xT, U, UT, AGGt, AGG, z, h, sq, idx,
                    M, WCV, Mb, wcvb, xTb, AGGtb, D, nbatch, stream);
  run_conv_bn(h, 128 * NN, 128, 64, conv2_w, z, xc, 512 * NN, 64, stream);
  // SA3 (C=64) on x2
  run_sa<64, false>(xc + 64 * NN, 512 * NN, sa3, xT, U, UT, AGGt, AGG, z, h, sq, idx,
                    M, WCV, Mb, wcvb, xTb, AGGtb, D, nbatch, stream);
  run_conv_bn(h, 128 * NN, 128, 128, conv3_w, z, xc, 512 * NN, 128, stream);
  // SA4 (C=128) on x3 — bf16 MFMA for U and Z convs (no kNN downstream)
  run_sa<128, true>(xc + 128 * NN, 512 * NN, sa4, xT, U, UT, AGGt, AGG, z, h, sq, idx,
                    M, WCV, Mb, wcvb, xTb, AGGtb, D, nbatch, stream);
  // conv4 (bf16 MFMA): h [B,256,N] -> z [B,256,N]
  transpose_bf16_kernel<<<dim3(NN / 32, 8, BB), 256, 0, stream>>>(h, 256 * NN, 256, NN, hTb);
  convert_bf16_kernel<<<(256 * 256 + 255) / 256, 256, 0, stream>>>(conv4_w, w4b, 256 * 256);
  mfma_gemm_lds_kernel<<<dim3(NN / 128, 2, BB), 256, 0, stream>>>(w4b, hTb, z, 256, 256);
  bn_fused_kernel<<<256, 256, 0, stream>>>(z, 256, xc, 512 * NN, 256);
  // conv5 (bf16 MFMA): xc [B,512,N] -> z [B,1024,N]; BN+LReLU+pool -> p
  transpose_bf16_kernel<<<dim3(NN / 32, 16, BB), 256, 0, stream>>>(xc, 512 * NN, 512, NN, xcTb);
  convert_bf16_kernel<<<(1024 * 512 + 255) / 256, 256, 0, stream>>>(conv5_w, w5b, 1024 * 512);
  mfma_gemm_lds_kernel<<<dim3(NN / 128, 8, BB), 256, 0, stream>>>(w5b, xcTb, z, 1024, 512);
  bn_pool_kernel<<<1024, 256, 0, stream>>>(z, p);
  // FC head
  linear_kernel<<<BB * 512, 64, 0, stream>>>(p, 2048, 512, lin1_w, lin1_b, t1);
  bnf_kernel<<<2, 256, 0, stream>>>(t1, 512);
  linear_kernel<<<BB * 256, 64, 0, stream>>>(t1, 512, 256, lin2_w, lin2_b, t2);
  bnf_kernel<<<1, 256, 0, stream>>>(t2, 256);
  linear_kernel<<<BB * 40, 64, 0, stream>>>(t2, 256, 40, lin3_w, lin3_b, (float*)d_out);
}

// Round 11
// 1745.885 us; speedup vs baseline: 1.0943x; 1.0943x over previous
//
#include <hip/hip_runtime.h>
#include <math.h>

#define BB 8
#define NN 2048
#define KNB 20

typedef __attribute__((ext_vector_type(8))) short bf16x8;
typedef __attribute__((ext_vector_type(4))) float f32x4;

__device__ inline unsigned short f2bf(float f) {
  union { float f; unsigned u; } v; v.f = f;
  unsigned r = v.u + 0x7FFF + ((v.u >> 16) & 1);  // RNE
  return (unsigned short)(r >> 16);
}

// ---------------------------------------------------------------- sq
__global__ __launch_bounds__(256) void sq_kernel(const float* __restrict__ x, int bs, int C,
                                                 float* __restrict__ sq) {
  int t = blockIdx.x * blockDim.x + threadIdx.x;
  int b = t / NN, n = t % NN;
  const float* xp = x + (size_t)b * bs + n;
  float s = 0.f;
  for (int c = 0; c < C; ++c) { float v = xp[c * NN]; s += v * v; }
  sq[t] = s;
}

// ---------------------------------------------------------------- M = wk^T wq
__global__ __launch_bounds__(256) void mprep_kernel(const float* __restrict__ wq,
                                                    const float* __restrict__ wk, int C,
                                                    float* __restrict__ M) {
  int T = blockIdx.x * 256 + threadIdx.x;
  if (T >= C * C) return;
  int c = T / C, cp = T % C;
  float a = 0.f;
  for (int e = 0; e < C; ++e) a += wk[e * C + c] * wq[e * C + cp];
  M[c * C + cp] = a;
}

// ---------------------------------------------------------------- wcv = wc @ wv
__global__ __launch_bounds__(256) void wcv_kernel(const float* __restrict__ wc,
                                                  const float* __restrict__ wv, int C,
                                                  float* __restrict__ out) {
  int T = blockIdx.x * 256 + threadIdx.x;
  if (T >= C * C) return;
  int o = T / C, c = T % C;
  float a = 0.f;
  for (int e = 0; e < C; ++e) a += wc[o * C + e] * wv[e * C + c];
  out[o * C + c] = a;
}

// ---------------------------------------------------------------- converts
__global__ __launch_bounds__(256) void convert_bf16_kernel(const float* __restrict__ in,
                                                           unsigned short* __restrict__ out,
                                                           int count) {
  int i = blockIdx.x * 256 + threadIdx.x;
  if (i < count) out[i] = f2bf(in[i]);
}

// ---------------------------------------------------------------- transpose (fp32)
__global__ __launch_bounds__(256) void transpose_kernel(const float* __restrict__ in, int inBS,
                                                        int R, int Cl, float* __restrict__ out) {
  __shared__ float tile[32][33];
  int b = blockIdx.z;
  const float* ip = in + (size_t)b * inBS;
  float* op = out + (size_t)b * R * Cl;
  int c0 = blockIdx.x * 32, r0 = blockIdx.y * 32;
  int tx = threadIdx.x & 31, ty = threadIdx.x >> 5;
  for (int yy = ty; yy < 32; yy += 8) {
    int r = r0 + yy, c = c0 + tx;
    tile[yy][tx] = (r < R && c < Cl) ? ip[(size_t)r * Cl + c] : 0.f;
  }
  __syncthreads();
  for (int yy = ty; yy < 32; yy += 8) {
    int c = c0 + yy, r = r0 + tx;
    if (c < Cl && r < R) op[(size_t)c * R + r] = tile[tx][yy];
  }
}

// ---------------------------------------------------------------- transpose + bf16 convert
__global__ __launch_bounds__(256) void transpose_bf16_kernel(const float* __restrict__ in, int inBS,
                                                             int R, int Cl,
                                                             unsigned short* __restrict__ out) {
  __shared__ float tile[32][33];
  int b = blockIdx.z;
  const float* ip = in + (size_t)b * inBS;
  unsigned short* op = out + (size_t)b * R * Cl;
  int c0 = blockIdx.x * 32, r0 = blockIdx.y * 32;
  int tx = threadIdx.x & 31, ty = threadIdx.x >> 5;
  for (int yy = ty; yy < 32; yy += 8) {
    int r = r0 + yy, c = c0 + tx;
    tile[yy][tx] = (r < R && c < Cl) ? ip[(size_t)r * Cl + c] : 0.f;
  }
  __syncthreads();
  for (int yy = ty; yy < 32; yy += 8) {
    int c = c0 + yy, r = r0 + tx;
    if (c < Cl && r < R) op[(size_t)c * R + r] = f2bf(tile[tx][yy]);
  }
}

// ---------------------------------------------------------------- MFMA GEMM, LDS double-buffered
// Z[b][o][n] = sum_k A[o][k] * B[b][n][k]; A,B bf16 K-contiguous, Z fp32.
__global__ __launch_bounds__(256, 2) void mfma_gemm_lds_kernel(
    const unsigned short* __restrict__ A, const unsigned short* __restrict__ B,
    float* __restrict__ Z, int O, int K) {
  const int b = blockIdx.z;
  const int n0 = blockIdx.x * 128, o0 = blockIdx.y * 128;
  const int tid = threadIdx.x;
  const int wave = tid >> 6, lane = tid & 63;
  const int wo = wave >> 1, wn = wave & 1;   // 64x64 quadrant per wave
  const int l16 = lane & 15, q = lane >> 4;
  __shared__ unsigned short Al[2][4096];     // 128 rows x 32 k (8 KB), frag order
  __shared__ unsigned short Bl[2][4096];
  const unsigned short* Ab = A + (size_t)o0 * K;
  const unsigned short* Bb = B + ((size_t)b * NN + n0) * K;

  const int p0 = tid, p1 = tid + 256;
  const int r0 = ((p0 >> 6) << 4) | (p0 & 15), c0 = ((p0 >> 4) & 3) * 8;
  const int r1 = ((p1 >> 6) << 4) | (p1 & 15), c1 = ((p1 >> 4) & 3) * 8;

  bf16x8 ar0, ar1, br0, br1;
  auto gload = [&](int k0) {
    ar0 = *(const bf16x8*)(Ab + (size_t)r0 * K + k0 + c0);
    ar1 = *(const bf16x8*)(Ab + (size_t)r1 * K + k0 + c1);
    br0 = *(const bf16x8*)(Bb + (size_t)r0 * K + k0 + c0);
    br1 = *(const bf16x8*)(Bb + (size_t)r1 * K + k0 + c1);
  };
  auto sstore = [&](int buf) {
    *(bf16x8*)&Al[buf][p0 * 8] = ar0;
    *(bf16x8*)&Al[buf][p1 * 8] = ar1;
    *(bf16x8*)&Bl[buf][p0 * 8] = br0;
    *(bf16x8*)&Bl[buf][p1 * 8] = br1;
  };

  f32x4 acc[4][4];
#pragma unroll
  for (int s = 0; s < 4; ++s)
#pragma unroll
    for (int t = 0; t < 4; ++t) acc[s][t] = (f32x4){0.f, 0.f, 0.f, 0.f};

  gload(0);
  sstore(0);
  int cur = 0;
  for (int k0 = 0; k0 < K; k0 += 32) {
    bool more = (k0 + 32) < K;
    if (more) gload(k0 + 32);
    __syncthreads();
    bf16x8 af[4], bfr[4];
#pragma unroll
    for (int s = 0; s < 4; ++s)
      af[s] = *(const bf16x8*)&Al[cur][((wo * 4 + s) * 64 + q * 16 + l16) * 8];
#pragma unroll
    for (int t = 0; t < 4; ++t)
      bfr[t] = *(const bf16x8*)&Bl[cur][((wn * 4 + t) * 64 + q * 16 + l16) * 8];
#pragma unroll
    for (int s = 0; s < 4; ++s)
#pragma unroll
      for (int t = 0; t < 4; ++t)
        acc[s][t] = __builtin_amdgcn_mfma_f32_16x16x32_bf16(af[s], bfr[t], acc[s][t], 0, 0, 0);
    if (more) sstore(cur ^ 1);
    cur ^= 1;
  }
#pragma unroll
  for (int s = 0; s < 4; ++s)
#pragma unroll
    for (int t = 0; t < 4; ++t) {
      float* zp = Z + ((size_t)b * O + o0 + wo * 64 + s * 16 + q * 4) * NN
                  + n0 + wn * 64 + t * 16 + l16;
#pragma unroll
      for (int r = 0; r < 4; ++r) zp[(size_t)r * NN] = acc[s][t][r];
    }
}

// ---------------------------------------------------------------- pd GEMM 128-tile, double-buffered
// Full matrix (r10's symmetric variant regressed: +17KB LDS -> 1 block/CU,
// occupancy 13%, 92 us vs 46. Reverted.)
// __launch_bounds__(256,2): (256,3) capped VGPR at 84 and spilled (r6).
__global__ __launch_bounds__(256, 2) void pd_gemm128_db_kernel(
    const float* __restrict__ x, int bs, int C, const float* __restrict__ sq,
    float* __restrict__ P, int b_base) {
  const int b = b_base + blockIdx.z;
  const int n0 = blockIdx.x * 128, m0 = blockIdx.y * 128;
  const int tid = threadIdx.x;
  const int tm = tid & 15, tn = tid >> 4;
  __shared__ float As[2][16][128], Bs[2][16][128];
  const float* xb = x + (size_t)b * bs;
  float acc[8][8];
#pragma unroll
  for (int i = 0; i < 8; ++i)
#pragma unroll
    for (int j = 0; j < 8; ++j) acc[i][j] = 0.f;

  float4 ara[2], arb[2];
  auto load_tile = [&](int k0) {
#pragma unroll
    for (int it = 0; it < 2; ++it) {
      int i = it * 256 + tid;
      int kc = i >> 5, c4 = i & 31;
      bool ok = (k0 + kc) < C;
      ara[it] = ok ? *(const float4*)&xb[(size_t)(k0 + kc) * NN + n0 + c4 * 4]
                   : make_float4(0.f, 0.f, 0.f, 0.f);
      arb[it] = ok ? *(const float4*)&xb[(size_t)(k0 + kc) * NN + m0 + c4 * 4]
                   : make_float4(0.f, 0.f, 0.f, 0.f);
    }
  };
  auto store_tile = [&](int buf) {
#pragma unroll
    for (int it = 0; it < 2; ++it) {
      int i = it * 256 + tid;
      int kc = i >> 5, c4 = i & 31;
      *(float4*)&As[buf][kc][c4 * 4] = ara[it];
      *(float4*)&Bs[buf][kc][c4 * 4] = arb[it];
    }
  };

  load_tile(0);
  store_tile(0);
  int cur = 0;
  for (int k0 = 0; k0 < C; k0 += 16) {
    bool more = (k0 + 16) < C;
    if (more) load_tile(k0 + 16);
    __syncthreads();
#pragma unroll
    for (int kc = 0; kc < 16; ++kc) {
      float4 a0 = *(const float4*)&As[cur][kc][tn * 4];
      float4 a1 = *(const float4*)&As[cur][kc][64 + tn * 4];
      float4 b0 = *(const float4*)&Bs[cur][kc][tm * 4];
      float4 b1 = *(const float4*)&Bs[cur][kc][64 + tm * 4];
      float ar[8] = {a0.x, a0.y, a0.z, a0.w, a1.x, a1.y, a1.z, a1.w};
      float br[8] = {b0.x, b0.y, b0.z, b0.w, b1.x, b1.y, b1.z, b1.w};
#pragma unroll
      for (int i = 0; i < 8; ++i)
#pragma unroll
        for (int j = 0; j < 8; ++j) acc[i][j] += ar[i] * br[j];
    }
    if (more) store_tile(cur ^ 1);
    cur ^= 1;
  }
  float4 sqa = *(const float4*)&sq[b * NN + m0 + tm * 4];
  float4 sqb = *(const float4*)&sq[b * NN + m0 + 64 + tm * 4];
#pragma unroll
  for (int h = 0; h < 2; ++h)
#pragma unroll
    for (int i = 0; i < 4; ++i) {
      int r = h * 4 + i;
      int nn = n0 + h * 64 + tn * 4 + i;
      float* prow = &P[((size_t)blockIdx.z * NN + nn) * NN + m0];
      float4 o0, o1;
      o0.x = 2.f * acc[r][0] - sqa.x; o0.y = 2.f * acc[r][1] - sqa.y;
      o0.z = 2.f * acc[r][2] - sqa.z; o0.w = 2.f * acc[r][3] - sqa.w;
      o1.x = 2.f * acc[r][4] - sqb.x; o1.y = 2.f * acc[r][5] - sqb.y;
      o1.z = 2.f * acc[r][6] - sqb.z; o1.w = 2.f * acc[r][7] - sqb.w;
      *(float4*)&prow[tm * 4] = o0;
      *(float4*)&prow[64 + tm * 4] = o1;
    }
}

// ---------------------------------------------------------------- top-20, two rows per wave
// Independent dependency chains interleave -> fills shuffle-latency bubbles
// (r10: removed topk from top-5; kept).
__global__ __launch_bounds__(64) void topk2_kernel(const float* __restrict__ P,
                                                   int* __restrict__ idx, int b_base) {
  const int n0 = blockIdx.x * 2;
  const int bl = blockIdx.y;
  const int b = b_base + bl;
  const int lane = threadIdx.x;
  const float4* rpA = (const float4*)(P + ((size_t)bl * NN + n0) * NN);
  const float4* rpB = (const float4*)(P + ((size_t)bl * NN + n0 + 1) * NN);
  float va[32], vb[32];
#pragma unroll
  for (int q = 0; q < 8; ++q) {
    float4 a = rpA[q * 64 + lane];
    float4 c = rpB[q * 64 + lane];
    int mb = q * 256 + lane * 4;
    va[q * 4 + 0] = (mb + 0 == n0) ? -INFINITY : a.x;
    va[q * 4 + 1] = (mb + 1 == n0) ? -INFINITY : a.y;
    va[q * 4 + 2] = (mb + 2 == n0) ? -INFINITY : a.z;
    va[q * 4 + 3] = (mb + 3 == n0) ? -INFINITY : a.w;
    vb[q * 4 + 0] = (mb + 0 == n0 + 1) ? -INFINITY : c.x;
    vb[q * 4 + 1] = (mb + 1 == n0 + 1) ? -INFINITY : c.y;
    vb[q * 4 + 2] = (mb + 2 == n0 + 1) ? -INFINITY : c.z;
    vb[q * 4 + 3] = (mb + 3 == n0 + 1) ? -INFINITY : c.w;
  }
  int* opA = idx + (size_t)(b * NN + n0) * KNB;
  int* opB = opA + KNB;
  for (int k = 0; k < KNB; ++k) {
    float bvA = va[0]; int bjA = 0;
    float bvB = vb[0]; int bjB = 0;
#pragma unroll
    for (int j = 1; j < 32; ++j) {
      if (va[j] > bvA) { bvA = va[j]; bjA = j; }
      if (vb[j] > bvB) { bvB = vb[j]; bjB = j; }
    }
    int bmA = (bjA >> 2) * 256 + lane * 4 + (bjA & 3);
    int bmB = (bjB >> 2) * 256 + lane * 4 + (bjB & 3);
#pragma unroll
    for (int s = 32; s > 0; s >>= 1) {
      float ovA = __shfl_down(bvA, s); int omA = __shfl_down(bmA, s);
      float ovB = __shfl_down(bvB, s); int omB = __shfl_down(bmB, s);
      if (ovA > bvA) { bvA = ovA; bmA = omA; }
      if (ovB > bvB) { bvB = ovB; bmB = omB; }
    }
    bmA = __shfl(bmA, 0); bmB = __shfl(bmB, 0);
    if (lane == 0) { opA[k] = bmA; opB[k] = bmB; }
    if (((bmA >> 2) & 63) == lane) {
      int jj = ((bmA >> 8) << 2) | (bmA & 3);
#pragma unroll
      for (int j = 0; j < 32; ++j)
        if (j == jj) va[j] = -INFINITY;
    }
    if (((bmB >> 2) & 63) == lane) {
      int jj = ((bmB >> 8) << 2) | (bmB & 3);
#pragma unroll
      for (int j = 0; j < 32; ++j)
        if (j == jj) vb[j] = -INFINITY;
    }
  }
}

// ---------------------------------------------------------------- conv GEMM 64-tile (small O)
__global__ __launch_bounds__(256, 2) void conv_gemm_kernel(
    const float* __restrict__ in, int inBS, int C, int O,
    const float* __restrict__ w, float* __restrict__ z) {
  const int b = blockIdx.z;
  const int n0 = blockIdx.x * 64, o0 = blockIdx.y * 64;
  const int tid = threadIdx.x;
  const int tm = tid & 15, tn = tid >> 4;
  __shared__ float Ws[16][68];
  __shared__ float Xs[16][64];
  const float* ib = in + (size_t)b * inBS;
  float acc[4][4];
#pragma unroll
  for (int i = 0; i < 4; ++i)
#pragma unroll
    for (int j = 0; j < 4; ++j) acc[i][j] = 0.f;

  for (int k0 = 0; k0 < C; k0 += 16) {
    __syncthreads();
#pragma unroll
    for (int it = 0; it < 4; ++it) {
      int i = it * 256 + tid;
      int kc = i >> 6, nl = i & 63;
      Xs[kc][nl] = ((k0 + kc) < C) ? ib[(size_t)(k0 + kc) * NN + n0 + nl] : 0.f;
      int ol = i >> 4, kc2 = i & 15;
      Ws[kc2][ol] = ((o0 + ol) < O && (k0 + kc2) < C) ? w[(size_t)(o0 + ol) * C + k0 + kc2] : 0.f;
    }
    __syncthreads();
#pragma unroll
    for (int kc = 0; kc < 16; ++kc) {
      float4 a = *(const float4*)&Ws[kc][tn * 4];
      float4 bv = *(const float4*)&Xs[kc][tm * 4];
      acc[0][0] += a.x * bv.x; acc[0][1] += a.x * bv.y; acc[0][2] += a.x * bv.z; acc[0][3] += a.x * bv.w;
      acc[1][0] += a.y * bv.x; acc[1][1] += a.y * bv.y; acc[1][2] += a.y * bv.z; acc[1][3] += a.y * bv.w;
      acc[2][0] += a.z * bv.x; acc[2][1] += a.z * bv.y; acc[2][2] += a.z * bv.z; acc[2][3] += a.z * bv.w;
      acc[3][0] += a.w * bv.x; acc[3][1] += a.w * bv.y; acc[3][2] += a.w * bv.z; acc[3][3] += a.w * bv.w;
    }
  }
#pragma unroll
  for (int i = 0; i < 4; ++i) {
    int o = o0 + tn * 4 + i;
    if (o < O) {
      float4 ov;
      ov.x = acc[i][0]; ov.y = acc[i][1]; ov.z = acc[i][2]; ov.w = acc[i][3];
      *(float4*)&z[((size_t)b * O + o) * NN + n0 + tm * 4] = ov;
    }
  }
}

// ---------------------------------------------------------------- conv GEMM 128-tile, double-buffered (fp32)
__global__ __launch_bounds__(256, 2) void conv_gemm128_db_kernel(
    const float* __restrict__ in, int inBS, int C, int O,
    const float* __restrict__ w, float* __restrict__ z) {
  const int b = blockIdx.z;
  const int n0 = blockIdx.x * 128, o0 = blockIdx.y * 128;
  const int tid = threadIdx.x;
  const int tm = tid & 15, tn = tid >> 4;
  __shared__ float Xs[2][16][128];
  __shared__ float Ws[2][16][132];
  const float* ib = in + (size_t)b * inBS;
  float acc[8][8];
#pragma unroll
  for (int i = 0; i < 8; ++i)
#pragma unroll
    for (int j = 0; j < 8; ++j) acc[i][j] = 0.f;

  float4 xr[2], wr[2];
  auto load_tile = [&](int k0) {
#pragma unroll
    for (int it = 0; it < 2; ++it) {
      int i = it * 256 + tid;
      int kc = i >> 5, c4 = i & 31;
      xr[it] = ((k0 + kc) < C) ? *(const float4*)&ib[(size_t)(k0 + kc) * NN + n0 + c4 * 4]
                               : make_float4(0.f, 0.f, 0.f, 0.f);
      int ol = i >> 2, kq = i & 3;
      wr[it] = ((k0 + kq * 4) < C) ? *(const float4*)&w[(size_t)(o0 + ol) * C + k0 + kq * 4]
                                   : make_float4(0.f, 0.f, 0.f, 0.f);
    }
  };
  auto store_tile = [&](int buf) {
#pragma unroll
    for (int it = 0; it < 2; ++it) {
      int i = it * 256 + tid;
      int kc = i >> 5, c4 = i & 31;
      *(float4*)&Xs[buf][kc][c4 * 4] = xr[it];
      int ol = i >> 2, kq = i & 3;
      Ws[buf][kq * 4 + 0][ol] = wr[it].x;
      Ws[buf][kq * 4 + 1][ol] = wr[it].y;
      Ws[buf][kq * 4 + 2][ol] = wr[it].z;
      Ws[buf][kq * 4 + 3][ol] = wr[it].w;
    }
  };

  load_tile(0);
  store_tile(0);
  int cur = 0;
  for (int k0 = 0; k0 < C; k0 += 16) {
    bool more = (k0 + 16) < C;
    if (more) load_tile(k0 + 16);
    __syncthreads();
#pragma unroll
    for (int kc = 0; kc < 16; ++kc) {
      float4 a0 = *(const float4*)&Ws[cur][kc][tn * 4];
      float4 a1 = *(const float4*)&Ws[cur][kc][64 + tn * 4];
      float4 b0 = *(const float4*)&Xs[cur][kc][tm * 4];
      float4 b1 = *(const float4*)&Xs[cur][kc][64 + tm * 4];
      float ar[8] = {a0.x, a0.y, a0.z, a0.w, a1.x, a1.y, a1.z, a1.w};
      float br[8] = {b0.x, b0.y, b0.z, b0.w, b1.x, b1.y, b1.z, b1.w};
#pragma unroll
      for (int i = 0; i < 8; ++i)
#pragma unroll
        for (int j = 0; j < 8; ++j) acc[i][j] += ar[i] * br[j];
    }
    if (more) store_tile(cur ^ 1);
    cur ^= 1;
  }
#pragma unroll
  for (int h = 0; h < 2; ++h)
#pragma unroll
    for (int i = 0; i < 4; ++i) {
      int r = h * 4 + i;
      int o = o0 + h * 64 + tn * 4 + i;
      float* zrow = &z[((size_t)b * O + o) * NN + n0];
      float4 o0v, o1v;
      o0v.x = acc[r][0]; o0v.y = acc[r][1]; o0v.z = acc[r][2]; o0v.w = acc[r][3];
      o1v.x = acc[r][4]; o1v.y = acc[r][5]; o1v.z = acc[r][6]; o1v.w = acc[r][7];
      *(float4*)&zrow[tm * 4] = o0v;
      *(float4*)&zrow[64 + tm * 4] = o1v;
    }
}

// ---------------------------------------------------------------- attention (wave/point)
template <int C>
__global__ __launch_bounds__(64) void att_wave_kernel(
    const float* __restrict__ xT, const float* __restrict__ UT,
    const int* __restrict__ idx, float* __restrict__ AGGt) {
  const int n = blockIdx.x & (NN - 1);
  const int b = blockIdx.x >> 11;
  const int lane = threadIdx.x;
  constexpr int CP = C + 1;
  __shared__ float nb[KNB][CP];
  __shared__ float sl[KNB];
  __shared__ int nidx[KNB];
  __shared__ float ul[C];
  const float* xTb = xT + (size_t)b * NN * C;
  if (lane < KNB) nidx[lane] = idx[(size_t)(b * NN + n) * KNB + lane];
  for (int c = lane; c < C; c += 64) ul[c] = UT[((size_t)b * NN + n) * C + c];
  __syncthreads();
  for (int i = lane; i < KNB * C; i += 64) {
    int k = i / C, c = i - k * C;
    nb[k][c] = xTb[(size_t)nidx[k] * C + c];
  }
  __syncthreads();
  float sv = -INFINITY;
  if (lane < KNB) {
    float a = 0.f;
#pragma unroll
    for (int c = 0; c < C; ++c) a += nb[lane][c] * ul[c];
    sv = a / sqrtf((float)C);
  }
  float mx = sv;
#pragma unroll
  for (int s = 32; s > 0; s >>= 1) mx = fmaxf(mx, __shfl_xor(mx, s));
  float e = (lane < KNB) ? expf(sv - mx) : 0.f;
  float sum = e;
#pragma unroll
  for (int s = 32; s > 0; s >>= 1) sum += __shfl_xor(sum, s);
  if (lane < KNB) sl[lane] = e / sum;
  __syncthreads();
  const float* xTn = xTb + (size_t)n * C;
  float* op = AGGt + ((size_t)b * NN + n) * C;
  for (int c = lane; c < C; c += 64) {
    float a = 0.f;
#pragma unroll
    for (int k = 0; k < KNB; ++k) a += sl[k] * nb[k][c];
    op[c] = a - xTn[c];
  }
}

// ---------------------------------------------------------------- fused BN (+LReLU)
__global__ __launch_bounds__(256) void bn_fused_kernel(const float* __restrict__ z, int O,
                                                       float* __restrict__ out, int outBS, int c0) {
  int o = blockIdx.x;
  int tid = threadIdx.x;
  __shared__ float s1[256], s2[256];
  __shared__ float smv, srv;
  float a1 = 0.f, a2 = 0.f;
  for (int i = tid; i < BB * NN; i += 256) {
    int b = i >> 11, n = i & (NN - 1);
    float v = z[((size_t)b * O + o) * NN + n];
    a1 += v; a2 += v * v;
  }
  s1[tid] = a1; s2[tid] = a2;
  __syncthreads();
  for (int st = 128; st > 0; st >>= 1) {
    if (tid < st) { s1[tid] += s1[tid + st]; s2[tid] += s2[tid + st]; }
    __syncthreads();
  }
  if (tid == 0) {
    float m = s1[0] / (BB * NN);
    float var = s2[0] / (BB * NN) - m * m;
    smv = m; srv = rsqrtf(var + 1e-5f);
  }
  __syncthreads();
  float m = smv, r = srv;
  for (int i = tid; i < BB * NN; i += 256) {
    int b = i >> 11, n = i & (NN - 1);
    float v = (z[((size_t)b * O + o) * NN + n] - m) * r;
    out[(size_t)b * outBS + (c0 + o) * NN + n] = v >= 0.f ? v : 0.2f * v;
  }
}

// ---------------------------------------------------------------- BN+LReLU into h[:,0:O,:], copy xin into h[:,O:2O,:]
__global__ __launch_bounds__(256) void bn_copy_kernel(const float* __restrict__ z, int O,
                                                      const float* __restrict__ xin, int xbs,
                                                      float* __restrict__ out) {
  int o = blockIdx.x;  // 0..2O-1
  int tid = threadIdx.x;
  int outBS = 2 * O * NN;
  if (o >= O) {
    int c = o - O;
    for (int i = tid; i < BB * NN; i += 256) {
      int b = i >> 11, n = i & (NN - 1);
      out[(size_t)b * outBS + o * NN + n] = xin[(size_t)b * xbs + c * NN + n];
    }
    return;
  }
  __shared__ float s1[256], s2[256];
  __shared__ float smv, srv;
  float a1 = 0.f, a2 = 0.f;
  for (int i = tid; i < BB * NN; i += 256) {
    int b = i >> 11, n = i & (NN - 1);
    float v = z[((size_t)b * O + o) * NN + n];
    a1 += v; a2 += v * v;
  }
  s1[tid] = a1; s2[tid] = a2;
  __syncthreads();
  for (int st = 128; st > 0; st >>= 1) {
    if (tid < st) { s1[tid] += s1[tid + st]; s2[tid] += s2[tid + st]; }
    __syncthreads();
  }
  if (tid == 0) {
    float m = s1[0] / (BB * NN);
    float var = s2[0] / (BB * NN) - m * m;
    smv = m; srv = rsqrtf(var + 1e-5f);
  }
  __syncthreads();
  float m = smv, r = srv;
  for (int i = tid; i < BB * NN; i += 256) {
    int b = i >> 11, n = i & (NN - 1);
    float v = (z[((size_t)b * O + o) * NN + n] - m) * r;
    out[(size_t)b * outBS + o * NN + n] = v >= 0.f ? v : 0.2f * v;
  }
}

// ---------------------------------------------------------------- fused BN+LReLU+max/mean pool (conv5)
__global__ __launch_bounds__(256) void bn_pool_kernel(const float* __restrict__ z,
                                                      float* __restrict__ p) {
  int o = blockIdx.x;
  int tid = threadIdx.x;
  __shared__ float s1[256], s2[256];
  __shared__ float smv, srv;
  float a1 = 0.f, a2 = 0.f;
  for (int i = tid; i < BB * NN; i += 256) {
    int b = i >> 11, n = i & (NN - 1);
    float v = z[((size_t)b * 1024 + o) * NN + n];
    a1 += v; a2 += v * v;
  }
  s1[tid] = a1; s2[tid] = a2;
  __syncthreads();
  for (int st = 128; st > 0; st >>= 1) {
    if (tid < st) { s1[tid] += s1[tid + st]; s2[tid] += s2[tid + st]; }
    __syncthreads();
  }
  if (tid == 0) {
    float m = s1[0] / (BB * NN);
    float var = s2[0] / (BB * NN) - m * m;
    smv = m; srv = rsqrtf(var + 1e-5f);
  }
  __syncthreads();
  float m = smv, r = srv;
  int b = tid >> 5, l = tid & 31;
  const float* zp = z + ((size_t)b * 1024 + o) * NN;
  float mx = -INFINITY, sm = 0.f;
  for (int n = l; n < NN; n += 32) {
    float v = (zp[n] - m) * r;
    v = v >= 0.f ? v : 0.2f * v;
    mx = fmaxf(mx, v); sm += v;
  }
#pragma unroll
  for (int s = 16; s > 0; s >>= 1) {
    mx = fmaxf(mx, __shfl_xor(mx, s));
    sm += __shfl_xor(sm, s);
  }
  if (l == 0) {
    p[b * 2048 + o] = mx;
    p[b * 2048 + 1024 + o] = sm * (1.f / NN);
  }
}

__global__ __launch_bounds__(64) void linear_kernel(const float* __restrict__ in, int IN, int OUT,
                                                    const float* __restrict__ w,
                                                    const float* __restrict__ bias,
                                                    float* __restrict__ out) {
  int o = blockIdx.x;
  int b = o / OUT, f = o % OUT;
  const float* ip = in + (size_t)b * IN;
  const float* wp = w + (size_t)f * IN;
  float a = 0.f;
  for (int i = threadIdx.x; i < IN; i += 64) a += ip[i] * wp[i];
#pragma unroll
  for (int s = 32; s > 0; s >>= 1) a += __shfl_down(a, s);
  if (threadIdx.x == 0) out[o] = a + bias[f];
}

__global__ __launch_bounds__(256) void bnf_kernel(float* __restrict__ t, int F) {
  int f = blockIdx.x * blockDim.x + threadIdx.x;
  if (f >= F) return;
  float s = 0.f, s2 = 0.f;
  for (int b = 0; b < BB; ++b) { float v = t[b * F + f]; s += v; s2 += v * v; }
  float m = s * (1.f / BB);
  float var = s2 * (1.f / BB) - m * m;
  float r = rsqrtf(var + 1e-5f);
  for (int b = 0; b < BB; ++b) {
    float v = (t[b * F + f] - m) * r;
    t[b * F + f] = v >= 0.f ? v : 0.2f * v;
  }
}

// ---------------------------------------------------------------- host side

struct SAW { const float *wq, *wk, *wv, *wc; };

static inline void run_conv(const float* in, int inBS, int C, int O, const float* w,
                            float* z, hipStream_t st) {
  if (O % 128 == 0)
    conv_gemm128_db_kernel<<<dim3(NN / 128, O / 128, BB), 256, 0, st>>>(in, inBS, C, O, w, z);
  else
    conv_gemm_kernel<<<dim3(NN / 64, (O + 63) / 64, BB), 256, 0, st>>>(in, inBS, C, O, w, z);
}

// MFMA==true only valid for C multiple of 128.
template <int C, bool MFMA>
static inline void run_sa(const float* xin, int xbs, SAW w,
                          float* xT, float* U, float* UT, float* AGGt,
                          float* AGG, float* z, float* h, float* sq, int* idx,
                          float* M, float* WCV, unsigned short* Mb, unsigned short* wcvb,
                          unsigned short* xTb, unsigned short* AGGtb,
                          float* D, int nbatch, hipStream_t st) {
  sq_kernel<<<BB * NN / 256, 256, 0, st>>>(xin, xbs, C, sq);
  transpose_kernel<<<dim3(NN / 32, (C + 31) / 32, BB), 256, 0, st>>>(xin, xbs, C, NN, xT);
  mprep_kernel<<<(C * C + 255) / 256, 256, 0, st>>>(w.wq, w.wk, C, M);
  wcv_kernel<<<(C * C + 255) / 256, 256, 0, st>>>(w.wc, w.wv, C, WCV);
  if (MFMA) {
    convert_bf16_kernel<<<(C * C + 255) / 256, 256, 0, st>>>(M, Mb, C * C);
    convert_bf16_kernel<<<(C * C + 255) / 256, 256, 0, st>>>(WCV, wcvb, C * C);
    transpose_bf16_kernel<<<dim3(NN / 32, (C + 31) / 32, BB), 256, 0, st>>>(xin, xbs, C, NN, xTb);
  }
  for (int bb = 0; bb < BB; bb += nbatch) {
    int nbc = (BB - bb) < nbatch ? (BB - bb) : nbatch;
    pd_gemm128_db_kernel<<<dim3(NN / 128, NN / 128, nbc), 256, 0, st>>>(xin, xbs, C, sq, D, bb);
    topk2_kernel<<<dim3(NN / 2, nbc), 64, 0, st>>>(D, idx, bb);
  }
  if (MFMA)
    mfma_gemm_lds_kernel<<<dim3(NN / 128, C / 128, BB), 256, 0, st>>>(Mb, xTb, U, C, C);
  else
    run_conv(xin, xbs, C, C, M, U, st);                            // U = M . x  [C][N]
  transpose_kernel<<<dim3(NN / 32, (C + 31) / 32, BB), 256, 0, st>>>(U, C * NN, C, NN, UT);
  att_wave_kernel<C><<<BB * NN, 64, 0, st>>>(xT, UT, idx, AGGt);   // AGGt [N][C]
  if (MFMA) {
    convert_bf16_kernel<<<(BB * NN * C + 255) / 256, 256, 0, st>>>(AGGt, AGGtb, BB * NN * C);
    mfma_gemm_lds_kernel<<<dim3(NN / 128, C / 128, BB), 256, 0, st>>>(wcvb, AGGtb, z, C, C);
  } else {
    transpose_kernel<<<dim3((C + 31) / 32, NN / 32, BB), 256, 0, st>>>(AGGt, NN * C, NN, C, AGG);
    run_conv(AGG, C * NN, C, C, WCV, z, st);                       // Z = (wc.wv) . AGG
  }
  bn_copy_kernel<<<2 * C, 256, 0, st>>>(z, C, xin, xbs, h);
}

static inline void run_conv_bn(const float* in, int inBS, int Cin, int O, const float* w,
                               float* z, float* out, int outBS, int c0, hipStream_t st) {
  run_conv(in, inBS, Cin, O, w, z, st);
  bn_fused_kernel<<<O, 256, 0, st>>>(z, O, out, outBS, c0);
}

extern "C" void kernel_launch(void* const* d_in, const int* in_sizes, int n_in,
                              void* d_out, int out_size, void* d_ws, size_t ws_size,
                              hipStream_t stream) {
  const float* x = (const float*)d_in[0];
  SAW sa1{(const float*)d_in[1], (const float*)d_in[2], (const float*)d_in[3], (const float*)d_in[4]};
  SAW sa2{(const float*)d_in[5], (const float*)d_in[6], (const float*)d_in[7], (const float*)d_in[8]};
  SAW sa3{(const float*)d_in[9], (const float*)d_in[10], (const float*)d_in[11], (const float*)d_in[12]};
  SAW sa4{(const float*)d_in[13], (const float*)d_in[14], (const float*)d_in[15], (const float*)d_in[16]};
  const float* conv1_w = (const float*)d_in[17];
  const float* conv2_w = (const float*)d_in[18];
  const float* conv3_w = (const float*)d_in[19];
  const float* conv4_w = (const float*)d_in[20];
  const float* conv5_w = (const float*)d_in[21];
  const float* lin1_w = (const float*)d_in[22];
  const float* lin1_b = (const float*)d_in[23];
  const float* lin2_w = (const float*)d_in[24];
  const float* lin2_b = (const float*)d_in[25];
  const float* lin3_w = (const float*)d_in[26];
  const float* lin3_b = (const float*)d_in[27];

  char* ws = (char*)d_ws;
  size_t off = 0;
  auto take = [&](size_t bytes) -> void* {
    void* p = ws + off;
    off += (bytes + 255) & ~(size_t)255;
    return p;
  };
  float* sq   = (float*)take((size_t)BB * NN * 4);
  int*   idx  = (int*)take((size_t)BB * NN * KNB * 4);
  float* M    = (float*)take((size_t)128 * 128 * 4);
  float* WCV  = (float*)take((size_t)128 * 128 * 4);
  unsigned short* Mb   = (unsigned short*)take((size_t)128 * 128 * 2);
  unsigned short* wcvb = (unsigned short*)take((size_t)128 * 128 * 2);
  unsigned short* w4b  = (unsigned short*)take((size_t)256 * 256 * 2);
  unsigned short* w5b  = (unsigned short*)take((size_t)1024 * 512 * 2);
  float* U    = (float*)take((size_t)BB * 128 * NN * 4);  // contiguous with AGG
  float* AGG  = (float*)take((size_t)BB * 128 * NN * 4);  // also hosts xT
  float* h    = (float*)take((size_t)BB * 256 * NN * 4);  // first half hosts UT
  float* z    = (float*)take((size_t)BB * 1024 * NN * 4); // hosts AGGt, AGGtb(+16MB), D-chunks
  float* xc   = (float*)take((size_t)BB * 512 * NN * 4);
  float* p    = (float*)take((size_t)BB * 2048 * 4);
  float* t1   = (float*)take((size_t)BB * 512 * 4);
  float* t2   = (float*)take((size_t)BB * 256 * 4);
  (void)n_in; (void)in_sizes; (void)out_size;

  // Overlays (phase-ordered lifetimes):
  float* xT = AGG;                                          // dead before AGG written
  float* UT = h;                                            // consumed before h written
  float* AGGt = z;                                          // first 8.4 MB of z
  unsigned short* xTb   = (unsigned short*)((char*)h + (size_t)BB * 128 * NN * 4);  // h 2nd half
  unsigned short* AGGtb = (unsigned short*)((char*)z + (size_t)16 * 1024 * 1024);   // z + 16 MB
  unsigned short* hTb   = (unsigned short*)U;               // conv4 phase (U dead)
  unsigned short* xcTb  = (unsigned short*)U;               // conv5 phase (U+AGG dead, 16.8 MB)

  size_t dfull = (size_t)BB * NN * NN * 4;
  bool fullD = (ws_size > off + dfull + 4096);
  float* D = fullD ? (float*)take(dfull) : z;               // !fullD: 4-batch chunks fill z exactly
  int nbatch = fullD ? BB : 4;

  // SA1 (C=3) -> h [B,6,N]
  run_sa<3, false>(x, 3 * NN, sa1, xT, U, UT, AGGt, AGG, z, h, sq, idx,
                   M, WCV, Mb, wcvb, xTb, AGGtb, D, nbatch, stream);
  run_conv_bn(h, 6 * NN, 6, 64, conv1_w, z, xc, 512 * NN, 0, stream);
  // SA2 (C=64) on x1
  run_sa<64, false>(xc + 0 * NN, 512 * NN, sa2, xT, U, UT, AGGt, AGG, z, h, sq, idx,
                    M, WCV, Mb, wcvb, xTb, AGGtb, D, nbatch, stream);
  run_conv_bn(h, 128 * NN, 128, 64, conv2_w, z, xc, 512 * NN, 64, stream);
  // SA3 (C=64) on x2
  run_sa<64, false>(xc + 64 * NN, 512 * NN, sa3, xT, U, UT, AGGt, AGG, z, h, sq, idx,
                    M, WCV, Mb, wcvb, xTb, AGGtb, D, nbatch, stream);
  run_conv_bn(h, 128 * NN, 128, 128, conv3_w, z, xc, 512 * NN, 128, stream);
  // SA4 (C=128) on x3 — bf16 MFMA for U and Z convs (no kNN downstream)
  run_sa<128, true>(xc + 128 * NN, 512 * NN, sa4, xT, U, UT, AGGt, AGG, z, h, sq, idx,
                    M, WCV, Mb, wcvb, xTb, AGGtb, D, nbatch, stream);
  // conv4 (bf16 MFMA): h [B,256,N] -> z [B,256,N]
  transpose_bf16_kernel<<<dim3(NN / 32, 8, BB), 256, 0, stream>>>(h, 256 * NN, 256, NN, hTb);
  convert_bf16_kernel<<<(256 * 256 + 255) / 256, 256, 0, stream>>>(conv4_w, w4b, 256 * 256);
  mfma_gemm_lds_kernel<<<dim3(NN / 128, 2, BB), 256, 0, stream>>>(w4b, hTb, z, 256, 256);
  bn_fused_kernel<<<256, 256, 0, stream>>>(z, 256, xc, 512 * NN, 256);
  // conv5 (bf16 MFMA): xc [B,512,N] -> z [B,1024,N]; BN+LReLU+pool -> p
  transpose_bf16_kernel<<<dim3(NN / 32, 16, BB), 256, 0, stream>>>(xc, 512 * NN, 512, NN, xcTb);
  convert_bf16_kernel<<<(1024 * 512 + 255) / 256, 256, 0, stream>>>(conv5_w, w5b, 1024 * 512);
  mfma_gemm_lds_kernel<<<dim3(NN / 128, 8, BB), 256, 0, stream>>>(w5b, xcTb, z, 1024, 512);
  bn_pool_kernel<<<1024, 256, 0, stream>>>(z, p);
  // FC head
  linear_kernel<<<BB * 512, 64, 0, stream>>>(p, 2048, 512, lin1_w, lin1_b, t1);
  bnf_kernel<<<2, 256, 0, stream>>>(t1, 512);
  linear_kernel<<<BB * 256, 64, 0, stream>>>(t1, 512, 256, lin2_w, lin2_b, t2);
  bnf_kernel<<<1, 256, 0, stream>>>(t2, 256);
  linear_kernel<<<BB * 40, 64, 0, stream>>>(t2, 256, 40, lin3_w, lin3_b, (float*)d_out);
}

// Round 12
// 1648.077 us; speedup vs baseline: 1.1592x; 1.0593x over previous
//
#include <hip/hip_runtime.h>
#include <math.h>

#define BB 8
#define NN 2048
#define KNB 20

typedef __attribute__((ext_vector_type(8))) short bf16x8;
typedef __attribute__((ext_vector_type(4))) float f32x4;

__device__ inline unsigned short f2bf(float f) {
  union { float f; unsigned u; } v; v.f = f;
  unsigned r = v.u + 0x7FFF + ((v.u >> 16) & 1);  // RNE
  return (unsigned short)(r >> 16);
}

// ---------------------------------------------------------------- sq
__global__ __launch_bounds__(256) void sq_kernel(const float* __restrict__ x, int bs, int C,
                                                 float* __restrict__ sq) {
  int t = blockIdx.x * blockDim.x + threadIdx.x;
  int b = t / NN, n = t % NN;
  const float* xp = x + (size_t)b * bs + n;
  float s = 0.f;
  for (int c = 0; c < C; ++c) { float v = xp[c * NN]; s += v * v; }
  sq[t] = s;
}

// ---------------------------------------------------------------- M = wk^T wq
__global__ __launch_bounds__(256) void mprep_kernel(const float* __restrict__ wq,
                                                    const float* __restrict__ wk, int C,
                                                    float* __restrict__ M) {
  int T = blockIdx.x * 256 + threadIdx.x;
  if (T >= C * C) return;
  int c = T / C, cp = T % C;
  float a = 0.f;
  for (int e = 0; e < C; ++e) a += wk[e * C + c] * wq[e * C + cp];
  M[c * C + cp] = a;
}

// ---------------------------------------------------------------- wcv = wc @ wv
__global__ __launch_bounds__(256) void wcv_kernel(const float* __restrict__ wc,
                                                  const float* __restrict__ wv, int C,
                                                  float* __restrict__ out) {
  int T = blockIdx.x * 256 + threadIdx.x;
  if (T >= C * C) return;
  int o = T / C, c = T % C;
  float a = 0.f;
  for (int e = 0; e < C; ++e) a += wc[o * C + e] * wv[e * C + c];
  out[o * C + c] = a;
}

// ---------------------------------------------------------------- converts
__global__ __launch_bounds__(256) void convert_bf16_kernel(const float* __restrict__ in,
                                                           unsigned short* __restrict__ out,
                                                           int count) {
  int i = blockIdx.x * 256 + threadIdx.x;
  if (i < count) out[i] = f2bf(in[i]);
}

// ---------------------------------------------------------------- transpose (fp32)
__global__ __launch_bounds__(256) void transpose_kernel(const float* __restrict__ in, int inBS,
                                                        int R, int Cl, float* __restrict__ out) {
  __shared__ float tile[32][33];
  int b = blockIdx.z;
  const float* ip = in + (size_t)b * inBS;
  float* op = out + (size_t)b * R * Cl;
  int c0 = blockIdx.x * 32, r0 = blockIdx.y * 32;
  int tx = threadIdx.x & 31, ty = threadIdx.x >> 5;
  for (int yy = ty; yy < 32; yy += 8) {
    int r = r0 + yy, c = c0 + tx;
    tile[yy][tx] = (r < R && c < Cl) ? ip[(size_t)r * Cl + c] : 0.f;
  }
  __syncthreads();
  for (int yy = ty; yy < 32; yy += 8) {
    int c = c0 + yy, r = r0 + tx;
    if (c < Cl && r < R) op[(size_t)c * R + r] = tile[tx][yy];
  }
}

// ---------------------------------------------------------------- transpose + bf16 convert
__global__ __launch_bounds__(256) void transpose_bf16_kernel(const float* __restrict__ in, int inBS,
                                                             int R, int Cl,
                                                             unsigned short* __restrict__ out) {
  __shared__ float tile[32][33];
  int b = blockIdx.z;
  const float* ip = in + (size_t)b * inBS;
  unsigned short* op = out + (size_t)b * R * Cl;
  int c0 = blockIdx.x * 32, r0 = blockIdx.y * 32;
  int tx = threadIdx.x & 31, ty = threadIdx.x >> 5;
  for (int yy = ty; yy < 32; yy += 8) {
    int r = r0 + yy, c = c0 + tx;
    tile[yy][tx] = (r < R && c < Cl) ? ip[(size_t)r * Cl + c] : 0.f;
  }
  __syncthreads();
  for (int yy = ty; yy < 32; yy += 8) {
    int c = c0 + yy, r = r0 + tx;
    if (c < Cl && r < R) op[(size_t)c * R + r] = f2bf(tile[tx][yy]);
  }
}

// ---------------------------------------------------------------- MFMA GEMM, LDS double-buffered
// Z[b][o][n] = sum_k A[o][k] * B[b][n][k]; A,B bf16 K-contiguous, Z fp32.
__global__ __launch_bounds__(256, 2) void mfma_gemm_lds_kernel(
    const unsigned short* __restrict__ A, const unsigned short* __restrict__ B,
    float* __restrict__ Z, int O, int K) {
  const int b = blockIdx.z;
  const int n0 = blockIdx.x * 128, o0 = blockIdx.y * 128;
  const int tid = threadIdx.x;
  const int wave = tid >> 6, lane = tid & 63;
  const int wo = wave >> 1, wn = wave & 1;   // 64x64 quadrant per wave
  const int l16 = lane & 15, q = lane >> 4;
  __shared__ unsigned short Al[2][4096];     // 128 rows x 32 k (8 KB), frag order
  __shared__ unsigned short Bl[2][4096];
  const unsigned short* Ab = A + (size_t)o0 * K;
  const unsigned short* Bb = B + ((size_t)b * NN + n0) * K;

  const int p0 = tid, p1 = tid + 256;
  const int r0 = ((p0 >> 6) << 4) | (p0 & 15), c0 = ((p0 >> 4) & 3) * 8;
  const int r1 = ((p1 >> 6) << 4) | (p1 & 15), c1 = ((p1 >> 4) & 3) * 8;

  bf16x8 ar0, ar1, br0, br1;
  auto gload = [&](int k0) {
    ar0 = *(const bf16x8*)(Ab + (size_t)r0 * K + k0 + c0);
    ar1 = *(const bf16x8*)(Ab + (size_t)r1 * K + k0 + c1);
    br0 = *(const bf16x8*)(Bb + (size_t)r0 * K + k0 + c0);
    br1 = *(const bf16x8*)(Bb + (size_t)r1 * K + k0 + c1);
  };
  auto sstore = [&](int buf) {
    *(bf16x8*)&Al[buf][p0 * 8] = ar0;
    *(bf16x8*)&Al[buf][p1 * 8] = ar1;
    *(bf16x8*)&Bl[buf][p0 * 8] = br0;
    *(bf16x8*)&Bl[buf][p1 * 8] = br1;
  };

  f32x4 acc[4][4];
#pragma unroll
  for (int s = 0; s < 4; ++s)
#pragma unroll
    for (int t = 0; t < 4; ++t) acc[s][t] = (f32x4){0.f, 0.f, 0.f, 0.f};

  gload(0);
  sstore(0);
  int cur = 0;
  for (int k0 = 0; k0 < K; k0 += 32) {
    bool more = (k0 + 32) < K;
    if (more) gload(k0 + 32);
    __syncthreads();
    bf16x8 af[4], bfr[4];
#pragma unroll
    for (int s = 0; s < 4; ++s)
      af[s] = *(const bf16x8*)&Al[cur][((wo * 4 + s) * 64 + q * 16 + l16) * 8];
#pragma unroll
    for (int t = 0; t < 4; ++t)
      bfr[t] = *(const bf16x8*)&Bl[cur][((wn * 4 + t) * 64 + q * 16 + l16) * 8];
#pragma unroll
    for (int s = 0; s < 4; ++s)
#pragma unroll
      for (int t = 0; t < 4; ++t)
        acc[s][t] = __builtin_amdgcn_mfma_f32_16x16x32_bf16(af[s], bfr[t], acc[s][t], 0, 0, 0);
    if (more) sstore(cur ^ 1);
    cur ^= 1;
  }
#pragma unroll
  for (int s = 0; s < 4; ++s)
#pragma unroll
    for (int t = 0; t < 4; ++t) {
      float* zp = Z + ((size_t)b * O + o0 + wo * 64 + s * 16 + q * 4) * NN
                  + n0 + wn * 64 + t * 16 + l16;
#pragma unroll
      for (int r = 0; r < 4; ++r) zp[(size_t)r * NN] = acc[s][t][r];
    }
}

// ---------------------------------------------------------------- pd GEMM 128-tile, double-buffered
// Full matrix (r10's symmetric variant regressed: +17KB LDS -> 1 block/CU).
// __launch_bounds__(256,2): (256,3) capped VGPR at 84 and spilled (r6).
__global__ __launch_bounds__(256, 2) void pd_gemm128_db_kernel(
    const float* __restrict__ x, int bs, int C, const float* __restrict__ sq,
    float* __restrict__ P, int b_base) {
  const int b = b_base + blockIdx.z;
  const int n0 = blockIdx.x * 128, m0 = blockIdx.y * 128;
  const int tid = threadIdx.x;
  const int tm = tid & 15, tn = tid >> 4;
  __shared__ float As[2][16][128], Bs[2][16][128];
  const float* xb = x + (size_t)b * bs;
  float acc[8][8];
#pragma unroll
  for (int i = 0; i < 8; ++i)
#pragma unroll
    for (int j = 0; j < 8; ++j) acc[i][j] = 0.f;

  float4 ara[2], arb[2];
  auto load_tile = [&](int k0) {
#pragma unroll
    for (int it = 0; it < 2; ++it) {
      int i = it * 256 + tid;
      int kc = i >> 5, c4 = i & 31;
      bool ok = (k0 + kc) < C;
      ara[it] = ok ? *(const float4*)&xb[(size_t)(k0 + kc) * NN + n0 + c4 * 4]
                   : make_float4(0.f, 0.f, 0.f, 0.f);
      arb[it] = ok ? *(const float4*)&xb[(size_t)(k0 + kc) * NN + m0 + c4 * 4]
                   : make_float4(0.f, 0.f, 0.f, 0.f);
    }
  };
  auto store_tile = [&](int buf) {
#pragma unroll
    for (int it = 0; it < 2; ++it) {
      int i = it * 256 + tid;
      int kc = i >> 5, c4 = i & 31;
      *(float4*)&As[buf][kc][c4 * 4] = ara[it];
      *(float4*)&Bs[buf][kc][c4 * 4] = arb[it];
    }
  };

  load_tile(0);
  store_tile(0);
  int cur = 0;
  for (int k0 = 0; k0 < C; k0 += 16) {
    bool more = (k0 + 16) < C;
    if (more) load_tile(k0 + 16);
    __syncthreads();
#pragma unroll
    for (int kc = 0; kc < 16; ++kc) {
      float4 a0 = *(const float4*)&As[cur][kc][tn * 4];
      float4 a1 = *(const float4*)&As[cur][kc][64 + tn * 4];
      float4 b0 = *(const float4*)&Bs[cur][kc][tm * 4];
      float4 b1 = *(const float4*)&Bs[cur][kc][64 + tm * 4];
      float ar[8] = {a0.x, a0.y, a0.z, a0.w, a1.x, a1.y, a1.z, a1.w};
      float br[8] = {b0.x, b0.y, b0.z, b0.w, b1.x, b1.y, b1.z, b1.w};
#pragma unroll
      for (int i = 0; i < 8; ++i)
#pragma unroll
        for (int j = 0; j < 8; ++j) acc[i][j] += ar[i] * br[j];
    }
    if (more) store_tile(cur ^ 1);
    cur ^= 1;
  }
  float4 sqa = *(const float4*)&sq[b * NN + m0 + tm * 4];
  float4 sqb = *(const float4*)&sq[b * NN + m0 + 64 + tm * 4];
#pragma unroll
  for (int h = 0; h < 2; ++h)
#pragma unroll
    for (int i = 0; i < 4; ++i) {
      int r = h * 4 + i;
      int nn = n0 + h * 64 + tn * 4 + i;
      float* prow = &P[((size_t)blockIdx.z * NN + nn) * NN + m0];
      float4 o0, o1;
      o0.x = 2.f * acc[r][0] - sqa.x; o0.y = 2.f * acc[r][1] - sqa.y;
      o0.z = 2.f * acc[r][2] - sqa.z; o0.w = 2.f * acc[r][3] - sqa.w;
      o1.x = 2.f * acc[r][4] - sqb.x; o1.y = 2.f * acc[r][5] - sqb.y;
      o1.z = 2.f * acc[r][6] - sqb.z; o1.w = 2.f * acc[r][7] - sqb.w;
      *(float4*)&prow[tm * 4] = o0;
      *(float4*)&prow[64 + tm * 4] = o1;
    }
}

// ---------------------------------------------------------------- top-20: 4 waves/block, 1 row/wave
// r11 showed 64-thr blocks cap at ~16 waves/CU (occupancy 30%, VALUBusy 57%) —
// the serial argmax's shuffle chains need more co-resident waves. 256-thr
// blocks give up to 32 waves/CU. Per-wave loop = r9's proven 1-row body
// (2-row ILP variant was NOT better per-row: 9.9 vs 9.1 ns).
__global__ __launch_bounds__(256) void topk4_kernel(const float* __restrict__ P,
                                                    int* __restrict__ idx, int b_base) {
  const int wave = threadIdx.x >> 6;
  const int lane = threadIdx.x & 63;
  const int n = blockIdx.x * 4 + wave;
  const int bl = blockIdx.y;
  const int b = b_base + bl;
  const float* row = P + ((size_t)bl * NN + n) * NN;
  const float4* rp = (const float4*)row;
  float v[32];
#pragma unroll
  for (int qq = 0; qq < 8; ++qq) {
    float4 vv = rp[qq * 64 + lane];
    int mb = qq * 256 + lane * 4;
    v[qq * 4 + 0] = (mb + 0 == n) ? -INFINITY : vv.x;
    v[qq * 4 + 1] = (mb + 1 == n) ? -INFINITY : vv.y;
    v[qq * 4 + 2] = (mb + 2 == n) ? -INFINITY : vv.z;
    v[qq * 4 + 3] = (mb + 3 == n) ? -INFINITY : vv.w;
  }
  int* op = idx + (size_t)(b * NN + n) * KNB;
  for (int k = 0; k < KNB; ++k) {
    float bv = v[0]; int bj = 0;
#pragma unroll
    for (int j = 1; j < 32; ++j)
      if (v[j] > bv) { bv = v[j]; bj = j; }
    int bm = (bj >> 2) * 256 + lane * 4 + (bj & 3);
#pragma unroll
    for (int s = 32; s > 0; s >>= 1) {
      float ov = __shfl_down(bv, s);
      int om = __shfl_down(bm, s);
      if (ov > bv) { bv = ov; bm = om; }
    }
    bm = __shfl(bm, 0);
    if (lane == 0) op[k] = bm;
    if (((bm >> 2) & 63) == lane) {
      int jj = ((bm >> 8) << 2) | (bm & 3);
#pragma unroll
      for (int j = 0; j < 32; ++j)
        if (j == jj) v[j] = -INFINITY;
    }
  }
}

// ---------------------------------------------------------------- conv GEMM 64-tile (small O)
__global__ __launch_bounds__(256, 2) void conv_gemm_kernel(
    const float* __restrict__ in, int inBS, int C, int O,
    const float* __restrict__ w, float* __restrict__ z) {
  const int b = blockIdx.z;
  const int n0 = blockIdx.x * 64, o0 = blockIdx.y * 64;
  const int tid = threadIdx.x;
  const int tm = tid & 15, tn = tid >> 4;
  __shared__ float Ws[16][68];
  __shared__ float Xs[16][64];
  const float* ib = in + (size_t)b * inBS;
  float acc[4][4];
#pragma unroll
  for (int i = 0; i < 4; ++i)
#pragma unroll
    for (int j = 0; j < 4; ++j) acc[i][j] = 0.f;

  for (int k0 = 0; k0 < C; k0 += 16) {
    __syncthreads();
#pragma unroll
    for (int it = 0; it < 4; ++it) {
      int i = it * 256 + tid;
      int kc = i >> 6, nl = i & 63;
      Xs[kc][nl] = ((k0 + kc) < C) ? ib[(size_t)(k0 + kc) * NN + n0 + nl] : 0.f;
      int ol = i >> 4, kc2 = i & 15;
      Ws[kc2][ol] = ((o0 + ol) < O && (k0 + kc2) < C) ? w[(size_t)(o0 + ol) * C + k0 + kc2] : 0.f;
    }
    __syncthreads();
#pragma unroll
    for (int kc = 0; kc < 16; ++kc) {
      float4 a = *(const float4*)&Ws[kc][tn * 4];
      float4 bv = *(const float4*)&Xs[kc][tm * 4];
      acc[0][0] += a.x * bv.x; acc[0][1] += a.x * bv.y; acc[0][2] += a.x * bv.z; acc[0][3] += a.x * bv.w;
      acc[1][0] += a.y * bv.x; acc[1][1] += a.y * bv.y; acc[1][2] += a.y * bv.z; acc[1][3] += a.y * bv.w;
      acc[2][0] += a.z * bv.x; acc[2][1] += a.z * bv.y; acc[2][2] += a.z * bv.z; acc[2][3] += a.z * bv.w;
      acc[3][0] += a.w * bv.x; acc[3][1] += a.w * bv.y; acc[3][2] += a.w * bv.z; acc[3][3] += a.w * bv.w;
    }
  }
#pragma unroll
  for (int i = 0; i < 4; ++i) {
    int o = o0 + tn * 4 + i;
    if (o < O) {
      float4 ov;
      ov.x = acc[i][0]; ov.y = acc[i][1]; ov.z = acc[i][2]; ov.w = acc[i][3];
      *(float4*)&z[((size_t)b * O + o) * NN + n0 + tm * 4] = ov;
    }
  }
}

// ---------------------------------------------------------------- conv GEMM 128-tile, double-buffered (fp32)
__global__ __launch_bounds__(256, 2) void conv_gemm128_db_kernel(
    const float* __restrict__ in, int inBS, int C, int O,
    const float* __restrict__ w, float* __restrict__ z) {
  const int b = blockIdx.z;
  const int n0 = blockIdx.x * 128, o0 = blockIdx.y * 128;
  const int tid = threadIdx.x;
  const int tm = tid & 15, tn = tid >> 4;
  __shared__ float Xs[2][16][128];
  __shared__ float Ws[2][16][132];
  const float* ib = in + (size_t)b * inBS;
  float acc[8][8];
#pragma unroll
  for (int i = 0; i < 8; ++i)
#pragma unroll
    for (int j = 0; j < 8; ++j) acc[i][j] = 0.f;

  float4 xr[2], wr[2];
  auto load_tile = [&](int k0) {
#pragma unroll
    for (int it = 0; it < 2; ++it) {
      int i = it * 256 + tid;
      int kc = i >> 5, c4 = i & 31;
      xr[it] = ((k0 + kc) < C) ? *(const float4*)&ib[(size_t)(k0 + kc) * NN + n0 + c4 * 4]
                               : make_float4(0.f, 0.f, 0.f, 0.f);
      int ol = i >> 2, kq = i & 3;
      wr[it] = ((k0 + kq * 4) < C) ? *(const float4*)&w[(size_t)(o0 + ol) * C + k0 + kq * 4]
                                   : make_float4(0.f, 0.f, 0.f, 0.f);
    }
  };
  auto store_tile = [&](int buf) {
#pragma unroll
    for (int it = 0; it < 2; ++it) {
      int i = it * 256 + tid;
      int kc = i >> 5, c4 = i & 31;
      *(float4*)&Xs[buf][kc][c4 * 4] = xr[it];
      int ol = i >> 2, kq = i & 3;
      Ws[buf][kq * 4 + 0][ol] = wr[it].x;
      Ws[buf][kq * 4 + 1][ol] = wr[it].y;
      Ws[buf][kq * 4 + 2][ol] = wr[it].z;
      Ws[buf][kq * 4 + 3][ol] = wr[it].w;
    }
  };

  load_tile(0);
  store_tile(0);
  int cur = 0;
  for (int k0 = 0; k0 < C; k0 += 16) {
    bool more = (k0 + 16) < C;
    if (more) load_tile(k0 + 16);
    __syncthreads();
#pragma unroll
    for (int kc = 0; kc < 16; ++kc) {
      float4 a0 = *(const float4*)&Ws[cur][kc][tn * 4];
      float4 a1 = *(const float4*)&Ws[cur][kc][64 + tn * 4];
      float4 b0 = *(const float4*)&Xs[cur][kc][tm * 4];
      float4 b1 = *(const float4*)&Xs[cur][kc][64 + tm * 4];
      float ar[8] = {a0.x, a0.y, a0.z, a0.w, a1.x, a1.y, a1.z, a1.w};
      float br[8] = {b0.x, b0.y, b0.z, b0.w, b1.x, b1.y, b1.z, b1.w};
#pragma unroll
      for (int i = 0; i < 8; ++i)
#pragma unroll
        for (int j = 0; j < 8; ++j) acc[i][j] += ar[i] * br[j];
    }
    if (more) store_tile(cur ^ 1);
    cur ^= 1;
  }
#pragma unroll
  for (int h = 0; h < 2; ++h)
#pragma unroll
    for (int i = 0; i < 4; ++i) {
      int r = h * 4 + i;
      int o = o0 + h * 64 + tn * 4 + i;
      float* zrow = &z[((size_t)b * O + o) * NN + n0];
      float4 o0v, o1v;
      o0v.x = acc[r][0]; o0v.y = acc[r][1]; o0v.z = acc[r][2]; o0v.w = acc[r][3];
      o1v.x = acc[r][4]; o1v.y = acc[r][5]; o1v.z = acc[r][6]; o1v.w = acc[r][7];
      *(float4*)&zrow[tm * 4] = o0v;
      *(float4*)&zrow[64 + tm * 4] = o1v;
    }
}

// ---------------------------------------------------------------- attention (wave/point)
template <int C>
__global__ __launch_bounds__(64) void att_wave_kernel(
    const float* __restrict__ xT, const float* __restrict__ UT,
    const int* __restrict__ idx, float* __restrict__ AGGt) {
  const int n = blockIdx.x & (NN - 1);
  const int b = blockIdx.x >> 11;
  const int lane = threadIdx.x;
  constexpr int CP = C + 1;
  __shared__ float nb[KNB][CP];
  __shared__ float sl[KNB];
  __shared__ int nidx[KNB];
  __shared__ float ul[C];
  const float* xTb = xT + (size_t)b * NN * C;
  if (lane < KNB) nidx[lane] = idx[(size_t)(b * NN + n) * KNB + lane];
  for (int c = lane; c < C; c += 64) ul[c] = UT[((size_t)b * NN + n) * C + c];
  __syncthreads();
  for (int i = lane; i < KNB * C; i += 64) {
    int k = i / C, c = i - k * C;
    nb[k][c] = xTb[(size_t)nidx[k] * C + c];
  }
  __syncthreads();
  float sv = -INFINITY;
  if (lane < KNB) {
    float a = 0.f;
#pragma unroll
    for (int c = 0; c < C; ++c) a += nb[lane][c] * ul[c];
    sv = a / sqrtf((float)C);
  }
  float mx = sv;
#pragma unroll
  for (int s = 32; s > 0; s >>= 1) mx = fmaxf(mx, __shfl_xor(mx, s));
  float e = (lane < KNB) ? expf(sv - mx) : 0.f;
  float sum = e;
#pragma unroll
  for (int s = 32; s > 0; s >>= 1) sum += __shfl_xor(sum, s);
  if (lane < KNB) sl[lane] = e / sum;
  __syncthreads();
  const float* xTn = xTb + (size_t)n * C;
  float* op = AGGt + ((size_t)b * NN + n) * C;
  for (int c = lane; c < C; c += 64) {
    float a = 0.f;
#pragma unroll
    for (int k = 0; k < KNB; ++k) a += sl[k] * nb[k][c];
    op[c] = a - xTn[c];
  }
}

// ---------------------------------------------------------------- fused BN (+LReLU)
__global__ __launch_bounds__(256) void bn_fused_kernel(const float* __restrict__ z, int O,
                                                       float* __restrict__ out, int outBS, int c0) {
  int o = blockIdx.x;
  int tid = threadIdx.x;
  __shared__ float s1[256], s2[256];
  __shared__ float smv, srv;
  float a1 = 0.f, a2 = 0.f;
  for (int i = tid; i < BB * NN; i += 256) {
    int b = i >> 11, n = i & (NN - 1);
    float v = z[((size_t)b * O + o) * NN + n];
    a1 += v; a2 += v * v;
  }
  s1[tid] = a1; s2[tid] = a2;
  __syncthreads();
  for (int st = 128; st > 0; st >>= 1) {
    if (tid < st) { s1[tid] += s1[tid + st]; s2[tid] += s2[tid + st]; }
    __syncthreads();
  }
  if (tid == 0) {
    float m = s1[0] / (BB * NN);
    float var = s2[0] / (BB * NN) - m * m;
    smv = m; srv = rsqrtf(var + 1e-5f);
  }
  __syncthreads();
  float m = smv, r = srv;
  for (int i = tid; i < BB * NN; i += 256) {
    int b = i >> 11, n = i & (NN - 1);
    float v = (z[((size_t)b * O + o) * NN + n] - m) * r;
    out[(size_t)b * outBS + (c0 + o) * NN + n] = v >= 0.f ? v : 0.2f * v;
  }
}

// ---------------------------------------------------------------- BN+LReLU into h[:,0:O,:], copy xin into h[:,O:2O,:]
__global__ __launch_bounds__(256) void bn_copy_kernel(const float* __restrict__ z, int O,
                                                      const float* __restrict__ xin, int xbs,
                                                      float* __restrict__ out) {
  int o = blockIdx.x;  // 0..2O-1
  int tid = threadIdx.x;
  int outBS = 2 * O * NN;
  if (o >= O) {
    int c = o - O;
    for (int i = tid; i < BB * NN; i += 256) {
      int b = i >> 11, n = i & (NN - 1);
      out[(size_t)b * outBS + o * NN + n] = xin[(size_t)b * xbs + c * NN + n];
    }
    return;
  }
  __shared__ float s1[256], s2[256];
  __shared__ float smv, srv;
  float a1 = 0.f, a2 = 0.f;
  for (int i = tid; i < BB * NN; i += 256) {
    int b = i >> 11, n = i & (NN - 1);
    float v = z[((size_t)b * O + o) * NN + n];
    a1 += v; a2 += v * v;
  }
  s1[tid] = a1; s2[tid] = a2;
  __syncthreads();
  for (int st = 128; st > 0; st >>= 1) {
    if (tid < st) { s1[tid] += s1[tid + st]; s2[tid] += s2[tid + st]; }
    __syncthreads();
  }
  if (tid == 0) {
    float m = s1[0] / (BB * NN);
    float var = s2[0] / (BB * NN) - m * m;
    smv = m; srv = rsqrtf(var + 1e-5f);
  }
  __syncthreads();
  float m = smv, r = srv;
  for (int i = tid; i < BB * NN; i += 256) {
    int b = i >> 11, n = i & (NN - 1);
    float v = (z[((size_t)b * O + o) * NN + n] - m) * r;
    out[(size_t)b * outBS + o * NN + n] = v >= 0.f ? v : 0.2f * v;
  }
}

// ---------------------------------------------------------------- fused BN+LReLU+max/mean pool (conv5)
__global__ __launch_bounds__(256) void bn_pool_kernel(const float* __restrict__ z,
                                                      float* __restrict__ p) {
  int o = blockIdx.x;
  int tid = threadIdx.x;
  __shared__ float s1[256], s2[256];
  __shared__ float smv, srv;
  float a1 = 0.f, a2 = 0.f;
  for (int i = tid; i < BB * NN; i += 256) {
    int b = i >> 11, n = i & (NN - 1);
    float v = z[((size_t)b * 1024 + o) * NN + n];
    a1 += v; a2 += v * v;
  }
  s1[tid] = a1; s2[tid] = a2;
  __syncthreads();
  for (int st = 128; st > 0; st >>= 1) {
    if (tid < st) { s1[tid] += s1[tid + st]; s2[tid] += s2[tid + st]; }
    __syncthreads();
  }
  if (tid == 0) {
    float m = s1[0] / (BB * NN);
    float var = s2[0] / (BB * NN) - m * m;
    smv = m; srv = rsqrtf(var + 1e-5f);
  }
  __syncthreads();
  float m = smv, r = srv;
  int b = tid >> 5, l = tid & 31;
  const float* zp = z + ((size_t)b * 1024 + o) * NN;
  float mx = -INFINITY, sm = 0.f;
  for (int n = l; n < NN; n += 32) {
    float v = (zp[n] - m) * r;
    v = v >= 0.f ? v : 0.2f * v;
    mx = fmaxf(mx, v); sm += v;
  }
#pragma unroll
  for (int s = 16; s > 0; s >>= 1) {
    mx = fmaxf(mx, __shfl_xor(mx, s));
    sm += __shfl_xor(sm, s);
  }
  if (l == 0) {
    p[b * 2048 + o] = mx;
    p[b * 2048 + 1024 + o] = sm * (1.f / NN);
  }
}

__global__ __launch_bounds__(64) void linear_kernel(const float* __restrict__ in, int IN, int OUT,
                                                    const float* __restrict__ w,
                                                    const float* __restrict__ bias,
                                                    float* __restrict__ out) {
  int o = blockIdx.x;
  int b = o / OUT, f = o % OUT;
  const float* ip = in + (size_t)b * IN;
  const float* wp = w + (size_t)f * IN;
  float a = 0.f;
  for (int i = threadIdx.x; i < IN; i += 64) a += ip[i] * wp[i];
#pragma unroll
  for (int s = 32; s > 0; s >>= 1) a += __shfl_down(a, s);
  if (threadIdx.x == 0) out[o] = a + bias[f];
}

__global__ __launch_bounds__(256) void bnf_kernel(float* __restrict__ t, int F) {
  int f = blockIdx.x * blockDim.x + threadIdx.x;
  if (f >= F) return;
  float s = 0.f, s2 = 0.f;
  for (int b = 0; b < BB; ++b) { float v = t[b * F + f]; s += v; s2 += v * v; }
  float m = s * (1.f / BB);
  float var = s2 * (1.f / BB) - m * m;
  float r = rsqrtf(var + 1e-5f);
  for (int b = 0; b < BB; ++b) {
    float v = (t[b * F + f] - m) * r;
    t[b * F + f] = v >= 0.f ? v : 0.2f * v;
  }
}

// ---------------------------------------------------------------- host side

struct SAW { const float *wq, *wk, *wv, *wc; };

static inline void run_conv(const float* in, int inBS, int C, int O, const float* w,
                            float* z, hipStream_t st) {
  if (O % 128 == 0)
    conv_gemm128_db_kernel<<<dim3(NN / 128, O / 128, BB), 256, 0, st>>>(in, inBS, C, O, w, z);
  else
    conv_gemm_kernel<<<dim3(NN / 64, (O + 63) / 64, BB), 256, 0, st>>>(in, inBS, C, O, w, z);
}

// MFMA==true only valid for C multiple of 128.
template <int C, bool MFMA>
static inline void run_sa(const float* xin, int xbs, SAW w,
                          float* xT, float* U, float* UT, float* AGGt,
                          float* AGG, float* z, float* h, float* sq, int* idx,
                          float* M, float* WCV, unsigned short* Mb, unsigned short* wcvb,
                          unsigned short* xTb, unsigned short* AGGtb,
                          float* D, int nbatch, hipStream_t st) {
  sq_kernel<<<BB * NN / 256, 256, 0, st>>>(xin, xbs, C, sq);
  transpose_kernel<<<dim3(NN / 32, (C + 31) / 32, BB), 256, 0, st>>>(xin, xbs, C, NN, xT);
  mprep_kernel<<<(C * C + 255) / 256, 256, 0, st>>>(w.wq, w.wk, C, M);
  wcv_kernel<<<(C * C + 255) / 256, 256, 0, st>>>(w.wc, w.wv, C, WCV);
  if (MFMA) {
    convert_bf16_kernel<<<(C * C + 255) / 256, 256, 0, st>>>(M, Mb, C * C);
    convert_bf16_kernel<<<(C * C + 255) / 256, 256, 0, st>>>(WCV, wcvb, C * C);
    transpose_bf16_kernel<<<dim3(NN / 32, (C + 31) / 32, BB), 256, 0, st>>>(xin, xbs, C, NN, xTb);
  }
  for (int bb = 0; bb < BB; bb += nbatch) {
    int nbc = (BB - bb) < nbatch ? (BB - bb) : nbatch;
    pd_gemm128_db_kernel<<<dim3(NN / 128, NN / 128, nbc), 256, 0, st>>>(xin, xbs, C, sq, D, bb);
    topk4_kernel<<<dim3(NN / 4, nbc), 256, 0, st>>>(D, idx, bb);
  }
  if (MFMA)
    mfma_gemm_lds_kernel<<<dim3(NN / 128, C / 128, BB), 256, 0, st>>>(Mb, xTb, U, C, C);
  else
    run_conv(xin, xbs, C, C, M, U, st);                            // U = M . x  [C][N]
  transpose_kernel<<<dim3(NN / 32, (C + 31) / 32, BB), 256, 0, st>>>(U, C * NN, C, NN, UT);
  att_wave_kernel<C><<<BB * NN, 64, 0, st>>>(xT, UT, idx, AGGt);   // AGGt [N][C]
  if (MFMA) {
    convert_bf16_kernel<<<(BB * NN * C + 255) / 256, 256, 0, st>>>(AGGt, AGGtb, BB * NN * C);
    mfma_gemm_lds_kernel<<<dim3(NN / 128, C / 128, BB), 256, 0, st>>>(wcvb, AGGtb, z, C, C);
  } else {
    transpose_kernel<<<dim3((C + 31) / 32, NN / 32, BB), 256, 0, st>>>(AGGt, NN * C, NN, C, AGG);
    run_conv(AGG, C * NN, C, C, WCV, z, st);                       // Z = (wc.wv) . AGG
  }
  bn_copy_kernel<<<2 * C, 256, 0, st>>>(z, C, xin, xbs, h);
}

static inline void run_conv_bn(const float* in, int inBS, int Cin, int O, const float* w,
                               float* z, float* out, int outBS, int c0, hipStream_t st) {
  run_conv(in, inBS, Cin, O, w, z, st);
  bn_fused_kernel<<<O, 256, 0, st>>>(z, O, out, outBS, c0);
}

extern "C" void kernel_launch(void* const* d_in, const int* in_sizes, int n_in,
                              void* d_out, int out_size, void* d_ws, size_t ws_size,
                              hipStream_t stream) {
  const float* x = (const float*)d_in[0];
  SAW sa1{(const float*)d_in[1], (const float*)d_in[2], (const float*)d_in[3], (const float*)d_in[4]};
  SAW sa2{(const float*)d_in[5], (const float*)d_in[6], (const float*)d_in[7], (const float*)d_in[8]};
  SAW sa3{(const float*)d_in[9], (const float*)d_in[10], (const float*)d_in[11], (const float*)d_in[12]};
  SAW sa4{(const float*)d_in[13], (const float*)d_in[14], (const float*)d_in[15], (const float*)d_in[16]};
  const float* conv1_w = (const float*)d_in[17];
  const float* conv2_w = (const float*)d_in[18];
  const float* conv3_w = (const float*)d_in[19];
  const float* conv4_w = (const float*)d_in[20];
  const float* conv5_w = (const float*)d_in[21];
  const float* lin1_w = (const float*)d_in[22];
  const float* lin1_b = (const float*)d_in[23];
  const float* lin2_w = (const float*)d_in[24];
  const float* lin2_b = (const float*)d_in[25];
  const float* lin3_w = (const float*)d_in[26];
  const float* lin3_b = (const float*)d_in[27];

  char* ws = (char*)d_ws;
  size_t off = 0;
  auto take = [&](size_t bytes) -> void* {
    void* p = ws + off;
    off += (bytes + 255) & ~(size_t)255;
    return p;
  };
  float* sq   = (float*)take((size_t)BB * NN * 4);
  int*   idx  = (int*)take((size_t)BB * NN * KNB * 4);
  float* M    = (float*)take((size_t)128 * 128 * 4);
  float* WCV  = (float*)take((size_t)128 * 128 * 4);
  unsigned short* Mb   = (unsigned short*)take((size_t)128 * 128 * 2);
  unsigned short* wcvb = (unsigned short*)take((size_t)128 * 128 * 2);
  unsigned short* w4b  = (unsigned short*)take((size_t)256 * 256 * 2);
  unsigned short* w5b  = (unsigned short*)take((size_t)1024 * 512 * 2);
  float* U    = (float*)take((size_t)BB * 128 * NN * 4);  // contiguous with AGG
  float* AGG  = (float*)take((size_t)BB * 128 * NN * 4);  // also hosts xT
  float* h    = (float*)take((size_t)BB * 256 * NN * 4);  // first half hosts UT
  float* z    = (float*)take((size_t)BB * 1024 * NN * 4); // hosts AGGt, AGGtb(+16MB), D-chunks
  float* xc   = (float*)take((size_t)BB * 512 * NN * 4);
  float* p    = (float*)take((size_t)BB * 2048 * 4);
  float* t1   = (float*)take((size_t)BB * 512 * 4);
  float* t2   = (float*)take((size_t)BB * 256 * 4);
  (void)n_in; (void)in_sizes; (void)out_size;

  // Overlays (phase-ordered lifetimes):
  float* xT = AGG;                                          // dead before AGG written
  float* UT = h;                                            // consumed before h written
  float* AGGt = z;                                          // first 8.4 MB of z
  unsigned short* xTb   = (unsigned short*)((char*)h + (size_t)BB * 128 * NN * 4);  // h 2nd half
  unsigned short* AGGtb = (unsigned short*)((char*)z + (size_t)16 * 1024 * 1024);   // z + 16 MB
  unsigned short* hTb   = (unsigned short*)U;               // conv4 phase (U dead)
  unsigned short* xcTb  = (unsigned short*)U;               // conv5 phase (U+AGG dead, 16.8 MB)

  size_t dfull = (size_t)BB * NN * NN * 4;
  bool fullD = (ws_size > off + dfull + 4096);
  float* D = fullD ? (float*)take(dfull) : z;               // !fullD: 4-batch chunks fill z exactly
  int nbatch = fullD ? BB : 4;

  // SA1 (C=3) -> h [B,6,N]
  run_sa<3, false>(x, 3 * NN, sa1, xT, U, UT, AGGt, AGG, z, h, sq, idx,
                   M, WCV, Mb, wcvb, xTb, AGGtb, D, nbatch, stream);
  run_conv_bn(h, 6 * NN, 6, 64, conv1_w, z, xc, 512 * NN, 0, stream);
  // SA2 (C=64) on x1
  run_sa<64, false>(xc + 0 * NN, 512 * NN, sa2, xT, U, UT, AGGt, AGG, z, h, sq, idx,
                    M, WCV, Mb, wcvb, xTb, AGGtb, D, nbatch, stream);
  run_conv_bn(h, 128 * NN, 128, 64, conv2_w, z, xc, 512 * NN, 64, stream);
  // SA3 (C=64) on x2
  run_sa<64, false>(xc + 64 * NN, 512 * NN, sa3, xT, U, UT, AGGt, AGG, z, h, sq, idx,
                    M, WCV, Mb, wcvb, xTb, AGGtb, D, nbatch, stream);
  run_conv_bn(h, 128 * NN, 128, 128, conv3_w, z, xc, 512 * NN, 128, stream);
  // SA4 (C=128) on x3 — bf16 MFMA for U and Z convs (no kNN downstream)
  run_sa<128, true>(xc + 128 * NN, 512 * NN, sa4, xT, U, UT, AGGt, AGG, z, h, sq, idx,
                    M, WCV, Mb, wcvb, xTb, AGGtb, D, nbatch, stream);
  // conv4 (bf16 MFMA): h [B,256,N] -> z [B,256,N]
  transpose_bf16_kernel<<<dim3(NN / 32, 8, BB), 256, 0, stream>>>(h, 256 * NN, 256, NN, hTb);
  convert_bf16_kernel<<<(256 * 256 + 255) / 256, 256, 0, stream>>>(conv4_w, w4b, 256 * 256);
  mfma_gemm_lds_kernel<<<dim3(NN / 128, 2, BB), 256, 0, stream>>>(w4b, hTb, z, 256, 256);
  bn_fused_kernel<<<256, 256, 0, stream>>>(z, 256, xc, 512 * NN, 256);
  // conv5 (bf16 MFMA): xc [B,512,N] -> z [B,1024,N]; BN+LReLU+pool -> p
  transpose_bf16_kernel<<<dim3(NN / 32, 16, BB), 256, 0, stream>>>(xc, 512 * NN, 512, NN, xcTb);
  convert_bf16_kernel<<<(1024 * 512 + 255) / 256, 256, 0, stream>>>(conv5_w, w5b, 1024 * 512);
  mfma_gemm_lds_kernel<<<dim3(NN / 128, 8, BB), 256, 0, stream>>>(w5b, xcTb, z, 1024, 512);
  bn_pool_kernel<<<1024, 256, 0, stream>>>(z, p);
  // FC head
  linear_kernel<<<BB * 512, 64, 0, stream>>>(p, 2048, 512, lin1_w, lin1_b, t1);
  bnf_kernel<<<2, 256, 0, stream>>>(t1, 512);
  linear_kernel<<<BB * 256, 64, 0, stream>>>(t1, 512, 256, lin2_w, lin2_b, t2);
  bnf_kernel<<<1, 256, 0, stream>>>(t2, 256);
  linear_kernel<<<BB * 40, 64, 0, stream>>>(t2, 256, 40, lin3_w, lin3_b, (float*)d_out);
}

// Round 14
// 1381.599 us; speedup vs baseline: 1.3828x; 1.1929x over previous
//
#include <hip/hip_runtime.h>
#include <math.h>

#define BB 8
#define NN 2048
#define KNB 20

typedef __attribute__((ext_vector_type(8))) short bf16x8;
typedef __attribute__((ext_vector_type(4))) float f32x4;

__device__ inline unsigned short f2bf(float f) {
  union { float f; unsigned u; } v; v.f = f;
  unsigned r = v.u + 0x7FFF + ((v.u >> 16) & 1);  // RNE
  return (unsigned short)(r >> 16);
}

// ---------------------------------------------------------------- sq
__global__ __launch_bounds__(256) void sq_kernel(const float* __restrict__ x, int bs, int C,
                                                 float* __restrict__ sq) {
  int t = blockIdx.x * blockDim.x + threadIdx.x;
  int b = t / NN, n = t % NN;
  const float* xp = x + (size_t)b * bs + n;
  float s = 0.f;
  for (int c = 0; c < C; ++c) { float v = xp[c * NN]; s += v * v; }
  sq[t] = s;
}

// ---------------------------------------------------------------- M = wk^T wq
__global__ __launch_bounds__(256) void mprep_kernel(const float* __restrict__ wq,
                                                    const float* __restrict__ wk, int C,
                                                    float* __restrict__ M) {
  int T = blockIdx.x * 256 + threadIdx.x;
  if (T >= C * C) return;
  int c = T / C, cp = T % C;
  float a = 0.f;
  for (int e = 0; e < C; ++e) a += wk[e * C + c] * wq[e * C + cp];
  M[c * C + cp] = a;
}

// ---------------------------------------------------------------- wcv = wc @ wv
__global__ __launch_bounds__(256) void wcv_kernel(const float* __restrict__ wc,
                                                  const float* __restrict__ wv, int C,
                                                  float* __restrict__ out) {
  int T = blockIdx.x * 256 + threadIdx.x;
  if (T >= C * C) return;
  int o = T / C, c = T % C;
  float a = 0.f;
  for (int e = 0; e < C; ++e) a += wc[o * C + e] * wv[e * C + c];
  out[o * C + c] = a;
}

// ---------------------------------------------------------------- converts
__global__ __launch_bounds__(256) void convert_bf16_kernel(const float* __restrict__ in,
                                                           unsigned short* __restrict__ out,
                                                           int count) {
  int i = blockIdx.x * 256 + threadIdx.x;
  if (i < count) out[i] = f2bf(in[i]);
}

// ---------------------------------------------------------------- transpose (fp32)
__global__ __launch_bounds__(256) void transpose_kernel(const float* __restrict__ in, int inBS,
                                                        int R, int Cl, float* __restrict__ out) {
  __shared__ float tile[32][33];
  int b = blockIdx.z;
  const float* ip = in + (size_t)b * inBS;
  float* op = out + (size_t)b * R * Cl;
  int c0 = blockIdx.x * 32, r0 = blockIdx.y * 32;
  int tx = threadIdx.x & 31, ty = threadIdx.x >> 5;
  for (int yy = ty; yy < 32; yy += 8) {
    int r = r0 + yy, c = c0 + tx;
    tile[yy][tx] = (r < R && c < Cl) ? ip[(size_t)r * Cl + c] : 0.f;
  }
  __syncthreads();
  for (int yy = ty; yy < 32; yy += 8) {
    int c = c0 + yy, r = r0 + tx;
    if (c < Cl && r < R) op[(size_t)c * R + r] = tile[tx][yy];
  }
}

// ---------------------------------------------------------------- transpose + bf16 convert
__global__ __launch_bounds__(256) void transpose_bf16_kernel(const float* __restrict__ in, int inBS,
                                                             int R, int Cl,
                                                             unsigned short* __restrict__ out) {
  __shared__ float tile[32][33];
  int b = blockIdx.z;
  const float* ip = in + (size_t)b * inBS;
  unsigned short* op = out + (size_t)b * R * Cl;
  int c0 = blockIdx.x * 32, r0 = blockIdx.y * 32;
  int tx = threadIdx.x & 31, ty = threadIdx.x >> 5;
  for (int yy = ty; yy < 32; yy += 8) {
    int r = r0 + yy, c = c0 + tx;
    tile[yy][tx] = (r < R && c < Cl) ? ip[(size_t)r * Cl + c] : 0.f;
  }
  __syncthreads();
  for (int yy = ty; yy < 32; yy += 8) {
    int c = c0 + yy, r = r0 + tx;
    if (c < Cl && r < R) op[(size_t)c * R + r] = f2bf(tile[tx][yy]);
  }
}

// ---------------------------------------------------------------- MFMA GEMM, LDS double-buffered
// Z[b][o][n] = sum_k A[o][k] * B[b][n][k]; A,B bf16 K-contiguous, Z fp32.
__global__ __launch_bounds__(256, 2) void mfma_gemm_lds_kernel(
    const unsigned short* __restrict__ A, const unsigned short* __restrict__ B,
    float* __restrict__ Z, int O, int K) {
  const int b = blockIdx.z;
  const int n0 = blockIdx.x * 128, o0 = blockIdx.y * 128;
  const int tid = threadIdx.x;
  const int wave = tid >> 6, lane = tid & 63;
  const int wo = wave >> 1, wn = wave & 1;   // 64x64 quadrant per wave
  const int l16 = lane & 15, q = lane >> 4;
  __shared__ unsigned short Al[2][4096];     // 128 rows x 32 k (8 KB), frag order
  __shared__ unsigned short Bl[2][4096];
  const unsigned short* Ab = A + (size_t)o0 * K;
  const unsigned short* Bb = B + ((size_t)b * NN + n0) * K;

  const int p0 = tid, p1 = tid + 256;
  const int r0 = ((p0 >> 6) << 4) | (p0 & 15), c0 = ((p0 >> 4) & 3) * 8;
  const int r1 = ((p1 >> 6) << 4) | (p1 & 15), c1 = ((p1 >> 4) & 3) * 8;

  bf16x8 ar0, ar1, br0, br1;
  auto gload = [&](int k0) {
    ar0 = *(const bf16x8*)(Ab + (size_t)r0 * K + k0 + c0);
    ar1 = *(const bf16x8*)(Ab + (size_t)r1 * K + k0 + c1);
    br0 = *(const bf16x8*)(Bb + (size_t)r0 * K + k0 + c0);
    br1 = *(const bf16x8*)(Bb + (size_t)r1 * K + k0 + c1);
  };
  auto sstore = [&](int buf) {
    *(bf16x8*)&Al[buf][p0 * 8] = ar0;
    *(bf16x8*)&Al[buf][p1 * 8] = ar1;
    *(bf16x8*)&Bl[buf][p0 * 8] = br0;
    *(bf16x8*)&Bl[buf][p1 * 8] = br1;
  };

  f32x4 acc[4][4];
#pragma unroll
  for (int s = 0; s < 4; ++s)
#pragma unroll
    for (int t = 0; t < 4; ++t) acc[s][t] = (f32x4){0.f, 0.f, 0.f, 0.f};

  gload(0);
  sstore(0);
  int cur = 0;
  for (int k0 = 0; k0 < K; k0 += 32) {
    bool more = (k0 + 32) < K;
    if (more) gload(k0 + 32);
    __syncthreads();
    bf16x8 af[4], bfr[4];
#pragma unroll
    for (int s = 0; s < 4; ++s)
      af[s] = *(const bf16x8*)&Al[cur][((wo * 4 + s) * 64 + q * 16 + l16) * 8];
#pragma unroll
    for (int t = 0; t < 4; ++t)
      bfr[t] = *(const bf16x8*)&Bl[cur][((wn * 4 + t) * 64 + q * 16 + l16) * 8];
#pragma unroll
    for (int s = 0; s < 4; ++s)
#pragma unroll
      for (int t = 0; t < 4; ++t)
        acc[s][t] = __builtin_amdgcn_mfma_f32_16x16x32_bf16(af[s], bfr[t], acc[s][t], 0, 0, 0);
    if (more) sstore(cur ^ 1);
    cur ^= 1;
  }
#pragma unroll
  for (int s = 0; s < 4; ++s)
#pragma unroll
    for (int t = 0; t < 4; ++t) {
      float* zp = Z + ((size_t)b * O + o0 + wo * 64 + s * 16 + q * 4) * NN
                  + n0 + wn * 64 + t * 16 + l16;
#pragma unroll
      for (int r = 0; r < 4; ++r) zp[(size_t)r * NN] = acc[s][t][r];
    }
}

// ---------------------------------------------------------------- pd GEMM 128-tile, double-buffered
// Full matrix (r10 symmetric variant regressed). (256,2): (256,3) spilled (r6).
__global__ __launch_bounds__(256, 2) void pd_gemm128_db_kernel(
    const float* __restrict__ x, int bs, int C, const float* __restrict__ sq,
    float* __restrict__ P, int b_base) {
  const int b = b_base + blockIdx.z;
  const int n0 = blockIdx.x * 128, m0 = blockIdx.y * 128;
  const int tid = threadIdx.x;
  const int tm = tid & 15, tn = tid >> 4;
  __shared__ float As[2][16][128], Bs[2][16][128];
  const float* xb = x + (size_t)b * bs;
  float acc[8][8];
#pragma unroll
  for (int i = 0; i < 8; ++i)
#pragma unroll
    for (int j = 0; j < 8; ++j) acc[i][j] = 0.f;

  float4 ara[2], arb[2];
  auto load_tile = [&](int k0) {
#pragma unroll
    for (int it = 0; it < 2; ++it) {
      int i = it * 256 + tid;
      int kc = i >> 5, c4 = i & 31;
      bool ok = (k0 + kc) < C;
      ara[it] = ok ? *(const float4*)&xb[(size_t)(k0 + kc) * NN + n0 + c4 * 4]
                   : make_float4(0.f, 0.f, 0.f, 0.f);
      arb[it] = ok ? *(const float4*)&xb[(size_t)(k0 + kc) * NN + m0 + c4 * 4]
                   : make_float4(0.f, 0.f, 0.f, 0.f);
    }
  };
  auto store_tile = [&](int buf) {
#pragma unroll
    for (int it = 0; it < 2; ++it) {
      int i = it * 256 + tid;
      int kc = i >> 5, c4 = i & 31;
      *(float4*)&As[buf][kc][c4 * 4] = ara[it];
      *(float4*)&Bs[buf][kc][c4 * 4] = arb[it];
    }
  };

  load_tile(0);
  store_tile(0);
  int cur = 0;
  for (int k0 = 0; k0 < C; k0 += 16) {
    bool more = (k0 + 16) < C;
    if (more) load_tile(k0 + 16);
    __syncthreads();
#pragma unroll
    for (int kc = 0; kc < 16; ++kc) {
      float4 a0 = *(const float4*)&As[cur][kc][tn * 4];
      float4 a1 = *(const float4*)&As[cur][kc][64 + tn * 4];
      float4 b0 = *(const float4*)&Bs[cur][kc][tm * 4];
      float4 b1 = *(const float4*)&Bs[cur][kc][64 + tm * 4];
      float ar[8] = {a0.x, a0.y, a0.z, a0.w, a1.x, a1.y, a1.z, a1.w};
      float br[8] = {b0.x, b0.y, b0.z, b0.w, b1.x, b1.y, b1.z, b1.w};
#pragma unroll
      for (int i = 0; i < 8; ++i)
#pragma unroll
        for (int j = 0; j < 8; ++j) acc[i][j] += ar[i] * br[j];
    }
    if (more) store_tile(cur ^ 1);
    cur ^= 1;
  }
  float4 sqa = *(const float4*)&sq[b * NN + m0 + tm * 4];
  float4 sqb = *(const float4*)&sq[b * NN + m0 + 64 + tm * 4];
#pragma unroll
  for (int h = 0; h < 2; ++h)
#pragma unroll
    for (int i = 0; i < 4; ++i) {
      int r = h * 4 + i;
      int nn = n0 + h * 64 + tn * 4 + i;
      float* prow = &P[((size_t)blockIdx.z * NN + nn) * NN + m0];
      float4 o0, o1;
      o0.x = 2.f * acc[r][0] - sqa.x; o0.y = 2.f * acc[r][1] - sqa.y;
      o0.z = 2.f * acc[r][2] - sqa.z; o0.w = 2.f * acc[r][3] - sqa.w;
      o1.x = 2.f * acc[r][4] - sqb.x; o1.y = 2.f * acc[r][5] - sqb.y;
      o1.z = 2.f * acc[r][6] - sqb.z; o1.w = 2.f * acc[r][7] - sqb.w;
      *(float4*)&prow[tm * 4] = o0;
      *(float4*)&prow[64 + tm * 4] = o1;
    }
}

// ---------------------------------------------------------------- top-20: EXACT-key bitonic + idx array
// r13 ERRATA: 21-bit truncated keys reordered near-ties -> wrong neighbors
// (absmax 0.488). Selection must compare exact fp32. This version sorts the
// full 32-bit orderable key with a parallel idx[32] permuted alongside
// (5 inst/exchange x 240), then 20 rounds of value-only butterfly max
// (12 inst) + owner head-shift. ~2.5k inst/row vs r12's ~4k tracked-argmax.
// Owner uniqueness assumes no exact fp32 duplicate pd (measure-zero).
__global__ __launch_bounds__(256) void topk_bsort_kernel(const float* __restrict__ P,
                                                         int* __restrict__ idx_out, int b_base) {
  const int wave = threadIdx.x >> 6;
  const int lane = threadIdx.x & 63;
  const int n = blockIdx.x * 4 + wave;
  const int bl = blockIdx.y;
  const int b = b_base + bl;
  const float4* rp = (const float4*)(P + ((size_t)bl * NN + n) * NN);
  unsigned key[32], mv[32];
#pragma unroll
  for (int q = 0; q < 8; ++q) {
    float4 vv = rp[q * 64 + lane];
    int mb = q * 256 + lane * 4;
    float fv[4] = {vv.x, vv.y, vv.z, vv.w};
#pragma unroll
    for (int j = 0; j < 4; ++j) {
      unsigned u = __float_as_uint(fv[j]);
      unsigned mask = (unsigned)(((int)u) >> 31) | 0x80000000u;  // orderable transform
      key[q * 4 + j] = (mb + j == n) ? 0u : (u ^ mask);
      mv[q * 4 + j] = (unsigned)(mb + j);
    }
  }
  // bitonic sort descending on key, idx permuted alongside
  // (direction rule verified by hand on n=4: (i&k)==0 -> slot i gets max)
#pragma unroll
  for (int k = 2; k <= 32; k <<= 1) {
#pragma unroll
    for (int j = k >> 1; j > 0; j >>= 1) {
#pragma unroll
      for (int i = 0; i < 32; ++i) {
        int l = i ^ j;
        if (l > i) {
          unsigned ka = key[i], kb = key[l];
          unsigned ia = mv[i], ib = mv[l];
          bool agt = ka > kb;
          unsigned kmax = agt ? ka : kb, kmin = agt ? kb : ka;
          unsigned imax = agt ? ia : ib, imin = agt ? ib : ia;
          if ((i & k) == 0) { key[i] = kmax; mv[i] = imin ^ imin ^ imax; key[l] = kmin; mv[l] = imin; }
          else              { key[i] = kmin; mv[i] = imin; key[l] = kmax; mv[l] = imax; }
        }
      }
    }
  }
  int* op = idx_out + (size_t)(b * NN + n) * KNB;
  for (int k = 0; k < KNB; ++k) {
    unsigned best = key[0];
#pragma unroll
    for (int s = 32; s > 0; s >>= 1) {
      unsigned o = (unsigned)__shfl_xor((int)best, s);
      best = best > o ? best : o;
    }
    bool own = (key[0] == best);
    if (own) {
      op[k] = (int)mv[0];
#pragma unroll
      for (int j = 0; j < 20; ++j) { key[j] = key[j + 1]; mv[j] = mv[j + 1]; }
    }
  }
}

// ---------------------------------------------------------------- conv GEMM 64-tile (small O)
__global__ __launch_bounds__(256, 2) void conv_gemm_kernel(
    const float* __restrict__ in, int inBS, int C, int O,
    const float* __restrict__ w, float* __restrict__ z) {
  const int b = blockIdx.z;
  const int n0 = blockIdx.x * 64, o0 = blockIdx.y * 64;
  const int tid = threadIdx.x;
  const int tm = tid & 15, tn = tid >> 4;
  __shared__ float Ws[16][68];
  __shared__ float Xs[16][64];
  const float* ib = in + (size_t)b * inBS;
  float acc[4][4];
#pragma unroll
  for (int i = 0; i < 4; ++i)
#pragma unroll
    for (int j = 0; j < 4; ++j) acc[i][j] = 0.f;

  for (int k0 = 0; k0 < C; k0 += 16) {
    __syncthreads();
#pragma unroll
    for (int it = 0; it < 4; ++it) {
      int i = it * 256 + tid;
      int kc = i >> 6, nl = i & 63;
      Xs[kc][nl] = ((k0 + kc) < C) ? ib[(size_t)(k0 + kc) * NN + n0 + nl] : 0.f;
      int ol = i >> 4, kc2 = i & 15;
      Ws[kc2][ol] = ((o0 + ol) < O && (k0 + kc2) < C) ? w[(size_t)(o0 + ol) * C + k0 + kc2] : 0.f;
    }
    __syncthreads();
#pragma unroll
    for (int kc = 0; kc < 16; ++kc) {
      float4 a = *(const float4*)&Ws[kc][tn * 4];
      float4 bv = *(const float4*)&Xs[kc][tm * 4];
      acc[0][0] += a.x * bv.x; acc[0][1] += a.x * bv.y; acc[0][2] += a.x * bv.z; acc[0][3] += a.x * bv.w;
      acc[1][0] += a.y * bv.x; acc[1][1] += a.y * bv.y; acc[1][2] += a.y * bv.z; acc[1][3] += a.y * bv.w;
      acc[2][0] += a.z * bv.x; acc[2][1] += a.z * bv.y; acc[2][2] += a.z * bv.z; acc[2][3] += a.z * bv.w;
      acc[3][0] += a.w * bv.x; acc[3][1] += a.w * bv.y; acc[3][2] += a.w * bv.z; acc[3][3] += a.w * bv.w;
    }
  }
#pragma unroll
  for (int i = 0; i < 4; ++i) {
    int o = o0 + tn * 4 + i;
    if (o < O) {
      float4 ov;
      ov.x = acc[i][0]; ov.y = acc[i][1]; ov.z = acc[i][2]; ov.w = acc[i][3];
      *(float4*)&z[((size_t)b * O + o) * NN + n0 + tm * 4] = ov;
    }
  }
}

// ---------------------------------------------------------------- conv GEMM 128-tile, double-buffered (fp32)
__global__ __launch_bounds__(256, 2) void conv_gemm128_db_kernel(
    const float* __restrict__ in, int inBS, int C, int O,
    const float* __restrict__ w, float* __restrict__ z) {
  const int b = blockIdx.z;
  const int n0 = blockIdx.x * 128, o0 = blockIdx.y * 128;
  const int tid = threadIdx.x;
  const int tm = tid & 15, tn = tid >> 4;
  __shared__ float Xs[2][16][128];
  __shared__ float Ws[2][16][132];
  const float* ib = in + (size_t)b * inBS;
  float acc[8][8];
#pragma unroll
  for (int i = 0; i < 8; ++i)
#pragma unroll
    for (int j = 0; j < 8; ++j) acc[i][j] = 0.f;

  float4 xr[2], wr[2];
  auto load_tile = [&](int k0) {
#pragma unroll
    for (int it = 0; it < 2; ++it) {
      int i = it * 256 + tid;
      int kc = i >> 5, c4 = i & 31;
      xr[it] = ((k0 + kc) < C) ? *(const float4*)&ib[(size_t)(k0 + kc) * NN + n0 + c4 * 4]
                               : make_float4(0.f, 0.f, 0.f, 0.f);
      int ol = i >> 2, kq = i & 3;
      wr[it] = ((k0 + kq * 4) < C) ? *(const float4*)&w[(size_t)(o0 + ol) * C + k0 + kq * 4]
                                   : make_float4(0.f, 0.f, 0.f, 0.f);
    }
  };
  auto store_tile = [&](int buf) {
#pragma unroll
    for (int it = 0; it < 2; ++it) {
      int i = it * 256 + tid;
      int kc = i >> 5, c4 = i & 31;
      *(float4*)&Xs[buf][kc][c4 * 4] = xr[it];
      int ol = i >> 2, kq = i & 3;
      Ws[buf][kq * 4 + 0][ol] = wr[it].x;
      Ws[buf][kq * 4 + 1][ol] = wr[it].y;
      Ws[buf][kq * 4 + 2][ol] = wr[it].z;
      Ws[buf][kq * 4 + 3][ol] = wr[it].w;
    }
  };

  load_tile(0);
  store_tile(0);
  int cur = 0;
  for (int k0 = 0; k0 < C; k0 += 16) {
    bool more = (k0 + 16) < C;
    if (more) load_tile(k0 + 16);
    __syncthreads();
#pragma unroll
    for (int kc = 0; kc < 16; ++kc) {
      float4 a0 = *(const float4*)&Ws[cur][kc][tn * 4];
      float4 a1 = *(const float4*)&Ws[cur][kc][64 + tn * 4];
      float4 b0 = *(const float4*)&Xs[cur][kc][tm * 4];
      float4 b1 = *(const float4*)&Xs[cur][kc][64 + tm * 4];
      float ar[8] = {a0.x, a0.y, a0.z, a0.w, a1.x, a1.y, a1.z, a1.w};
      float br[8] = {b0.x, b0.y, b0.z, b0.w, b1.x, b1.y, b1.z, b1.w};
#pragma unroll
      for (int i = 0; i < 8; ++i)
#pragma unroll
        for (int j = 0; j < 8; ++j) acc[i][j] += ar[i] * br[j];
    }
    if (more) store_tile(cur ^ 1);
    cur ^= 1;
  }
#pragma unroll
  for (int h = 0; h < 2; ++h)
#pragma unroll
    for (int i = 0; i < 4; ++i) {
      int r = h * 4 + i;
      int o = o0 + h * 64 + tn * 4 + i;
      float* zrow = &z[((size_t)b * O + o) * NN + n0];
      float4 o0v, o1v;
      o0v.x = acc[r][0]; o0v.y = acc[r][1]; o0v.z = acc[r][2]; o0v.w = acc[r][3];
      o1v.x = acc[r][4]; o1v.y = acc[r][5]; o1v.z = acc[r][6]; o1v.w = acc[r][7];
      *(float4*)&zrow[tm * 4] = o0v;
      *(float4*)&zrow[64 + tm * 4] = o1v;
    }
}

// ---------------------------------------------------------------- attention (wave/point)
// BF16OUT: write bf16 AGGtb directly (MFMA path) — removes the standalone
// 8.4M-element convert kernel.
template <int C, bool BF16OUT>
__global__ __launch_bounds__(64) void att_wave_kernel(
    const float* __restrict__ xT, const float* __restrict__ UT,
    const int* __restrict__ idx, float* __restrict__ AGGt,
    unsigned short* __restrict__ AGGtb) {
  const int n = blockIdx.x & (NN - 1);
  const int b = blockIdx.x >> 11;
  const int lane = threadIdx.x;
  constexpr int CP = C + 1;
  __shared__ float nb[KNB][CP];
  __shared__ float sl[KNB];
  __shared__ int nidx[KNB];
  __shared__ float ul[C];
  const float* xTb = xT + (size_t)b * NN * C;
  if (lane < KNB) nidx[lane] = idx[(size_t)(b * NN + n) * KNB + lane];
  for (int c = lane; c < C; c += 64) ul[c] = UT[((size_t)b * NN + n) * C + c];
  __syncthreads();
  for (int i = lane; i < KNB * C; i += 64) {
    int k = i / C, c = i - k * C;
    nb[k][c] = xTb[(size_t)nidx[k] * C + c];
  }
  __syncthreads();
  float sv = -INFINITY;
  if (lane < KNB) {
    float a = 0.f;
#pragma unroll
    for (int c = 0; c < C; ++c) a += nb[lane][c] * ul[c];
    sv = a / sqrtf((float)C);
  }
  float mx = sv;
#pragma unroll
  for (int s = 32; s > 0; s >>= 1) mx = fmaxf(mx, __shfl_xor(mx, s));
  float e = (lane < KNB) ? expf(sv - mx) : 0.f;
  float sum = e;
#pragma unroll
  for (int s = 32; s > 0; s >>= 1) sum += __shfl_xor(sum, s);
  if (lane < KNB) sl[lane] = e / sum;
  __syncthreads();
  const float* xTn = xTb + (size_t)n * C;
  for (int c = lane; c < C; c += 64) {
    float a = 0.f;
#pragma unroll
    for (int k = 0; k < KNB; ++k) a += sl[k] * nb[k][c];
    float r = a - xTn[c];
    if (BF16OUT)
      AGGtb[((size_t)b * NN + n) * C + c] = f2bf(r);
    else
      AGGt[((size_t)b * NN + n) * C + c] = r;
  }
}

// ---------------------------------------------------------------- fused BN (+LReLU)
__global__ __launch_bounds__(256) void bn_fused_kernel(const float* __restrict__ z, int O,
                                                       float* __restrict__ out, int outBS, int c0) {
  int o = blockIdx.x;
  int tid = threadIdx.x;
  __shared__ float s1[256], s2[256];
  __shared__ float smv, srv;
  float a1 = 0.f, a2 = 0.f;
  for (int i = tid; i < BB * NN; i += 256) {
    int b = i >> 11, n = i & (NN - 1);
    float v = z[((size_t)b * O + o) * NN + n];
    a1 += v; a2 += v * v;
  }
  s1[tid] = a1; s2[tid] = a2;
  __syncthreads();
  for (int st = 128; st > 0; st >>= 1) {
    if (tid < st) { s1[tid] += s1[tid + st]; s2[tid] += s2[tid + st]; }
    __syncthreads();
  }
  if (tid == 0) {
    float m = s1[0] / (BB * NN);
    float var = s2[0] / (BB * NN) - m * m;
    smv = m; srv = rsqrtf(var + 1e-5f);
  }
  __syncthreads();
  float m = smv, r = srv;
  for (int i = tid; i < BB * NN; i += 256) {
    int b = i >> 11, n = i & (NN - 1);
    float v = (z[((size_t)b * O + o) * NN + n] - m) * r;
    out[(size_t)b * outBS + (c0 + o) * NN + n] = v >= 0.f ? v : 0.2f * v;
  }
}

// ---------------------------------------------------------------- BN+LReLU into h[:,0:O,:], copy xin into h[:,O:2O,:]
__global__ __launch_bounds__(256) void bn_copy_kernel(const float* __restrict__ z, int O,
                                                      const float* __restrict__ xin, int xbs,
                                                      float* __restrict__ out) {
  int o = blockIdx.x;  // 0..2O-1
  int tid = threadIdx.x;
  int outBS = 2 * O * NN;
  if (o >= O) {
    int c = o - O;
    for (int i = tid; i < BB * NN; i += 256) {
      int b = i >> 11, n = i & (NN - 1);
      out[(size_t)b * outBS + o * NN + n] = xin[(size_t)b * xbs + c * NN + n];
    }
    return;
  }
  __shared__ float s1[256], s2[256];
  __shared__ float smv, srv;
  float a1 = 0.f, a2 = 0.f;
  for (int i = tid; i < BB * NN; i += 256) {
    int b = i >> 11, n = i & (NN - 1);
    float v = z[((size_t)b * O + o) * NN + n];
    a1 += v; a2 += v * v;
  }
  s1[tid] = a1; s2[tid] = a2;
  __syncthreads();
  for (int st = 128; st > 0; st >>= 1) {
    if (tid < st) { s1[tid] += s1[tid + st]; s2[tid] += s2[tid + st]; }
    __syncthreads();
  }
  if (tid == 0) {
    float m = s1[0] / (BB * NN);
    float var = s2[0] / (BB * NN) - m * m;
    smv = m; srv = rsqrtf(var + 1e-5f);
  }
  __syncthreads();
  float m = smv, r = srv;
  for (int i = tid; i < BB * NN; i += 256) {
    int b = i >> 11, n = i & (NN - 1);
    float v = (z[((size_t)b * O + o) * NN + n] - m) * r;
    out[(size_t)b * outBS + o * NN + n] = v >= 0.f ? v : 0.2f * v;
  }
}

// ---------------------------------------------------------------- fused BN+LReLU+max/mean pool (conv5)
__global__ __launch_bounds__(256) void bn_pool_kernel(const float* __restrict__ z,
                                                      float* __restrict__ p) {
  int o = blockIdx.x;
  int tid = threadIdx.x;
  __shared__ float s1[256], s2[256];
  __shared__ float smv, srv;
  float a1 = 0.f, a2 = 0.f;
  for (int i = tid; i < BB * NN; i += 256) {
    int b = i >> 11, n = i & (NN - 1);
    float v = z[((size_t)b * 1024 + o) * NN + n];
    a1 += v; a2 += v * v;
  }
  s1[tid] = a1; s2[tid] = a2;
  __syncthreads();
  for (int st = 128; st > 0; st >>= 1) {
    if (tid < st) { s1[tid] += s1[tid + st]; s2[tid] += s2[tid + st]; }
    __syncthreads();
  }
  if (tid == 0) {
    float m = s1[0] / (BB * NN);
    float var = s2[0] / (BB * NN) - m * m;
    smv = m; srv = rsqrtf(var + 1e-5f);
  }
  __syncthreads();
  float m = smv, r = srv;
  int b = tid >> 5, l = tid & 31;
  const float* zp = z + ((size_t)b * 1024 + o) * NN;
  float mx = -INFINITY, sm = 0.f;
  for (int n = l; n < NN; n += 32) {
    float v = (zp[n] - m) * r;
    v = v >= 0.f ? v : 0.2f * v;
    mx = fmaxf(mx, v); sm += v;
  }
#pragma unroll
  for (int s = 16; s > 0; s >>= 1) {
    mx = fmaxf(mx, __shfl_xor(mx, s));
    sm += __shfl_xor(sm, s);
  }
  if (l == 0) {
    p[b * 2048 + o] = mx;
    p[b * 2048 + 1024 + o] = sm * (1.f / NN);
  }
}

__global__ __launch_bounds__(64) void linear_kernel(const float* __restrict__ in, int IN, int OUT,
                                                    const float* __restrict__ w,
                                                    const float* __restrict__ bias,
                                                    float* __restrict__ out) {
  int o = blockIdx.x;
  int b = o / OUT, f = o % OUT;
  const float* ip = in + (size_t)b * IN;
  const float* wp = w + (size_t)f * IN;
  float a = 0.f;
  for (int i = threadIdx.x; i < IN; i += 64) a += ip[i] * wp[i];
#pragma unroll
  for (int s = 32; s > 0; s >>= 1) a += __shfl_down(a, s);
  if (threadIdx.x == 0) out[o] = a + bias[f];
}

__global__ __launch_bounds__(256) void bnf_kernel(float* __restrict__ t, int F) {
  int f = blockIdx.x * blockDim.x + threadIdx.x;
  if (f >= F) return;
  float s = 0.f, s2 = 0.f;
  for (int b = 0; b < BB; ++b) { float v = t[b * F + f]; s += v; s2 += v * v; }
  float m = s * (1.f / BB);
  float var = s2 * (1.f / BB) - m * m;
  float r = rsqrtf(var + 1e-5f);
  for (int b = 0; b < BB; ++b) {
    float v = (t[b * F + f] - m) * r;
    t[b * F + f] = v >= 0.f ? v : 0.2f * v;
  }
}

// ---------------------------------------------------------------- host side

struct SAW { const float *wq, *wk, *wv, *wc; };

static inline void run_conv(const float* in, int inBS, int C, int O, const float* w,
                            float* z, hipStream_t st) {
  if (O % 128 == 0)
    conv_gemm128_db_kernel<<<dim3(NN / 128, O / 128, BB), 256, 0, st>>>(in, inBS, C, O, w, z);
  else
    conv_gemm_kernel<<<dim3(NN / 64, (O + 63) / 64, BB), 256, 0, st>>>(in, inBS, C, O, w, z);
}

// MFMA==true only valid for C multiple of 128.
template <int C, bool MFMA>
static inline void run_sa(const float* xin, int xbs, SAW w,
                          float* xT, float* U, float* UT, float* AGGt,
                          float* AGG, float* z, float* h, float* sq, int* idx,
                          float* M, float* WCV, unsigned short* Mb, unsigned short* wcvb,
                          unsigned short* xTb, unsigned short* AGGtb,
                          float* D, int nbatch, hipStream_t st) {
  sq_kernel<<<BB * NN / 256, 256, 0, st>>>(xin, xbs, C, sq);
  transpose_kernel<<<dim3(NN / 32, (C + 31) / 32, BB), 256, 0, st>>>(xin, xbs, C, NN, xT);
  mprep_kernel<<<(C * C + 255) / 256, 256, 0, st>>>(w.wq, w.wk, C, M);
  wcv_kernel<<<(C * C + 255) / 256, 256, 0, st>>>(w.wc, w.wv, C, WCV);
  if (MFMA) {
    convert_bf16_kernel<<<(C * C + 255) / 256, 256, 0, st>>>(M, Mb, C * C);
    convert_bf16_kernel<<<(C * C + 255) / 256, 256, 0, st>>>(WCV, wcvb, C * C);
    transpose_bf16_kernel<<<dim3(NN / 32, (C + 31) / 32, BB), 256, 0, st>>>(xin, xbs, C, NN, xTb);
  }
  for (int bb = 0; bb < BB; bb += nbatch) {
    int nbc = (BB - bb) < nbatch ? (BB - bb) : nbatch;
    pd_gemm128_db_kernel<<<dim3(NN / 128, NN / 128, nbc), 256, 0, st>>>(xin, xbs, C, sq, D, bb);
    topk_bsort_kernel<<<dim3(NN / 4, nbc), 256, 0, st>>>(D, idx, bb);
  }
  if (MFMA)
    mfma_gemm_lds_kernel<<<dim3(NN / 128, C / 128, BB), 256, 0, st>>>(Mb, xTb, U, C, C);
  else
    run_conv(xin, xbs, C, C, M, U, st);                            // U = M . x  [C][N]
  transpose_kernel<<<dim3(NN / 32, (C + 31) / 32, BB), 256, 0, st>>>(U, C * NN, C, NN, UT);
  if (MFMA) {
    att_wave_kernel<C, true><<<BB * NN, 64, 0, st>>>(xT, UT, idx, AGGt, AGGtb);
    mfma_gemm_lds_kernel<<<dim3(NN / 128, C / 128, BB), 256, 0, st>>>(wcvb, AGGtb, z, C, C);
  } else {
    att_wave_kernel<C, false><<<BB * NN, 64, 0, st>>>(xT, UT, idx, AGGt, AGGtb);
    transpose_kernel<<<dim3((C + 31) / 32, NN / 32, BB), 256, 0, st>>>(AGGt, NN * C, NN, C, AGG);
    run_conv(AGG, C * NN, C, C, WCV, z, st);                       // Z = (wc.wv) . AGG
  }
  bn_copy_kernel<<<2 * C, 256, 0, st>>>(z, C, xin, xbs, h);
}

static inline void run_conv_bn(const float* in, int inBS, int Cin, int O, const float* w,
                               float* z, float* out, int outBS, int c0, hipStream_t st) {
  run_conv(in, inBS, Cin, O, w, z, st);
  bn_fused_kernel<<<O, 256, 0, st>>>(z, O, out, outBS, c0);
}

extern "C" void kernel_launch(void* const* d_in, const int* in_sizes, int n_in,
                              void* d_out, int out_size, void* d_ws, size_t ws_size,
                              hipStream_t stream) {
  const float* x = (const float*)d_in[0];
  SAW sa1{(const float*)d_in[1], (const float*)d_in[2], (const float*)d_in[3], (const float*)d_in[4]};
  SAW sa2{(const float*)d_in[5], (const float*)d_in[6], (const float*)d_in[7], (const float*)d_in[8]};
  SAW sa3{(const float*)d_in[9], (const float*)d_in[10], (const float*)d_in[11], (const float*)d_in[12]};
  SAW sa4{(const float*)d_in[13], (const float*)d_in[14], (const float*)d_in[15], (const float*)d_in[16]};
  const float* conv1_w = (const float*)d_in[17];
  const float* conv2_w = (const float*)d_in[18];
  const float* conv3_w = (const float*)d_in[19];
  const float* conv4_w = (const float*)d_in[20];
  const float* conv5_w = (const float*)d_in[21];
  const float* lin1_w = (const float*)d_in[22];
  const float* lin1_b = (const float*)d_in[23];
  const float* lin2_w = (const float*)d_in[24];
  const float* lin2_b = (const float*)d_in[25];
  const float* lin3_w = (const float*)d_in[26];
  const float* lin3_b = (const float*)d_in[27];

  char* ws = (char*)d_ws;
  size_t off = 0;
  auto take = [&](size_t bytes) -> void* {
    void* p = ws + off;
    off += (bytes + 255) & ~(size_t)255;
    return p;
  };
  float* sq   = (float*)take((size_t)BB * NN * 4);
  int*   idx  = (int*)take((size_t)BB * NN * KNB * 4);
  float* M    = (float*)take((size_t)128 * 128 * 4);
  float* WCV  = (float*)take((size_t)128 * 128 * 4);
  unsigned short* Mb   = (unsigned short*)take((size_t)128 * 128 * 2);
  unsigned short* wcvb = (unsigned short*)take((size_t)128 * 128 * 2);
  unsigned short* w4b  = (unsigned short*)take((size_t)256 * 256 * 2);
  unsigned short* w5b  = (unsigned short*)take((size_t)1024 * 512 * 2);
  float* U    = (float*)take((size_t)BB * 128 * NN * 4);  // contiguous with AGG
  float* AGG  = (float*)take((size_t)BB * 128 * NN * 4);  // also hosts xT
  float* h    = (float*)take((size_t)BB * 256 * NN * 4);  // first half hosts UT
  float* z    = (float*)take((size_t)BB * 1024 * NN * 4); // hosts AGGt, AGGtb(+16MB), D-chunks
  float* xc   = (float*)take((size_t)BB * 512 * NN * 4);
  float* p    = (float*)take((size_t)BB * 2048 * 4);
  float* t1   = (float*)take((size_t)BB * 512 * 4);
  float* t2   = (float*)take((size_t)BB * 256 * 4);
  (void)n_in; (void)in_sizes; (void)out_size;

  // Overlays (phase-ordered lifetimes):
  float* xT = AGG;                                          // dead before AGG written
  float* UT = h;                                            // consumed before h written
  float* AGGt = z;                                          // first 8.4 MB of z
  unsigned short* xTb   = (unsigned short*)((char*)h + (size_t)BB * 128 * NN * 4);  // h 2nd half
  unsigned short* AGGtb = (unsigned short*)((char*)z + (size_t)16 * 1024 * 1024);   // z + 16 MB
  unsigned short* hTb   = (unsigned short*)U;               // conv4 phase (U dead)
  unsigned short* xcTb  = (unsigned short*)U;               // conv5 phase (U+AGG dead, 16.8 MB)

  size_t dfull = (size_t)BB * NN * NN * 4;
  bool fullD = (ws_size > off + dfull + 4096);
  float* D = fullD ? (float*)take(dfull) : z;               // !fullD: 4-batch chunks fill z exactly
  int nbatch = fullD ? BB : 4;

  // SA1 (C=3) -> h [B,6,N]
  run_sa<3, false>(x, 3 * NN, sa1, xT, U, UT, AGGt, AGG, z, h, sq, idx,
                   M, WCV, Mb, wcvb, xTb, AGGtb, D, nbatch, stream);
  run_conv_bn(h, 6 * NN, 6, 64, conv1_w, z, xc, 512 * NN, 0, stream);
  // SA2 (C=64) on x1
  run_sa<64, false>(xc + 0 * NN, 512 * NN, sa2, xT, U, UT, AGGt, AGG, z, h, sq, idx,
                    M, WCV, Mb, wcvb, xTb, AGGtb, D, nbatch, stream);
  run_conv_bn(h, 128 * NN, 128, 64, conv2_w, z, xc, 512 * NN, 64, stream);
  // SA3 (C=64) on x2
  run_sa<64, false>(xc + 64 * NN, 512 * NN, sa3, xT, U, UT, AGGt, AGG, z, h, sq, idx,
                    M, WCV, Mb, wcvb, xTb, AGGtb, D, nbatch, stream);
  run_conv_bn(h, 128 * NN, 128, 128, conv3_w, z, xc, 512 * NN, 128, stream);
  // SA4 (C=128) on x3 — bf16 MFMA for U and Z convs (no kNN downstream)
  run_sa<128, true>(xc + 128 * NN, 512 * NN, sa4, xT, U, UT, AGGt, AGG, z, h, sq, idx,
                    M, WCV, Mb, wcvb, xTb, AGGtb, D, nbatch, stream);
  // conv4 (bf16 MFMA): h [B,256,N] -> z [B,256,N]
  transpose_bf16_kernel<<<dim3(NN / 32, 8, BB), 256, 0, stream>>>(h, 256 * NN, 256, NN, hTb);
  convert_bf16_kernel<<<(256 * 256 + 255) / 256, 256, 0, stream>>>(conv4_w, w4b, 256 * 256);
  mfma_gemm_lds_kernel<<<dim3(NN / 128, 2, BB), 256, 0, stream>>>(w4b, hTb, z, 256, 256);
  bn_fused_kernel<<<256, 256, 0, stream>>>(z, 256, xc, 512 * NN, 256);
  // conv5 (bf16 MFMA): xc [B,512,N] -> z [B,1024,N]; BN+LReLU+pool -> p
  transpose_bf16_kernel<<<dim3(NN / 32, 16, BB), 256, 0, stream>>>(xc, 512 * NN, 512, NN, xcTb);
  convert_bf16_kernel<<<(1024 * 512 + 255) / 256, 256, 0, stream>>>(conv5_w, w5b, 1024 * 512);
  mfma_gemm_lds_kernel<<<dim3(NN / 128, 8, BB), 256, 0, stream>>>(w5b, xcTb, z, 1024, 512);
  bn_pool_kernel<<<1024, 256, 0, stream>>>(z, p);
  // FC head
  linear_kernel<<<BB * 512, 64, 0, stream>>>(p, 2048, 512, lin1_w, lin1_b, t1);
  bnf_kernel<<<2, 256, 0, stream>>>(t1, 512);
  linear_kernel<<<BB * 256, 64, 0, stream>>>(t1, 512, 256, lin2_w, lin2_b, t2);
  bnf_kernel<<<1, 256, 0, stream>>>(t2, 256);
  linear_kernel<<<BB * 40, 64, 0, stream>>>(t2, 256, 40, lin3_w, lin3_b, (float*)d_out);
}

// Round 15
// 1299.136 us; speedup vs baseline: 1.4706x; 1.0635x over previous
//
#include <hip/hip_runtime.h>
#include <math.h>

#define BB 8
#define NN 2048
#define KNB 20

typedef __attribute__((ext_vector_type(8))) short bf16x8;
typedef __attribute__((ext_vector_type(8))) _Float16 f16x8;
typedef __attribute__((ext_vector_type(4))) float f32x4;

__device__ inline unsigned short f2bf(float f) {
  union { float f; unsigned u; } v; v.f = f;
  unsigned r = v.u + 0x7FFF + ((v.u >> 16) & 1);  // RNE
  return (unsigned short)(r >> 16);
}

// ---------------------------------------------------------------- sq
__global__ __launch_bounds__(256) void sq_kernel(const float* __restrict__ x, int bs, int C,
                                                 float* __restrict__ sq) {
  int t = blockIdx.x * blockDim.x + threadIdx.x;
  int b = t / NN, n = t % NN;
  const float* xp = x + (size_t)b * bs + n;
  float s = 0.f;
  for (int c = 0; c < C; ++c) { float v = xp[c * NN]; s += v * v; }
  sq[t] = s;
}

// ---------------------------------------------------------------- M = wk^T wq
__global__ __launch_bounds__(256) void mprep_kernel(const float* __restrict__ wq,
                                                    const float* __restrict__ wk, int C,
                                                    float* __restrict__ M) {
  int T = blockIdx.x * 256 + threadIdx.x;
  if (T >= C * C) return;
  int c = T / C, cp = T % C;
  float a = 0.f;
  for (int e = 0; e < C; ++e) a += wk[e * C + c] * wq[e * C + cp];
  M[c * C + cp] = a;
}

// ---------------------------------------------------------------- wcv = wc @ wv
__global__ __launch_bounds__(256) void wcv_kernel(const float* __restrict__ wc,
                                                  const float* __restrict__ wv, int C,
                                                  float* __restrict__ out) {
  int T = blockIdx.x * 256 + threadIdx.x;
  if (T >= C * C) return;
  int o = T / C, c = T % C;
  float a = 0.f;
  for (int e = 0; e < C; ++e) a += wc[o * C + e] * wv[e * C + c];
  out[o * C + c] = a;
}

// ---------------------------------------------------------------- converts
__global__ __launch_bounds__(256) void convert_bf16_kernel(const float* __restrict__ in,
                                                           unsigned short* __restrict__ out,
                                                           int count) {
  int i = blockIdx.x * 256 + threadIdx.x;
  if (i < count) out[i] = f2bf(in[i]);
}

// ---------------------------------------------------------------- transpose (fp32)
__global__ __launch_bounds__(256) void transpose_kernel(const float* __restrict__ in, int inBS,
                                                        int R, int Cl, float* __restrict__ out) {
  __shared__ float tile[32][33];
  int b = blockIdx.z;
  const float* ip = in + (size_t)b * inBS;
  float* op = out + (size_t)b * R * Cl;
  int c0 = blockIdx.x * 32, r0 = blockIdx.y * 32;
  int tx = threadIdx.x & 31, ty = threadIdx.x >> 5;
  for (int yy = ty; yy < 32; yy += 8) {
    int r = r0 + yy, c = c0 + tx;
    tile[yy][tx] = (r < R && c < Cl) ? ip[(size_t)r * Cl + c] : 0.f;
  }
  __syncthreads();
  for (int yy = ty; yy < 32; yy += 8) {
    int c = c0 + yy, r = r0 + tx;
    if (c < Cl && r < R) op[(size_t)c * R + r] = tile[tx][yy];
  }
}

// ---------------------------------------------------------------- transpose + bf16 convert
__global__ __launch_bounds__(256) void transpose_bf16_kernel(const float* __restrict__ in, int inBS,
                                                             int R, int Cl,
                                                             unsigned short* __restrict__ out) {
  __shared__ float tile[32][33];
  int b = blockIdx.z;
  const float* ip = in + (size_t)b * inBS;
  unsigned short* op = out + (size_t)b * R * Cl;
  int c0 = blockIdx.x * 32, r0 = blockIdx.y * 32;
  int tx = threadIdx.x & 31, ty = threadIdx.x >> 5;
  for (int yy = ty; yy < 32; yy += 8) {
    int r = r0 + yy, c = c0 + tx;
    tile[yy][tx] = (r < R && c < Cl) ? ip[(size_t)r * Cl + c] : 0.f;
  }
  __syncthreads();
  for (int yy = ty; yy < 32; yy += 8) {
    int c = c0 + yy, r = r0 + tx;
    if (c < Cl && r < R) op[(size_t)c * R + r] = f2bf(tile[tx][yy]);
  }
}

// ---------------------------------------------------------------- transpose + fp16 hi/lo split
// hi = f16(v), lo = f16(v - hi): hi+lo carries ~22 mantissa bits; product sum
// hi.hi + hi.lo + lo.hi has ~5e-7 relative error (at/below fp32 dot noise).
__global__ __launch_bounds__(256) void transpose_f16split_kernel(
    const float* __restrict__ in, int inBS, int R, int Cl,
    _Float16* __restrict__ hi, _Float16* __restrict__ lo) {
  __shared__ float tile[32][33];
  int b = blockIdx.z;
  const float* ip = in + (size_t)b * inBS;
  _Float16* hp = hi + (size_t)b * R * Cl;
  _Float16* lp = lo + (size_t)b * R * Cl;
  int c0 = blockIdx.x * 32, r0 = blockIdx.y * 32;
  int tx = threadIdx.x & 31, ty = threadIdx.x >> 5;
  for (int yy = ty; yy < 32; yy += 8) {
    int r = r0 + yy, c = c0 + tx;
    tile[yy][tx] = (r < R && c < Cl) ? ip[(size_t)r * Cl + c] : 0.f;
  }
  __syncthreads();
  for (int yy = ty; yy < 32; yy += 8) {
    int c = c0 + yy, r = r0 + tx;
    if (c < Cl && r < R) {
      float v = tile[tx][yy];
      _Float16 hv = (_Float16)v;
      hp[(size_t)c * R + r] = hv;
      lp[(size_t)c * R + r] = (_Float16)(v - (float)hv);
    }
  }
}

// ---------------------------------------------------------------- MFMA GEMM, LDS double-buffered (bf16)
// Z[b][o][n] = sum_k A[o][k] * B[b][n][k]; A,B bf16 K-contiguous, Z fp32.
__global__ __launch_bounds__(256, 2) void mfma_gemm_lds_kernel(
    const unsigned short* __restrict__ A, const unsigned short* __restrict__ B,
    float* __restrict__ Z, int O, int K) {
  const int b = blockIdx.z;
  const int n0 = blockIdx.x * 128, o0 = blockIdx.y * 128;
  const int tid = threadIdx.x;
  const int wave = tid >> 6, lane = tid & 63;
  const int wo = wave >> 1, wn = wave & 1;   // 64x64 quadrant per wave
  const int l16 = lane & 15, q = lane >> 4;
  __shared__ unsigned short Al[2][4096];     // 128 rows x 32 k (8 KB), frag order
  __shared__ unsigned short Bl[2][4096];
  const unsigned short* Ab = A + (size_t)o0 * K;
  const unsigned short* Bb = B + ((size_t)b * NN + n0) * K;

  const int p0 = tid, p1 = tid + 256;
  const int r0 = ((p0 >> 6) << 4) | (p0 & 15), c0 = ((p0 >> 4) & 3) * 8;
  const int r1 = ((p1 >> 6) << 4) | (p1 & 15), c1 = ((p1 >> 4) & 3) * 8;

  bf16x8 ar0, ar1, br0, br1;
  auto gload = [&](int k0) {
    ar0 = *(const bf16x8*)(Ab + (size_t)r0 * K + k0 + c0);
    ar1 = *(const bf16x8*)(Ab + (size_t)r1 * K + k0 + c1);
    br0 = *(const bf16x8*)(Bb + (size_t)r0 * K + k0 + c0);
    br1 = *(const bf16x8*)(Bb + (size_t)r1 * K + k0 + c1);
  };
  auto sstore = [&](int buf) {
    *(bf16x8*)&Al[buf][p0 * 8] = ar0;
    *(bf16x8*)&Al[buf][p1 * 8] = ar1;
    *(bf16x8*)&Bl[buf][p0 * 8] = br0;
    *(bf16x8*)&Bl[buf][p1 * 8] = br1;
  };

  f32x4 acc[4][4];
#pragma unroll
  for (int s = 0; s < 4; ++s)
#pragma unroll
    for (int t = 0; t < 4; ++t) acc[s][t] = (f32x4){0.f, 0.f, 0.f, 0.f};

  gload(0);
  sstore(0);
  int cur = 0;
  for (int k0 = 0; k0 < K; k0 += 32) {
    bool more = (k0 + 32) < K;
    if (more) gload(k0 + 32);
    __syncthreads();
    bf16x8 af[4], bfr[4];
#pragma unroll
    for (int s = 0; s < 4; ++s)
      af[s] = *(const bf16x8*)&Al[cur][((wo * 4 + s) * 64 + q * 16 + l16) * 8];
#pragma unroll
    for (int t = 0; t < 4; ++t)
      bfr[t] = *(const bf16x8*)&Bl[cur][((wn * 4 + t) * 64 + q * 16 + l16) * 8];
#pragma unroll
    for (int s = 0; s < 4; ++s)
#pragma unroll
      for (int t = 0; t < 4; ++t)
        acc[s][t] = __builtin_amdgcn_mfma_f32_16x16x32_bf16(af[s], bfr[t], acc[s][t], 0, 0, 0);
    if (more) sstore(cur ^ 1);
    cur ^= 1;
  }
#pragma unroll
  for (int s = 0; s < 4; ++s)
#pragma unroll
    for (int t = 0; t < 4; ++t) {
      float* zp = Z + ((size_t)b * O + o0 + wo * 64 + s * 16 + q * 4) * NN
                  + n0 + wn * 64 + t * 16 + l16;
#pragma unroll
      for (int r = 0; r < 4; ++r) zp[(size_t)r * NN] = acc[s][t][r];
    }
}

// ---------------------------------------------------------------- pd via f16 split MFMA
// P[bl][n][m] = 2*(hi_n+lo_n).(hi_m+lo_m) - sq[m], computed as
// hi.hi + hi.lo + lo.hi (lo.lo ~2^-22, dropped). Relative error ~5e-7 — at
// fp32's own rounding level, so kNN selection is unchanged (r13 lesson:
// 2.4e-4 noise breaks it; this is 500x finer). 128x128 tile, 4-wave 64x64
// quadrants, single-buffered (32 KB LDS), 48 MFMA/wave/chunk. C%32==0.
__global__ __launch_bounds__(256, 2) void pd_mfma_kernel(
    const _Float16* __restrict__ xhi, const _Float16* __restrict__ xlo, int C,
    const float* __restrict__ sq, float* __restrict__ P, int b_base) {
  const int bl = blockIdx.z;
  const int b = b_base + bl;
  const int n0 = blockIdx.x * 128, m0 = blockIdx.y * 128;
  const int tid = threadIdx.x;
  const int wave = tid >> 6, lane = tid & 63;
  const int wn_ = wave >> 1, wm_ = wave & 1;   // n / m quadrant
  const int l16 = lane & 15, q = lane >> 4;
  __shared__ _Float16 Ah[4096], Al[4096], Bh[4096], Bl[4096];  // frag order, 8 KB each
  const _Float16* Ahg = xhi + ((size_t)b * NN + n0) * C;
  const _Float16* Alg = xlo + ((size_t)b * NN + n0) * C;
  const _Float16* Bhg = xhi + ((size_t)b * NN + m0) * C;
  const _Float16* Blg = xlo + ((size_t)b * NN + m0) * C;

  const int p0 = tid, p1 = tid + 256;
  const int r0 = ((p0 >> 6) << 4) | (p0 & 15), c0 = ((p0 >> 4) & 3) * 8;
  const int r1 = ((p1 >> 6) << 4) | (p1 & 15), c1 = ((p1 >> 4) & 3) * 8;

  f32x4 acc[4][4];
#pragma unroll
  for (int s = 0; s < 4; ++s)
#pragma unroll
    for (int t = 0; t < 4; ++t) acc[s][t] = (f32x4){0.f, 0.f, 0.f, 0.f};

  for (int k0 = 0; k0 < C; k0 += 32) {
    __syncthreads();
    *(f16x8*)&Ah[p0 * 8] = *(const f16x8*)(Ahg + (size_t)r0 * C + k0 + c0);
    *(f16x8*)&Ah[p1 * 8] = *(const f16x8*)(Ahg + (size_t)r1 * C + k0 + c1);
    *(f16x8*)&Al[p0 * 8] = *(const f16x8*)(Alg + (size_t)r0 * C + k0 + c0);
    *(f16x8*)&Al[p1 * 8] = *(const f16x8*)(Alg + (size_t)r1 * C + k0 + c1);
    *(f16x8*)&Bh[p0 * 8] = *(const f16x8*)(Bhg + (size_t)r0 * C + k0 + c0);
    *(f16x8*)&Bh[p1 * 8] = *(const f16x8*)(Bhg + (size_t)r1 * C + k0 + c1);
    *(f16x8*)&Bl[p0 * 8] = *(const f16x8*)(Blg + (size_t)r0 * C + k0 + c0);
    *(f16x8*)&Bl[p1 * 8] = *(const f16x8*)(Blg + (size_t)r1 * C + k0 + c1);
    __syncthreads();
    f16x8 ah[4], al[4], bh[4], blv[4];
#pragma unroll
    for (int s = 0; s < 4; ++s) {
      int pi = ((wn_ * 4 + s) * 64 + q * 16 + l16) * 8;
      ah[s] = *(const f16x8*)&Ah[pi];
      al[s] = *(const f16x8*)&Al[pi];
    }
#pragma unroll
    for (int t = 0; t < 4; ++t) {
      int pi = ((wm_ * 4 + t) * 64 + q * 16 + l16) * 8;
      bh[t] = *(const f16x8*)&Bh[pi];
      blv[t] = *(const f16x8*)&Bl[pi];
    }
#pragma unroll
    for (int s = 0; s < 4; ++s)
#pragma unroll
      for (int t = 0; t < 4; ++t) {
        acc[s][t] = __builtin_amdgcn_mfma_f32_16x16x32_f16(ah[s], bh[t], acc[s][t], 0, 0, 0);
        acc[s][t] = __builtin_amdgcn_mfma_f32_16x16x32_f16(ah[s], blv[t], acc[s][t], 0, 0, 0);
        acc[s][t] = __builtin_amdgcn_mfma_f32_16x16x32_f16(al[s], bh[t], acc[s][t], 0, 0, 0);
      }
  }
#pragma unroll
  for (int s = 0; s < 4; ++s)
#pragma unroll
    for (int t = 0; t < 4; ++t) {
      int col = m0 + wm_ * 64 + t * 16 + l16;
      float sqv = sq[b * NN + col];
      float* pp = P + ((size_t)bl * NN + n0 + wn_ * 64 + s * 16 + q * 4) * NN + col;
#pragma unroll
      for (int r = 0; r < 4; ++r) pp[(size_t)r * NN] = 2.f * acc[s][t][r] - sqv;
    }
}

// ---------------------------------------------------------------- pd GEMM 128-tile, fp32 (SA1, C=3)
__global__ __launch_bounds__(256, 2) void pd_gemm128_db_kernel(
    const float* __restrict__ x, int bs, int C, const float* __restrict__ sq,
    float* __restrict__ P, int b_base) {
  const int b = b_base + blockIdx.z;
  const int n0 = blockIdx.x * 128, m0 = blockIdx.y * 128;
  const int tid = threadIdx.x;
  const int tm = tid & 15, tn = tid >> 4;
  __shared__ float As[2][16][128], Bs[2][16][128];
  const float* xb = x + (size_t)b * bs;
  float acc[8][8];
#pragma unroll
  for (int i = 0; i < 8; ++i)
#pragma unroll
    for (int j = 0; j < 8; ++j) acc[i][j] = 0.f;

  float4 ara[2], arb[2];
  auto load_tile = [&](int k0) {
#pragma unroll
    for (int it = 0; it < 2; ++it) {
      int i = it * 256 + tid;
      int kc = i >> 5, c4 = i & 31;
      bool ok = (k0 + kc) < C;
      ara[it] = ok ? *(const float4*)&xb[(size_t)(k0 + kc) * NN + n0 + c4 * 4]
                   : make_float4(0.f, 0.f, 0.f, 0.f);
      arb[it] = ok ? *(const float4*)&xb[(size_t)(k0 + kc) * NN + m0 + c4 * 4]
                   : make_float4(0.f, 0.f, 0.f, 0.f);
    }
  };
  auto store_tile = [&](int buf) {
#pragma unroll
    for (int it = 0; it < 2; ++it) {
      int i = it * 256 + tid;
      int kc = i >> 5, c4 = i & 31;
      *(float4*)&As[buf][kc][c4 * 4] = ara[it];
      *(float4*)&Bs[buf][kc][c4 * 4] = arb[it];
    }
  };

  load_tile(0);
  store_tile(0);
  int cur = 0;
  for (int k0 = 0; k0 < C; k0 += 16) {
    bool more = (k0 + 16) < C;
    if (more) load_tile(k0 + 16);
    __syncthreads();
#pragma unroll
    for (int kc = 0; kc < 16; ++kc) {
      float4 a0 = *(const float4*)&As[cur][kc][tn * 4];
      float4 a1 = *(const float4*)&As[cur][kc][64 + tn * 4];
      float4 b0 = *(const float4*)&Bs[cur][kc][tm * 4];
      float4 b1 = *(const float4*)&Bs[cur][kc][64 + tm * 4];
      float ar[8] = {a0.x, a0.y, a0.z, a0.w, a1.x, a1.y, a1.z, a1.w};
      float br[8] = {b0.x, b0.y, b0.z, b0.w, b1.x, b1.y, b1.z, b1.w};
#pragma unroll
      for (int i = 0; i < 8; ++i)
#pragma unroll
        for (int j = 0; j < 8; ++j) acc[i][j] += ar[i] * br[j];
    }
    if (more) store_tile(cur ^ 1);
    cur ^= 1;
  }
  float4 sqa = *(const float4*)&sq[b * NN + m0 + tm * 4];
  float4 sqb = *(const float4*)&sq[b * NN + m0 + 64 + tm * 4];
#pragma unroll
  for (int h = 0; h < 2; ++h)
#pragma unroll
    for (int i = 0; i < 4; ++i) {
      int r = h * 4 + i;
      int nn = n0 + h * 64 + tn * 4 + i;
      float* prow = &P[((size_t)blockIdx.z * NN + nn) * NN + m0];
      float4 o0, o1;
      o0.x = 2.f * acc[r][0] - sqa.x; o0.y = 2.f * acc[r][1] - sqa.y;
      o0.z = 2.f * acc[r][2] - sqa.z; o0.w = 2.f * acc[r][3] - sqa.w;
      o1.x = 2.f * acc[r][4] - sqb.x; o1.y = 2.f * acc[r][5] - sqb.y;
      o1.z = 2.f * acc[r][6] - sqb.z; o1.w = 2.f * acc[r][7] - sqb.w;
      *(float4*)&prow[tm * 4] = o0;
      *(float4*)&prow[64 + tm * 4] = o1;
    }
}

// ---------------------------------------------------------------- top-20: EXACT-key bitonic + idx array
// (r13 errata: truncated keys break selection; exact 32-bit keys required.)
__global__ __launch_bounds__(256) void topk_bsort_kernel(const float* __restrict__ P,
                                                         int* __restrict__ idx_out, int b_base) {
  const int wave = threadIdx.x >> 6;
  const int lane = threadIdx.x & 63;
  const int n = blockIdx.x * 4 + wave;
  const int bl = blockIdx.y;
  const int b = b_base + bl;
  const float4* rp = (const float4*)(P + ((size_t)bl * NN + n) * NN);
  unsigned key[32], mv[32];
#pragma unroll
  for (int q = 0; q < 8; ++q) {
    float4 vv = rp[q * 64 + lane];
    int mb = q * 256 + lane * 4;
    float fv[4] = {vv.x, vv.y, vv.z, vv.w};
#pragma unroll
    for (int j = 0; j < 4; ++j) {
      unsigned u = __float_as_uint(fv[j]);
      unsigned mask = (unsigned)(((int)u) >> 31) | 0x80000000u;  // orderable transform
      key[q * 4 + j] = (mb + j == n) ? 0u : (u ^ mask);
      mv[q * 4 + j] = (unsigned)(mb + j);
    }
  }
#pragma unroll
  for (int k = 2; k <= 32; k <<= 1) {
#pragma unroll
    for (int j = k >> 1; j > 0; j >>= 1) {
#pragma unroll
      for (int i = 0; i < 32; ++i) {
        int l = i ^ j;
        if (l > i) {
          unsigned ka = key[i], kb = key[l];
          unsigned ia = mv[i], ib = mv[l];
          bool agt = ka > kb;
          unsigned kmax = agt ? ka : kb, kmin = agt ? kb : ka;
          unsigned imax = agt ? ia : ib, imin = agt ? ib : ia;
          if ((i & k) == 0) { key[i] = kmax; mv[i] = imax; key[l] = kmin; mv[l] = imin; }
          else              { key[i] = kmin; mv[i] = imin; key[l] = kmax; mv[l] = imax; }
        }
      }
    }
  }
  int* op = idx_out + (size_t)(b * NN + n) * KNB;
  for (int k = 0; k < KNB; ++k) {
    unsigned best = key[0];
#pragma unroll
    for (int s = 32; s > 0; s >>= 1) {
      unsigned o = (unsigned)__shfl_xor((int)best, s);
      best = best > o ? best : o;
    }
    bool own = (key[0] == best);
    if (own) {
      op[k] = (int)mv[0];
#pragma unroll
      for (int j = 0; j < 20; ++j) { key[j] = key[j + 1]; mv[j] = mv[j + 1]; }
    }
  }
}

// ---------------------------------------------------------------- conv GEMM 64-tile (small O)
__global__ __launch_bounds__(256, 2) void conv_gemm_kernel(
    const float* __restrict__ in, int inBS, int C, int O,
    const float* __restrict__ w, float* __restrict__ z) {
  const int b = blockIdx.z;
  const int n0 = blockIdx.x * 64, o0 = blockIdx.y * 64;
  const int tid = threadIdx.x;
  const int tm = tid & 15, tn = tid >> 4;
  __shared__ float Ws[16][68];
  __shared__ float Xs[16][64];
  const float* ib = in + (size_t)b * inBS;
  float acc[4][4];
#pragma unroll
  for (int i = 0; i < 4; ++i)
#pragma unroll
    for (int j = 0; j < 4; ++j) acc[i][j] = 0.f;

  for (int k0 = 0; k0 < C; k0 += 16) {
    __syncthreads();
#pragma unroll
    for (int it = 0; it < 4; ++it) {
      int i = it * 256 + tid;
      int kc = i >> 6, nl = i & 63;
      Xs[kc][nl] = ((k0 + kc) < C) ? ib[(size_t)(k0 + kc) * NN + n0 + nl] : 0.f;
      int ol = i >> 4, kc2 = i & 15;
      Ws[kc2][ol] = ((o0 + ol) < O && (k0 + kc2) < C) ? w[(size_t)(o0 + ol) * C + k0 + kc2] : 0.f;
    }
    __syncthreads();
#pragma unroll
    for (int kc = 0; kc < 16; ++kc) {
      float4 a = *(const float4*)&Ws[kc][tn * 4];
      float4 bv = *(const float4*)&Xs[kc][tm * 4];
      acc[0][0] += a.x * bv.x; acc[0][1] += a.x * bv.y; acc[0][2] += a.x * bv.z; acc[0][3] += a.x * bv.w;
      acc[1][0] += a.y * bv.x; acc[1][1] += a.y * bv.y; acc[1][2] += a.y * bv.z; acc[1][3] += a.y * bv.w;
      acc[2][0] += a.z * bv.x; acc[2][1] += a.z * bv.y; acc[2][2] += a.z * bv.z; acc[2][3] += a.z * bv.w;
      acc[3][0] += a.w * bv.x; acc[3][1] += a.w * bv.y; acc[3][2] += a.w * bv.z; acc[3][3] += a.w * bv.w;
    }
  }
#pragma unroll
  for (int i = 0; i < 4; ++i) {
    int o = o0 + tn * 4 + i;
    if (o < O) {
      float4 ov;
      ov.x = acc[i][0]; ov.y = acc[i][1]; ov.z = acc[i][2]; ov.w = acc[i][3];
      *(float4*)&z[((size_t)b * O + o) * NN + n0 + tm * 4] = ov;
    }
  }
}

// ---------------------------------------------------------------- conv GEMM 128-tile, double-buffered (fp32)
__global__ __launch_bounds__(256, 2) void conv_gemm128_db_kernel(
    const float* __restrict__ in, int inBS, int C, int O,
    const float* __restrict__ w, float* __restrict__ z) {
  const int b = blockIdx.z;
  const int n0 = blockIdx.x * 128, o0 = blockIdx.y * 128;
  const int tid = threadIdx.x;
  const int tm = tid & 15, tn = tid >> 4;
  __shared__ float Xs[2][16][128];
  __shared__ float Ws[2][16][132];
  const float* ib = in + (size_t)b * inBS;
  float acc[8][8];
#pragma unroll
  for (int i = 0; i < 8; ++i)
#pragma unroll
    for (int j = 0; j < 8; ++j) acc[i][j] = 0.f;

  float4 xr[2], wr[2];
  auto load_tile = [&](int k0) {
#pragma unroll
    for (int it = 0; it < 2; ++it) {
      int i = it * 256 + tid;
      int kc = i >> 5, c4 = i & 31;
      xr[it] = ((k0 + kc) < C) ? *(const float4*)&ib[(size_t)(k0 + kc) * NN + n0 + c4 * 4]
                               : make_float4(0.f, 0.f, 0.f, 0.f);
      int ol = i >> 2, kq = i & 3;
      wr[it] = ((k0 + kq * 4) < C) ? *(const float4*)&w[(size_t)(o0 + ol) * C + k0 + kq * 4]
                                   : make_float4(0.f, 0.f, 0.f, 0.f);
    }
  };
  auto store_tile = [&](int buf) {
#pragma unroll
    for (int it = 0; it < 2; ++it) {
      int i = it * 256 + tid;
      int kc = i >> 5, c4 = i & 31;
      *(float4*)&Xs[buf][kc][c4 * 4] = xr[it];
      int ol = i >> 2, kq = i & 3;
      Ws[buf][kq * 4 + 0][ol] = wr[it].x;
      Ws[buf][kq * 4 + 1][ol] = wr[it].y;
      Ws[buf][kq * 4 + 2][ol] = wr[it].z;
      Ws[buf][kq * 4 + 3][ol] = wr[it].w;
    }
  };

  load_tile(0);
  store_tile(0);
  int cur = 0;
  for (int k0 = 0; k0 < C; k0 += 16) {
    bool more = (k0 + 16) < C;
    if (more) load_tile(k0 + 16);
    __syncthreads();
#pragma unroll
    for (int kc = 0; kc < 16; ++kc) {
      float4 a0 = *(const float4*)&Ws[cur][kc][tn * 4];
      float4 a1 = *(const float4*)&Ws[cur][kc][64 + tn * 4];
      float4 b0 = *(const float4*)&Xs[cur][kc][tm * 4];
      float4 b1 = *(const float4*)&Xs[cur][kc][64 + tm * 4];
      float ar[8] = {a0.x, a0.y, a0.z, a0.w, a1.x, a1.y, a1.z, a1.w};
      float br[8] = {b0.x, b0.y, b0.z, b0.w, b1.x, b1.y, b1.z, b1.w};
#pragma unroll
      for (int i = 0; i < 8; ++i)
#pragma unroll
        for (int j = 0; j < 8; ++j) acc[i][j] += ar[i] * br[j];
    }
    if (more) store_tile(cur ^ 1);
    cur ^= 1;
  }
#pragma unroll
  for (int h = 0; h < 2; ++h)
#pragma unroll
    for (int i = 0; i < 4; ++i) {
      int r = h * 4 + i;
      int o = o0 + h * 64 + tn * 4 + i;
      float* zrow = &z[((size_t)b * O + o) * NN + n0];
      float4 o0v, o1v;
      o0v.x = acc[r][0]; o0v.y = acc[r][1]; o0v.z = acc[r][2]; o0v.w = acc[r][3];
      o1v.x = acc[r][4]; o1v.y = acc[r][5]; o1v.z = acc[r][6]; o1v.w = acc[r][7];
      *(float4*)&zrow[tm * 4] = o0v;
      *(float4*)&zrow[64 + tm * 4] = o1v;
    }
}

// ---------------------------------------------------------------- attention (wave/point)
template <int C, bool BF16OUT>
__global__ __launch_bounds__(64) void att_wave_kernel(
    const float* __restrict__ xT, const float* __restrict__ UT,
    const int* __restrict__ idx, float* __restrict__ AGGt,
    unsigned short* __restrict__ AGGtb) {
  const int n = blockIdx.x & (NN - 1);
  const int b = blockIdx.x >> 11;
  const int lane = threadIdx.x;
  constexpr int CP = C + 1;
  __shared__ float nb[KNB][CP];
  __shared__ float sl[KNB];
  __shared__ int nidx[KNB];
  __shared__ float ul[C];
  const float* xTb = xT + (size_t)b * NN * C;
  if (lane < KNB) nidx[lane] = idx[(size_t)(b * NN + n) * KNB + lane];
  for (int c = lane; c < C; c += 64) ul[c] = UT[((size_t)b * NN + n) * C + c];
  __syncthreads();
  for (int i = lane; i < KNB * C; i += 64) {
    int k = i / C, c = i - k * C;
    nb[k][c] = xTb[(size_t)nidx[k] * C + c];
  }
  __syncthreads();
  float sv = -INFINITY;
  if (lane < KNB) {
    float a = 0.f;
#pragma unroll
    for (int c = 0; c < C; ++c) a += nb[lane][c] * ul[c];
    sv = a / sqrtf((float)C);
  }
  float mx = sv;
#pragma unroll
  for (int s = 32; s > 0; s >>= 1) mx = fmaxf(mx, __shfl_xor(mx, s));
  float e = (lane < KNB) ? expf(sv - mx) : 0.f;
  float sum = e;
#pragma unroll
  for (int s = 32; s > 0; s >>= 1) sum += __shfl_xor(sum, s);
  if (lane < KNB) sl[lane] = e / sum;
  __syncthreads();
  const float* xTn = xTb + (size_t)n * C;
  for (int c = lane; c < C; c += 64) {
    float a = 0.f;
#pragma unroll
    for (int k = 0; k < KNB; ++k) a += sl[k] * nb[k][c];
    float r = a - xTn[c];
    if (BF16OUT)
      AGGtb[((size_t)b * NN + n) * C + c] = f2bf(r);
    else
      AGGt[((size_t)b * NN + n) * C + c] = r;
  }
}

// ---------------------------------------------------------------- fused BN (+LReLU)
__global__ __launch_bounds__(256) void bn_fused_kernel(const float* __restrict__ z, int O,
                                                       float* __restrict__ out, int outBS, int c0) {
  int o = blockIdx.x;
  int tid = threadIdx.x;
  __shared__ float s1[256], s2[256];
  __shared__ float smv, srv;
  float a1 = 0.f, a2 = 0.f;
  for (int i = tid; i < BB * NN; i += 256) {
    int b = i >> 11, n = i & (NN - 1);
    float v = z[((size_t)b * O + o) * NN + n];
    a1 += v; a2 += v * v;
  }
  s1[tid] = a1; s2[tid] = a2;
  __syncthreads();
  for (int st = 128; st > 0; st >>= 1) {
    if (tid < st) { s1[tid] += s1[tid + st]; s2[tid] += s2[tid + st]; }
    __syncthreads();
  }
  if (tid == 0) {
    float m = s1[0] / (BB * NN);
    float var = s2[0] / (BB * NN) - m * m;
    smv = m; srv = rsqrtf(var + 1e-5f);
  }
  __syncthreads();
  float m = smv, r = srv;
  for (int i = tid; i < BB * NN; i += 256) {
    int b = i >> 11, n = i & (NN - 1);
    float v = (z[((size_t)b * O + o) * NN + n] - m) * r;
    out[(size_t)b * outBS + (c0 + o) * NN + n] = v >= 0.f ? v : 0.2f * v;
  }
}

// ---------------------------------------------------------------- BN+LReLU into h[:,0:O,:], copy xin into h[:,O:2O,:]
__global__ __launch_bounds__(256) void bn_copy_kernel(const float* __restrict__ z, int O,
                                                      const float* __restrict__ xin, int xbs,
                                                      float* __restrict__ out) {
  int o = blockIdx.x;  // 0..2O-1
  int tid = threadIdx.x;
  int outBS = 2 * O * NN;
  if (o >= O) {
    int c = o - O;
    for (int i = tid; i < BB * NN; i += 256) {
      int b = i >> 11, n = i & (NN - 1);
      out[(size_t)b * outBS + o * NN + n] = xin[(size_t)b * xbs + c * NN + n];
    }
    return;
  }
  __shared__ float s1[256], s2[256];
  __shared__ float smv, srv;
  float a1 = 0.f, a2 = 0.f;
  for (int i = tid; i < BB * NN; i += 256) {
    int b = i >> 11, n = i & (NN - 1);
    float v = z[((size_t)b * O + o) * NN + n];
    a1 += v; a2 += v * v;
  }
  s1[tid] = a1; s2[tid] = a2;
  __syncthreads();
  for (int st = 128; st > 0; st >>= 1) {
    if (tid < st) { s1[tid] += s1[tid + st]; s2[tid] += s2[tid + st]; }
    __syncthreads();
  }
  if (tid == 0) {
    float m = s1[0] / (BB * NN);
    float var = s2[0] / (BB * NN) - m * m;
    smv = m; srv = rsqrtf(var + 1e-5f);
  }
  __syncthreads();
  float m = smv, r = srv;
  for (int i = tid; i < BB * NN; i += 256) {
    int b = i >> 11, n = i & (NN - 1);
    float v = (z[((size_t)b * O + o) * NN + n] - m) * r;
    out[(size_t)b * outBS + o * NN + n] = v >= 0.f ? v : 0.2f * v;
  }
}

// ---------------------------------------------------------------- fused BN+LReLU+max/mean pool (conv5)
__global__ __launch_bounds__(256) void bn_pool_kernel(const float* __restrict__ z,
                                                      float* __restrict__ p) {
  int o = blockIdx.x;
  int tid = threadIdx.x;
  __shared__ float s1[256], s2[256];
  __shared__ float smv, srv;
  float a1 = 0.f, a2 = 0.f;
  for (int i = tid; i < BB * NN; i += 256) {
    int b = i >> 11, n = i & (NN - 1);
    float v = z[((size_t)b * 1024 + o) * NN + n];
    a1 += v; a2 += v * v;
  }
  s1[tid] = a1; s2[tid] = a2;
  __syncthreads();
  for (int st = 128; st > 0; st >>= 1) {
    if (tid < st) { s1[tid] += s1[tid + st]; s2[tid] += s2[tid + st]; }
    __syncthreads();
  }
  if (tid == 0) {
    float m = s1[0] / (BB * NN);
    float var = s2[0] / (BB * NN) - m * m;
    smv = m; srv = rsqrtf(var + 1e-5f);
  }
  __syncthreads();
  float m = smv, r = srv;
  int b = tid >> 5, l = tid & 31;
  const float* zp = z + ((size_t)b * 1024 + o) * NN;
  float mx = -INFINITY, sm = 0.f;
  for (int n = l; n < NN; n += 32) {
    float v = (zp[n] - m) * r;
    v = v >= 0.f ? v : 0.2f * v;
    mx = fmaxf(mx, v); sm += v;
  }
#pragma unroll
  for (int s = 16; s > 0; s >>= 1) {
    mx = fmaxf(mx, __shfl_xor(mx, s));
    sm += __shfl_xor(sm, s);
  }
  if (l == 0) {
    p[b * 2048 + o] = mx;
    p[b * 2048 + 1024 + o] = sm * (1.f / NN);
  }
}

__global__ __launch_bounds__(64) void linear_kernel(const float* __restrict__ in, int IN, int OUT,
                                                    const float* __restrict__ w,
                                                    const float* __restrict__ bias,
                                                    float* __restrict__ out) {
  int o = blockIdx.x;
  int b = o / OUT, f = o % OUT;
  const float* ip = in + (size_t)b * IN;
  const float* wp = w + (size_t)f * IN;
  float a = 0.f;
  for (int i = threadIdx.x; i < IN; i += 64) a += ip[i] * wp[i];
#pragma unroll
  for (int s = 32; s > 0; s >>= 1) a += __shfl_down(a, s);
  if (threadIdx.x == 0) out[o] = a + bias[f];
}

__global__ __launch_bounds__(256) void bnf_kernel(float* __restrict__ t, int F) {
  int f = blockIdx.x * blockDim.x + threadIdx.x;
  if (f >= F) return;
  float s = 0.f, s2 = 0.f;
  for (int b = 0; b < BB; ++b) { float v = t[b * F + f]; s += v; s2 += v * v; }
  float m = s * (1.f / BB);
  float var = s2 * (1.f / BB) - m * m;
  float r = rsqrtf(var + 1e-5f);
  for (int b = 0; b < BB; ++b) {
    float v = (t[b * F + f] - m) * r;
    t[b * F + f] = v >= 0.f ? v : 0.2f * v;
  }
}

// ---------------------------------------------------------------- host side

struct SAW { const float *wq, *wk, *wv, *wc; };

static inline void run_conv(const float* in, int inBS, int C, int O, const float* w,
                            float* z, hipStream_t st) {
  if (O % 128 == 0)
    conv_gemm128_db_kernel<<<dim3(NN / 128, O / 128, BB), 256, 0, st>>>(in, inBS, C, O, w, z);
  else
    conv_gemm_kernel<<<dim3(NN / 64, (O + 63) / 64, BB), 256, 0, st>>>(in, inBS, C, O, w, z);
}

// MFMA==true only valid for C multiple of 128; PDM (f16-split pd) for C%32==0.
template <int C, bool MFMA>
static inline void run_sa(const float* xin, int xbs, SAW w,
                          float* xT, float* U, float* UT, float* AGGt,
                          float* AGG, float* z, float* h, float* sq, int* idx,
                          float* M, float* WCV, unsigned short* Mb, unsigned short* wcvb,
                          unsigned short* xTb, unsigned short* AGGtb,
                          _Float16* xhi, _Float16* xlo,
                          float* D, int nbatch, hipStream_t st) {
  constexpr bool PDM = (C % 32 == 0);
  sq_kernel<<<BB * NN / 256, 256, 0, st>>>(xin, xbs, C, sq);
  transpose_kernel<<<dim3(NN / 32, (C + 31) / 32, BB), 256, 0, st>>>(xin, xbs, C, NN, xT);
  mprep_kernel<<<(C * C + 255) / 256, 256, 0, st>>>(w.wq, w.wk, C, M);
  wcv_kernel<<<(C * C + 255) / 256, 256, 0, st>>>(w.wc, w.wv, C, WCV);
  if (PDM)
    transpose_f16split_kernel<<<dim3(NN / 32, (C + 31) / 32, BB), 256, 0, st>>>(
        xin, xbs, C, NN, xhi, xlo);
  if (MFMA) {
    convert_bf16_kernel<<<(C * C + 255) / 256, 256, 0, st>>>(M, Mb, C * C);
    convert_bf16_kernel<<<(C * C + 255) / 256, 256, 0, st>>>(WCV, wcvb, C * C);
    transpose_bf16_kernel<<<dim3(NN / 32, (C + 31) / 32, BB), 256, 0, st>>>(xin, xbs, C, NN, xTb);
  }
  for (int bb = 0; bb < BB; bb += nbatch) {
    int nbc = (BB - bb) < nbatch ? (BB - bb) : nbatch;
    if (PDM)
      pd_mfma_kernel<<<dim3(16, 16, nbc), 256, 0, st>>>(xhi, xlo, C, sq, D, bb);
    else
      pd_gemm128_db_kernel<<<dim3(NN / 128, NN / 128, nbc), 256, 0, st>>>(xin, xbs, C, sq, D, bb);
    topk_bsort_kernel<<<dim3(NN / 4, nbc), 256, 0, st>>>(D, idx, bb);
  }
  if (MFMA)
    mfma_gemm_lds_kernel<<<dim3(NN / 128, C / 128, BB), 256, 0, st>>>(Mb, xTb, U, C, C);
  else
    run_conv(xin, xbs, C, C, M, U, st);                            // U = M . x  [C][N]
  transpose_kernel<<<dim3(NN / 32, (C + 31) / 32, BB), 256, 0, st>>>(U, C * NN, C, NN, UT);
  if (MFMA) {
    att_wave_kernel<C, true><<<BB * NN, 64, 0, st>>>(xT, UT, idx, AGGt, AGGtb);
    mfma_gemm_lds_kernel<<<dim3(NN / 128, C / 128, BB), 256, 0, st>>>(wcvb, AGGtb, z, C, C);
  } else {
    att_wave_kernel<C, false><<<BB * NN, 64, 0, st>>>(xT, UT, idx, AGGt, AGGtb);
    transpose_kernel<<<dim3((C + 31) / 32, NN / 32, BB), 256, 0, st>>>(AGGt, NN * C, NN, C, AGG);
    run_conv(AGG, C * NN, C, C, WCV, z, st);                       // Z = (wc.wv) . AGG
  }
  bn_copy_kernel<<<2 * C, 256, 0, st>>>(z, C, xin, xbs, h);
}

static inline void run_conv_bn(const float* in, int inBS, int Cin, int O, const float* w,
                               float* z, float* out, int outBS, int c0, hipStream_t st) {
  run_conv(in, inBS, Cin, O, w, z, st);
  bn_fused_kernel<<<O, 256, 0, st>>>(z, O, out, outBS, c0);
}

extern "C" void kernel_launch(void* const* d_in, const int* in_sizes, int n_in,
                              void* d_out, int out_size, void* d_ws, size_t ws_size,
                              hipStream_t stream) {
  const float* x = (const float*)d_in[0];
  SAW sa1{(const float*)d_in[1], (const float*)d_in[2], (const float*)d_in[3], (const float*)d_in[4]};
  SAW sa2{(const float*)d_in[5], (const float*)d_in[6], (const float*)d_in[7], (const float*)d_in[8]};
  SAW sa3{(const float*)d_in[9], (const float*)d_in[10], (const float*)d_in[11], (const float*)d_in[12]};
  SAW sa4{(const float*)d_in[13], (const float*)d_in[14], (const float*)d_in[15], (const float*)d_in[16]};
  const float* conv1_w = (const float*)d_in[17];
  const float* conv2_w = (const float*)d_in[18];
  const float* conv3_w = (const float*)d_in[19];
  const float* conv4_w = (const float*)d_in[20];
  const float* conv5_w = (const float*)d_in[21];
  const float* lin1_w = (const float*)d_in[22];
  const float* lin1_b = (const float*)d_in[23];
  const float* lin2_w = (const float*)d_in[24];
  const float* lin2_b = (const float*)d_in[25];
  const float* lin3_w = (const float*)d_in[26];
  const float* lin3_b = (const float*)d_in[27];

  char* ws = (char*)d_ws;
  size_t off = 0;
  auto take = [&](size_t bytes) -> void* {
    void* p = ws + off;
    off += (bytes + 255) & ~(size_t)255;
    return p;
  };
  float* sq   = (float*)take((size_t)BB * NN * 4);
  int*   idx  = (int*)take((size_t)BB * NN * KNB * 4);
  float* M    = (float*)take((size_t)128 * 128 * 4);
  float* WCV  = (float*)take((size_t)128 * 128 * 4);
  unsigned short* Mb   = (unsigned short*)take((size_t)128 * 128 * 2);
  unsigned short* wcvb = (unsigned short*)take((size_t)128 * 128 * 2);
  unsigned short* w4b  = (unsigned short*)take((size_t)256 * 256 * 2);
  unsigned short* w5b  = (unsigned short*)take((size_t)1024 * 512 * 2);
  float* U    = (float*)take((size_t)BB * 128 * NN * 4);  // contiguous with AGG
  float* AGG  = (float*)take((size_t)BB * 128 * NN * 4);  // also hosts xT
  float* h    = (float*)take((size_t)BB * 256 * NN * 4);  // overlays below
  float* z    = (float*)take((size_t)BB * 1024 * NN * 4); // hosts AGGt, AGGtb(+16MB), D-chunks
  float* xc   = (float*)take((size_t)BB * 512 * NN * 4);
  float* p    = (float*)take((size_t)BB * 2048 * 4);
  float* t1   = (float*)take((size_t)BB * 512 * 4);
  float* t2   = (float*)take((size_t)BB * 256 * 4);
  (void)n_in; (void)in_sizes; (void)out_size;

  // Overlays (phase-ordered lifetimes):
  float* xT = AGG;                                          // dead before AGG written
  float* UT = h;                                            // consumed before h written
  float* AGGt = z;                                          // first 8.4 MB of z
  unsigned short* xTb   = (unsigned short*)((char*)h + (size_t)BB * 128 * NN * 4);  // h 2nd half
  unsigned short* AGGtb = (unsigned short*)((char*)z + (size_t)16 * 1024 * 1024);   // z + 16 MB
  unsigned short* hTb   = (unsigned short*)U;               // conv4 phase (U dead)
  unsigned short* xcTb  = (unsigned short*)U;               // conv5 phase (U+AGG dead, 16.8 MB)
  // f16 hi/lo split of x for pd: live only before pd loop ends; UT (same
  // region) is written strictly after. 4 MB each at C=128 (exact fit in the
  // 8.4 MB UT half; no overlap with xTb at h+8.39 MB).
  _Float16* xhi = (_Float16*)h;
  _Float16* xlo = (_Float16*)((char*)h + (size_t)BB * NN * 128 * 2);

  size_t dfull = (size_t)BB * NN * NN * 4;
  bool fullD = (ws_size > off + dfull + 4096);
  float* D = fullD ? (float*)take(dfull) : z;               // !fullD: 4-batch chunks fill z exactly
  int nbatch = fullD ? BB : 4;

  // SA1 (C=3) -> h [B,6,N]  (fp32 pd; C=3 not MFMA-tileable)
  run_sa<3, false>(x, 3 * NN, sa1, xT, U, UT, AGGt, AGG, z, h, sq, idx,
                   M, WCV, Mb, wcvb, xTb, AGGtb, xhi, xlo, D, nbatch, stream);
  run_conv_bn(h, 6 * NN, 6, 64, conv1_w, z, xc, 512 * NN, 0, stream);
  // SA2 (C=64) on x1  (f16-split MFMA pd)
  run_sa<64, false>(xc + 0 * NN, 512 * NN, sa2, xT, U, UT, AGGt, AGG, z, h, sq, idx,
                    M, WCV, Mb, wcvb, xTb, AGGtb, xhi, xlo, D, nbatch, stream);
  run_conv_bn(h, 128 * NN, 128, 64, conv2_w, z, xc, 512 * NN, 64, stream);
  // SA3 (C=64) on x2
  run_sa<64, false>(xc + 64 * NN, 512 * NN, sa3, xT, U, UT, AGGt, AGG, z, h, sq, idx,
                    M, WCV, Mb, wcvb, xTb, AGGtb, xhi, xlo, D, nbatch, stream);
  run_conv_bn(h, 128 * NN, 128, 128, conv3_w, z, xc, 512 * NN, 128, stream);
  // SA4 (C=128) on x3 — bf16 MFMA for U and Z convs (no kNN downstream)
  run_sa<128, true>(xc + 128 * NN, 512 * NN, sa4, xT, U, UT, AGGt, AGG, z, h, sq, idx,
                    M, WCV, Mb, wcvb, xTb, AGGtb, xhi, xlo, D, nbatch, stream);
  // conv4 (bf16 MFMA): h [B,256,N] -> z [B,256,N]
  transpose_bf16_kernel<<<dim3(NN / 32, 8, BB), 256, 0, stream>>>(h, 256 * NN, 256, NN, hTb);
  convert_bf16_kernel<<<(256 * 256 + 255) / 256, 256, 0, stream>>>(conv4_w, w4b, 256 * 256);
  mfma_gemm_lds_kernel<<<dim3(NN / 128, 2, BB), 256, 0, stream>>>(w4b, hTb, z, 256, 256);
  bn_fused_kernel<<<256, 256, 0, stream>>>(z, 256, xc, 512 * NN, 256);
  // conv5 (bf16 MFMA): xc [B,512,N] -> z [B,1024,N]; BN+LReLU+pool -> p
  transpose_bf16_kernel<<<dim3(NN / 32, 16, BB), 256, 0, stream>>>(xc, 512 * NN, 512, NN, xcTb);
  convert_bf16_kernel<<<(1024 * 512 + 255) / 256, 256, 0, stream>>>(conv5_w, w5b, 1024 * 512);
  mfma_gemm_lds_kernel<<<dim3(NN / 128, 8, BB), 256, 0, stream>>>(w5b, xcTb, z, 1024, 512);
  bn_pool_kernel<<<1024, 256, 0, stream>>>(z, p);
  // FC head
  linear_kernel<<<BB * 512, 64, 0, stream>>>(p, 2048, 512, lin1_w, lin1_b, t1);
  bnf_kernel<<<2, 256, 0, stream>>>(t1, 512);
  linear_kernel<<<BB * 256, 64, 0, stream>>>(t1, 512, 256, lin2_w, lin2_b, t2);
  bnf_kernel<<<1, 256, 0, stream>>>(t2, 256);
  linear_kernel<<<BB * 40, 64, 0, stream>>>(t2, 256, 40, lin3_w, lin3_b, (float*)d_out);
}

// Round 16
// 1174.853 us; speedup vs baseline: 1.6261x; 1.1058x over previous
//
#include <hip/hip_runtime.h>
#include <math.h>

#define BB 8
#define NN 2048
#define KNB 20

typedef __attribute__((ext_vector_type(8))) short bf16x8;
typedef __attribute__((ext_vector_type(8))) _Float16 f16x8;
typedef __attribute__((ext_vector_type(4))) float f32x4;

__device__ inline unsigned short f2bf(float f) {
  union { float f; unsigned u; } v; v.f = f;
  unsigned r = v.u + 0x7FFF + ((v.u >> 16) & 1);  // RNE
  return (unsigned short)(r >> 16);
}

// ---------------------------------------------------------------- sq
__global__ __launch_bounds__(256) void sq_kernel(const float* __restrict__ x, int bs, int C,
                                                 float* __restrict__ sq) {
  int t = blockIdx.x * blockDim.x + threadIdx.x;
  int b = t / NN, n = t % NN;
  const float* xp = x + (size_t)b * bs + n;
  float s = 0.f;
  for (int c = 0; c < C; ++c) { float v = xp[c * NN]; s += v * v; }
  sq[t] = s;
}

// ---------------------------------------------------------------- fused weight prep
// M[c][cp] = sum_e wk[e*C+c]*wq[e*C+cp];  WCV[o][c] = sum_e wc[o*C+e]*wv[e*C+c]
// r15 post-mortem: the thread-per-output serial-loop versions were
// latency-bound (47 us each, VALUBusy 0.7%, 64 blocks, no unroll). This is
// wave-per-output with lane-split reduction: 2*C*C waves, ~3 us.
__global__ __launch_bounds__(256) void prep_mw_kernel(
    const float* __restrict__ wq, const float* __restrict__ wk,
    const float* __restrict__ wv, const float* __restrict__ wc, int C,
    float* __restrict__ M, float* __restrict__ WCV,
    unsigned short* __restrict__ Mb, unsigned short* __restrict__ wcvb, int emitBF) {
  int w = blockIdx.x * 4 + (threadIdx.x >> 6);
  int lane = threadIdx.x & 63;
  int total = 2 * C * C;
  if (w >= total) return;
  float a = 0.f;
  if (w < C * C) {
    int c = w / C, cp = w - c * C;
    for (int e = lane; e < C; e += 64) a += wk[e * C + c] * wq[e * C + cp];
  } else {
    int t = w - C * C;
    int o = t / C, c = t - o * C;
    for (int e = lane; e < C; e += 64) a += wc[o * C + e] * wv[e * C + c];
  }
#pragma unroll
  for (int s = 32; s > 0; s >>= 1) a += __shfl_down(a, s);
  if (lane == 0) {
    if (w < C * C) {
      M[w] = a;
      if (emitBF) Mb[w] = f2bf(a);
    } else {
      int t = w - C * C;
      WCV[t] = a;
      if (emitBF) wcvb[t] = f2bf(a);
    }
  }
}

// ---------------------------------------------------------------- converts (conv4/5 weights)
__global__ __launch_bounds__(256) void convert_bf16_kernel(const float* __restrict__ in,
                                                           unsigned short* __restrict__ out,
                                                           int count) {
  int i = blockIdx.x * 256 + threadIdx.x;
  if (i < count) out[i] = f2bf(in[i]);
}

// ---------------------------------------------------------------- transpose (fp32)
__global__ __launch_bounds__(256) void transpose_kernel(const float* __restrict__ in, int inBS,
                                                        int R, int Cl, float* __restrict__ out) {
  __shared__ float tile[32][33];
  int b = blockIdx.z;
  const float* ip = in + (size_t)b * inBS;
  float* op = out + (size_t)b * R * Cl;
  int c0 = blockIdx.x * 32, r0 = blockIdx.y * 32;
  int tx = threadIdx.x & 31, ty = threadIdx.x >> 5;
  for (int yy = ty; yy < 32; yy += 8) {
    int r = r0 + yy, c = c0 + tx;
    tile[yy][tx] = (r < R && c < Cl) ? ip[(size_t)r * Cl + c] : 0.f;
  }
  __syncthreads();
  for (int yy = ty; yy < 32; yy += 8) {
    int c = c0 + yy, r = r0 + tx;
    if (c < Cl && r < R) op[(size_t)c * R + r] = tile[tx][yy];
  }
}

// ---------------------------------------------------------------- transpose + bf16 convert
__global__ __launch_bounds__(256) void transpose_bf16_kernel(const float* __restrict__ in, int inBS,
                                                             int R, int Cl,
                                                             unsigned short* __restrict__ out) {
  __shared__ float tile[32][33];
  int b = blockIdx.z;
  const float* ip = in + (size_t)b * inBS;
  unsigned short* op = out + (size_t)b * R * Cl;
  int c0 = blockIdx.x * 32, r0 = blockIdx.y * 32;
  int tx = threadIdx.x & 31, ty = threadIdx.x >> 5;
  for (int yy = ty; yy < 32; yy += 8) {
    int r = r0 + yy, c = c0 + tx;
    tile[yy][tx] = (r < R && c < Cl) ? ip[(size_t)r * Cl + c] : 0.f;
  }
  __syncthreads();
  for (int yy = ty; yy < 32; yy += 8) {
    int c = c0 + yy, r = r0 + tx;
    if (c < Cl && r < R) op[(size_t)c * R + r] = f2bf(tile[tx][yy]);
  }
}

// ---------------------------------------------------------------- transpose + fp16 hi/lo split
__global__ __launch_bounds__(256) void transpose_f16split_kernel(
    const float* __restrict__ in, int inBS, int R, int Cl,
    _Float16* __restrict__ hi, _Float16* __restrict__ lo) {
  __shared__ float tile[32][33];
  int b = blockIdx.z;
  const float* ip = in + (size_t)b * inBS;
  _Float16* hp = hi + (size_t)b * R * Cl;
  _Float16* lp = lo + (size_t)b * R * Cl;
  int c0 = blockIdx.x * 32, r0 = blockIdx.y * 32;
  int tx = threadIdx.x & 31, ty = threadIdx.x >> 5;
  for (int yy = ty; yy < 32; yy += 8) {
    int r = r0 + yy, c = c0 + tx;
    tile[yy][tx] = (r < R && c < Cl) ? ip[(size_t)r * Cl + c] : 0.f;
  }
  __syncthreads();
  for (int yy = ty; yy < 32; yy += 8) {
    int c = c0 + yy, r = r0 + tx;
    if (c < Cl && r < R) {
      float v = tile[tx][yy];
      _Float16 hv = (_Float16)v;
      hp[(size_t)c * R + r] = hv;
      lp[(size_t)c * R + r] = (_Float16)(v - (float)hv);
    }
  }
}

// ---------------------------------------------------------------- MFMA GEMM, LDS double-buffered (bf16)
__global__ __launch_bounds__(256, 2) void mfma_gemm_lds_kernel(
    const unsigned short* __restrict__ A, const unsigned short* __restrict__ B,
    float* __restrict__ Z, int O, int K) {
  const int b = blockIdx.z;
  const int n0 = blockIdx.x * 128, o0 = blockIdx.y * 128;
  const int tid = threadIdx.x;
  const int wave = tid >> 6, lane = tid & 63;
  const int wo = wave >> 1, wn = wave & 1;
  const int l16 = lane & 15, q = lane >> 4;
  __shared__ unsigned short Al[2][4096];
  __shared__ unsigned short Bl[2][4096];
  const unsigned short* Ab = A + (size_t)o0 * K;
  const unsigned short* Bb = B + ((size_t)b * NN + n0) * K;

  const int p0 = tid, p1 = tid + 256;
  const int r0 = ((p0 >> 6) << 4) | (p0 & 15), c0 = ((p0 >> 4) & 3) * 8;
  const int r1 = ((p1 >> 6) << 4) | (p1 & 15), c1 = ((p1 >> 4) & 3) * 8;

  bf16x8 ar0, ar1, br0, br1;
  auto gload = [&](int k0) {
    ar0 = *(const bf16x8*)(Ab + (size_t)r0 * K + k0 + c0);
    ar1 = *(const bf16x8*)(Ab + (size_t)r1 * K + k0 + c1);
    br0 = *(const bf16x8*)(Bb + (size_t)r0 * K + k0 + c0);
    br1 = *(const bf16x8*)(Bb + (size_t)r1 * K + k0 + c1);
  };
  auto sstore = [&](int buf) {
    *(bf16x8*)&Al[buf][p0 * 8] = ar0;
    *(bf16x8*)&Al[buf][p1 * 8] = ar1;
    *(bf16x8*)&Bl[buf][p0 * 8] = br0;
    *(bf16x8*)&Bl[buf][p1 * 8] = br1;
  };

  f32x4 acc[4][4];
#pragma unroll
  for (int s = 0; s < 4; ++s)
#pragma unroll
    for (int t = 0; t < 4; ++t) acc[s][t] = (f32x4){0.f, 0.f, 0.f, 0.f};

  gload(0);
  sstore(0);
  int cur = 0;
  for (int k0 = 0; k0 < K; k0 += 32) {
    bool more = (k0 + 32) < K;
    if (more) gload(k0 + 32);
    __syncthreads();
    bf16x8 af[4], bfr[4];
#pragma unroll
    for (int s = 0; s < 4; ++s)
      af[s] = *(const bf16x8*)&Al[cur][((wo * 4 + s) * 64 + q * 16 + l16) * 8];
#pragma unroll
    for (int t = 0; t < 4; ++t)
      bfr[t] = *(const bf16x8*)&Bl[cur][((wn * 4 + t) * 64 + q * 16 + l16) * 8];
#pragma unroll
    for (int s = 0; s < 4; ++s)
#pragma unroll
      for (int t = 0; t < 4; ++t)
        acc[s][t] = __builtin_amdgcn_mfma_f32_16x16x32_bf16(af[s], bfr[t], acc[s][t], 0, 0, 0);
    if (more) sstore(cur ^ 1);
    cur ^= 1;
  }
#pragma unroll
  for (int s = 0; s < 4; ++s)
#pragma unroll
    for (int t = 0; t < 4; ++t) {
      float* zp = Z + ((size_t)b * O + o0 + wo * 64 + s * 16 + q * 4) * NN
                  + n0 + wn * 64 + t * 16 + l16;
#pragma unroll
      for (int r = 0; r < 4; ++r) zp[(size_t)r * NN] = acc[s][t][r];
    }
}

// ---------------------------------------------------------------- pd via f16 split MFMA
// hi.hi + hi.lo + lo.hi; rel err ~5e-7 (fp32-level) -> selection unchanged.
__global__ __launch_bounds__(256, 2) void pd_mfma_kernel(
    const _Float16* __restrict__ xhi, const _Float16* __restrict__ xlo, int C,
    const float* __restrict__ sq, float* __restrict__ P, int b_base) {
  const int bl = blockIdx.z;
  const int b = b_base + bl;
  const int n0 = blockIdx.x * 128, m0 = blockIdx.y * 128;
  const int tid = threadIdx.x;
  const int wave = tid >> 6, lane = tid & 63;
  const int wn_ = wave >> 1, wm_ = wave & 1;
  const int l16 = lane & 15, q = lane >> 4;
  __shared__ _Float16 Ah[4096], Al[4096], Bh[4096], Bl[4096];
  const _Float16* Ahg = xhi + ((size_t)b * NN + n0) * C;
  const _Float16* Alg = xlo + ((size_t)b * NN + n0) * C;
  const _Float16* Bhg = xhi + ((size_t)b * NN + m0) * C;
  const _Float16* Blg = xlo + ((size_t)b * NN + m0) * C;

  const int p0 = tid, p1 = tid + 256;
  const int r0 = ((p0 >> 6) << 4) | (p0 & 15), c0 = ((p0 >> 4) & 3) * 8;
  const int r1 = ((p1 >> 6) << 4) | (p1 & 15), c1 = ((p1 >> 4) & 3) * 8;

  f32x4 acc[4][4];
#pragma unroll
  for (int s = 0; s < 4; ++s)
#pragma unroll
    for (int t = 0; t < 4; ++t) acc[s][t] = (f32x4){0.f, 0.f, 0.f, 0.f};

  for (int k0 = 0; k0 < C; k0 += 32) {
    __syncthreads();
    *(f16x8*)&Ah[p0 * 8] = *(const f16x8*)(Ahg + (size_t)r0 * C + k0 + c0);
    *(f16x8*)&Ah[p1 * 8] = *(const f16x8*)(Ahg + (size_t)r1 * C + k0 + c1);
    *(f16x8*)&Al[p0 * 8] = *(const f16x8*)(Alg + (size_t)r0 * C + k0 + c0);
    *(f16x8*)&Al[p1 * 8] = *(const f16x8*)(Alg + (size_t)r1 * C + k0 + c1);
    *(f16x8*)&Bh[p0 * 8] = *(const f16x8*)(Bhg + (size_t)r0 * C + k0 + c0);
    *(f16x8*)&Bh[p1 * 8] = *(const f16x8*)(Bhg + (size_t)r1 * C + k0 + c1);
    *(f16x8*)&Bl[p0 * 8] = *(const f16x8*)(Blg + (size_t)r0 * C + k0 + c0);
    *(f16x8*)&Bl[p1 * 8] = *(const f16x8*)(Blg + (size_t)r1 * C + k0 + c1);
    __syncthreads();
    f16x8 ah[4], al[4], bh[4], blv[4];
#pragma unroll
    for (int s = 0; s < 4; ++s) {
      int pi = ((wn_ * 4 + s) * 64 + q * 16 + l16) * 8;
      ah[s] = *(const f16x8*)&Ah[pi];
      al[s] = *(const f16x8*)&Al[pi];
    }
#pragma unroll
    for (int t = 0; t < 4; ++t) {
      int pi = ((wm_ * 4 + t) * 64 + q * 16 + l16) * 8;
      bh[t] = *(const f16x8*)&Bh[pi];
      blv[t] = *(const f16x8*)&Bl[pi];
    }
#pragma unroll
    for (int s = 0; s < 4; ++s)
#pragma unroll
      for (int t = 0; t < 4; ++t) {
        acc[s][t] = __builtin_amdgcn_mfma_f32_16x16x32_f16(ah[s], bh[t], acc[s][t], 0, 0, 0);
        acc[s][t] = __builtin_amdgcn_mfma_f32_16x16x32_f16(ah[s], blv[t], acc[s][t], 0, 0, 0);
        acc[s][t] = __builtin_amdgcn_mfma_f32_16x16x32_f16(al[s], bh[t], acc[s][t], 0, 0, 0);
      }
  }
#pragma unroll
  for (int s = 0; s < 4; ++s)
#pragma unroll
    for (int t = 0; t < 4; ++t) {
      int col = m0 + wm_ * 64 + t * 16 + l16;
      float sqv = sq[b * NN + col];
      float* pp = P + ((size_t)bl * NN + n0 + wn_ * 64 + s * 16 + q * 4) * NN + col;
#pragma unroll
      for (int r = 0; r < 4; ++r) pp[(size_t)r * NN] = 2.f * acc[s][t][r] - sqv;
    }
}

// ---------------------------------------------------------------- pd GEMM 128-tile, fp32 (SA1, C=3)
__global__ __launch_bounds__(256, 2) void pd_gemm128_db_kernel(
    const float* __restrict__ x, int bs, int C, const float* __restrict__ sq,
    float* __restrict__ P, int b_base) {
  const int b = b_base + blockIdx.z;
  const int n0 = blockIdx.x * 128, m0 = blockIdx.y * 128;
  const int tid = threadIdx.x;
  const int tm = tid & 15, tn = tid >> 4;
  __shared__ float As[2][16][128], Bs[2][16][128];
  const float* xb = x + (size_t)b * bs;
  float acc[8][8];
#pragma unroll
  for (int i = 0; i < 8; ++i)
#pragma unroll
    for (int j = 0; j < 8; ++j) acc[i][j] = 0.f;

  float4 ara[2], arb[2];
  auto load_tile = [&](int k0) {
#pragma unroll
    for (int it = 0; it < 2; ++it) {
      int i = it * 256 + tid;
      int kc = i >> 5, c4 = i & 31;
      bool ok = (k0 + kc) < C;
      ara[it] = ok ? *(const float4*)&xb[(size_t)(k0 + kc) * NN + n0 + c4 * 4]
                   : make_float4(0.f, 0.f, 0.f, 0.f);
      arb[it] = ok ? *(const float4*)&xb[(size_t)(k0 + kc) * NN + m0 + c4 * 4]
                   : make_float4(0.f, 0.f, 0.f, 0.f);
    }
  };
  auto store_tile = [&](int buf) {
#pragma unroll
    for (int it = 0; it < 2; ++it) {
      int i = it * 256 + tid;
      int kc = i >> 5, c4 = i & 31;
      *(float4*)&As[buf][kc][c4 * 4] = ara[it];
      *(float4*)&Bs[buf][kc][c4 * 4] = arb[it];
    }
  };

  load_tile(0);
  store_tile(0);
  int cur = 0;
  for (int k0 = 0; k0 < C; k0 += 16) {
    bool more = (k0 + 16) < C;
    if (more) load_tile(k0 + 16);
    __syncthreads();
#pragma unroll
    for (int kc = 0; kc < 16; ++kc) {
      float4 a0 = *(const float4*)&As[cur][kc][tn * 4];
      float4 a1 = *(const float4*)&As[cur][kc][64 + tn * 4];
      float4 b0 = *(const float4*)&Bs[cur][kc][tm * 4];
      float4 b1 = *(const float4*)&Bs[cur][kc][64 + tm * 4];
      float ar[8] = {a0.x, a0.y, a0.z, a0.w, a1.x, a1.y, a1.z, a1.w};
      float br[8] = {b0.x, b0.y, b0.z, b0.w, b1.x, b1.y, b1.z, b1.w};
#pragma unroll
      for (int i = 0; i < 8; ++i)
#pragma unroll
        for (int j = 0; j < 8; ++j) acc[i][j] += ar[i] * br[j];
    }
    if (more) store_tile(cur ^ 1);
    cur ^= 1;
  }
  float4 sqa = *(const float4*)&sq[b * NN + m0 + tm * 4];
  float4 sqb = *(const float4*)&sq[b * NN + m0 + 64 + tm * 4];
#pragma unroll
  for (int h = 0; h < 2; ++h)
#pragma unroll
    for (int i = 0; i < 4; ++i) {
      int r = h * 4 + i;
      int nn = n0 + h * 64 + tn * 4 + i;
      float* prow = &P[((size_t)blockIdx.z * NN + nn) * NN + m0];
      float4 o0, o1;
      o0.x = 2.f * acc[r][0] - sqa.x; o0.y = 2.f * acc[r][1] - sqa.y;
      o0.z = 2.f * acc[r][2] - sqa.z; o0.w = 2.f * acc[r][3] - sqa.w;
      o1.x = 2.f * acc[r][4] - sqb.x; o1.y = 2.f * acc[r][5] - sqb.y;
      o1.z = 2.f * acc[r][6] - sqb.z; o1.w = 2.f * acc[r][7] - sqb.w;
      *(float4*)&prow[tm * 4] = o0;
      *(float4*)&prow[64 + tm * 4] = o1;
    }
}

// ---------------------------------------------------------------- top-20: EXACT-key bitonic + idx array
__global__ __launch_bounds__(256) void topk_bsort_kernel(const float* __restrict__ P,
                                                         int* __restrict__ idx_out, int b_base) {
  const int wave = threadIdx.x >> 6;
  const int lane = threadIdx.x & 63;
  const int n = blockIdx.x * 4 + wave;
  const int bl = blockIdx.y;
  const int b = b_base + bl;
  const float4* rp = (const float4*)(P + ((size_t)bl * NN + n) * NN);
  unsigned key[32], mv[32];
#pragma unroll
  for (int q = 0; q < 8; ++q) {
    float4 vv = rp[q * 64 + lane];
    int mb = q * 256 + lane * 4;
    float fv[4] = {vv.x, vv.y, vv.z, vv.w};
#pragma unroll
    for (int j = 0; j < 4; ++j) {
      unsigned u = __float_as_uint(fv[j]);
      unsigned mask = (unsigned)(((int)u) >> 31) | 0x80000000u;
      key[q * 4 + j] = (mb + j == n) ? 0u : (u ^ mask);
      mv[q * 4 + j] = (unsigned)(mb + j);
    }
  }
#pragma unroll
  for (int k = 2; k <= 32; k <<= 1) {
#pragma unroll
    for (int j = k >> 1; j > 0; j >>= 1) {
#pragma unroll
      for (int i = 0; i < 32; ++i) {
        int l = i ^ j;
        if (l > i) {
          unsigned ka = key[i], kb = key[l];
          unsigned ia = mv[i], ib = mv[l];
          bool agt = ka > kb;
          unsigned kmax = agt ? ka : kb, kmin = agt ? kb : ka;
          unsigned imax = agt ? ia : ib, imin = agt ? ib : ia;
          if ((i & k) == 0) { key[i] = kmax; mv[i] = imax; key[l] = kmin; mv[l] = imin; }
          else              { key[i] = kmin; mv[i] = imin; key[l] = kmax; mv[l] = imax; }
        }
      }
    }
  }
  int* op = idx_out + (size_t)(b * NN + n) * KNB;
  for (int k = 0; k < KNB; ++k) {
    unsigned best = key[0];
#pragma unroll
    for (int s = 32; s > 0; s >>= 1) {
      unsigned o = (unsigned)__shfl_xor((int)best, s);
      best = best > o ? best : o;
    }
    bool own = (key[0] == best);
    if (own) {
      op[k] = (int)mv[0];
#pragma unroll
      for (int j = 0; j < 20; ++j) { key[j] = key[j + 1]; mv[j] = mv[j + 1]; }
    }
  }
}

// ---------------------------------------------------------------- conv GEMM 64-tile (small O)
__global__ __launch_bounds__(256, 2) void conv_gemm_kernel(
    const float* __restrict__ in, int inBS, int C, int O,
    const float* __restrict__ w, float* __restrict__ z) {
  const int b = blockIdx.z;
  const int n0 = blockIdx.x * 64, o0 = blockIdx.y * 64;
  const int tid = threadIdx.x;
  const int tm = tid & 15, tn = tid >> 4;
  __shared__ float Ws[16][68];
  __shared__ float Xs[16][64];
  const float* ib = in + (size_t)b * inBS;
  float acc[4][4];
#pragma unroll
  for (int i = 0; i < 4; ++i)
#pragma unroll
    for (int j = 0; j < 4; ++j) acc[i][j] = 0.f;

  for (int k0 = 0; k0 < C; k0 += 16) {
    __syncthreads();
#pragma unroll
    for (int it = 0; it < 4; ++it) {
      int i = it * 256 + tid;
      int kc = i >> 6, nl = i & 63;
      Xs[kc][nl] = ((k0 + kc) < C) ? ib[(size_t)(k0 + kc) * NN + n0 + nl] : 0.f;
      int ol = i >> 4, kc2 = i & 15;
      Ws[kc2][ol] = ((o0 + ol) < O && (k0 + kc2) < C) ? w[(size_t)(o0 + ol) * C + k0 + kc2] : 0.f;
    }
    __syncthreads();
#pragma unroll
    for (int kc = 0; kc < 16; ++kc) {
      float4 a = *(const float4*)&Ws[kc][tn * 4];
      float4 bv = *(const float4*)&Xs[kc][tm * 4];
      acc[0][0] += a.x * bv.x; acc[0][1] += a.x * bv.y; acc[0][2] += a.x * bv.z; acc[0][3] += a.x * bv.w;
      acc[1][0] += a.y * bv.x; acc[1][1] += a.y * bv.y; acc[1][2] += a.y * bv.z; acc[1][3] += a.y * bv.w;
      acc[2][0] += a.z * bv.x; acc[2][1] += a.z * bv.y; acc[2][2] += a.z * bv.z; acc[2][3] += a.z * bv.w;
      acc[3][0] += a.w * bv.x; acc[3][1] += a.w * bv.y; acc[3][2] += a.w * bv.z; acc[3][3] += a.w * bv.w;
    }
  }
#pragma unroll
  for (int i = 0; i < 4; ++i) {
    int o = o0 + tn * 4 + i;
    if (o < O) {
      float4 ov;
      ov.x = acc[i][0]; ov.y = acc[i][1]; ov.z = acc[i][2]; ov.w = acc[i][3];
      *(float4*)&z[((size_t)b * O + o) * NN + n0 + tm * 4] = ov;
    }
  }
}

// ---------------------------------------------------------------- conv GEMM 128-tile, double-buffered (fp32)
__global__ __launch_bounds__(256, 2) void conv_gemm128_db_kernel(
    const float* __restrict__ in, int inBS, int C, int O,
    const float* __restrict__ w, float* __restrict__ z) {
  const int b = blockIdx.z;
  const int n0 = blockIdx.x * 128, o0 = blockIdx.y * 128;
  const int tid = threadIdx.x;
  const int tm = tid & 15, tn = tid >> 4;
  __shared__ float Xs[2][16][128];
  __shared__ float Ws[2][16][132];
  const float* ib = in + (size_t)b * inBS;
  float acc[8][8];
#pragma unroll
  for (int i = 0; i < 8; ++i)
#pragma unroll
    for (int j = 0; j < 8; ++j) acc[i][j] = 0.f;

  float4 xr[2], wr[2];
  auto load_tile = [&](int k0) {
#pragma unroll
    for (int it = 0; it < 2; ++it) {
      int i = it * 256 + tid;
      int kc = i >> 5, c4 = i & 31;
      xr[it] = ((k0 + kc) < C) ? *(const float4*)&ib[(size_t)(k0 + kc) * NN + n0 + c4 * 4]
                               : make_float4(0.f, 0.f, 0.f, 0.f);
      int ol = i >> 2, kq = i & 3;
      wr[it] = ((k0 + kq * 4) < C) ? *(const float4*)&w[(size_t)(o0 + ol) * C + k0 + kq * 4]
                                   : make_float4(0.f, 0.f, 0.f, 0.f);
    }
  };
  auto store_tile = [&](int buf) {
#pragma unroll
    for (int it = 0; it < 2; ++it) {
      int i = it * 256 + tid;
      int kc = i >> 5, c4 = i & 31;
      *(float4*)&Xs[buf][kc][c4 * 4] = xr[it];
      int ol = i >> 2, kq = i & 3;
      Ws[buf][kq * 4 + 0][ol] = wr[it].x;
      Ws[buf][kq * 4 + 1][ol] = wr[it].y;
      Ws[buf][kq * 4 + 2][ol] = wr[it].z;
      Ws[buf][kq * 4 + 3][ol] = wr[it].w;
    }
  };

  load_tile(0);
  store_tile(0);
  int cur = 0;
  for (int k0 = 0; k0 < C; k0 += 16) {
    bool more = (k0 + 16) < C;
    if (more) load_tile(k0 + 16);
    __syncthreads();
#pragma unroll
    for (int kc = 0; kc < 16; ++kc) {
      float4 a0 = *(const float4*)&Ws[cur][kc][tn * 4];
      float4 a1 = *(const float4*)&Ws[cur][kc][64 + tn * 4];
      float4 b0 = *(const float4*)&Xs[cur][kc][tm * 4];
      float4 b1 = *(const float4*)&Xs[cur][kc][64 + tm * 4];
      float ar[8] = {a0.x, a0.y, a0.z, a0.w, a1.x, a1.y, a1.z, a1.w};
      float br[8] = {b0.x, b0.y, b0.z, b0.w, b1.x, b1.y, b1.z, b1.w};
#pragma unroll
      for (int i = 0; i < 8; ++i)
#pragma unroll
        for (int j = 0; j < 8; ++j) acc[i][j] += ar[i] * br[j];
    }
    if (more) store_tile(cur ^ 1);
    cur ^= 1;
  }
#pragma unroll
  for (int h = 0; h < 2; ++h)
#pragma unroll
    for (int i = 0; i < 4; ++i) {
      int r = h * 4 + i;
      int o = o0 + h * 64 + tn * 4 + i;
      float* zrow = &z[((size_t)b * O + o) * NN + n0];
      float4 o0v, o1v;
      o0v.x = acc[r][0]; o0v.y = acc[r][1]; o0v.z = acc[r][2]; o0v.w = acc[r][3];
      o1v.x = acc[r][4]; o1v.y = acc[r][5]; o1v.z = acc[r][6]; o1v.w = acc[r][7];
      *(float4*)&zrow[tm * 4] = o0v;
      *(float4*)&zrow[64 + tm * 4] = o1v;
    }
}

// ---------------------------------------------------------------- attention (wave/point)
template <int C, bool BF16OUT>
__global__ __launch_bounds__(64) void att_wave_kernel(
    const float* __restrict__ xT, const float* __restrict__ UT,
    const int* __restrict__ idx, float* __restrict__ AGGt,
    unsigned short* __restrict__ AGGtb) {
  const int n = blockIdx.x & (NN - 1);
  const int b = blockIdx.x >> 11;
  const int lane = threadIdx.x;
  constexpr int CP = C + 1;
  __shared__ float nb[KNB][CP];
  __shared__ float sl[KNB];
  __shared__ int nidx[KNB];
  __shared__ float ul[C];
  const float* xTb = xT + (size_t)b * NN * C;
  if (lane < KNB) nidx[lane] = idx[(size_t)(b * NN + n) * KNB + lane];
  for (int c = lane; c < C; c += 64) ul[c] = UT[((size_t)b * NN + n) * C + c];
  __syncthreads();
  for (int i = lane; i < KNB * C; i += 64) {
    int k = i / C, c = i - k * C;
    nb[k][c] = xTb[(size_t)nidx[k] * C + c];
  }
  __syncthreads();
  float sv = -INFINITY;
  if (lane < KNB) {
    float a = 0.f;
#pragma unroll
    for (int c = 0; c < C; ++c) a += nb[lane][c] * ul[c];
    sv = a / sqrtf((float)C);
  }
  float mx = sv;
#pragma unroll
  for (int s = 32; s > 0; s >>= 1) mx = fmaxf(mx, __shfl_xor(mx, s));
  float e = (lane < KNB) ? expf(sv - mx) : 0.f;
  float sum = e;
#pragma unroll
  for (int s = 32; s > 0; s >>= 1) sum += __shfl_xor(sum, s);
  if (lane < KNB) sl[lane] = e / sum;
  __syncthreads();
  const float* xTn = xTb + (size_t)n * C;
  for (int c = lane; c < C; c += 64) {
    float a = 0.f;
#pragma unroll
    for (int k = 0; k < KNB; ++k) a += sl[k] * nb[k][c];
    float r = a - xTn[c];
    if (BF16OUT)
      AGGtb[((size_t)b * NN + n) * C + c] = f2bf(r);
    else
      AGGt[((size_t)b * NN + n) * C + c] = r;
  }
}

// ---------------------------------------------------------------- fused BN (+LReLU)
__global__ __launch_bounds__(256) void bn_fused_kernel(const float* __restrict__ z, int O,
                                                       float* __restrict__ out, int outBS, int c0) {
  int o = blockIdx.x;
  int tid = threadIdx.x;
  __shared__ float s1[256], s2[256];
  __shared__ float smv, srv;
  float a1 = 0.f, a2 = 0.f;
  for (int i = tid; i < BB * NN; i += 256) {
    int b = i >> 11, n = i & (NN - 1);
    float v = z[((size_t)b * O + o) * NN + n];
    a1 += v; a2 += v * v;
  }
  s1[tid] = a1; s2[tid] = a2;
  __syncthreads();
  for (int st = 128; st > 0; st >>= 1) {
    if (tid < st) { s1[tid] += s1[tid + st]; s2[tid] += s2[tid + st]; }
    __syncthreads();
  }
  if (tid == 0) {
    float m = s1[0] / (BB * NN);
    float var = s2[0] / (BB * NN) - m * m;
    smv = m; srv = rsqrtf(var + 1e-5f);
  }
  __syncthreads();
  float m = smv, r = srv;
  for (int i = tid; i < BB * NN; i += 256) {
    int b = i >> 11, n = i & (NN - 1);
    float v = (z[((size_t)b * O + o) * NN + n] - m) * r;
    out[(size_t)b * outBS + (c0 + o) * NN + n] = v >= 0.f ? v : 0.2f * v;
  }
}

// ---------------------------------------------------------------- BN+LReLU into h[:,0:O,:], copy xin into h[:,O:2O,:]
__global__ __launch_bounds__(256) void bn_copy_kernel(const float* __restrict__ z, int O,
                                                      const float* __restrict__ xin, int xbs,
                                                      float* __restrict__ out) {
  int o = blockIdx.x;  // 0..2O-1
  int tid = threadIdx.x;
  int outBS = 2 * O * NN;
  if (o >= O) {
    int c = o - O;
    for (int i = tid; i < BB * NN; i += 256) {
      int b = i >> 11, n = i & (NN - 1);
      out[(size_t)b * outBS + o * NN + n] = xin[(size_t)b * xbs + c * NN + n];
    }
    return;
  }
  __shared__ float s1[256], s2[256];
  __shared__ float smv, srv;
  float a1 = 0.f, a2 = 0.f;
  for (int i = tid; i < BB * NN; i += 256) {
    int b = i >> 11, n = i & (NN - 1);
    float v = z[((size_t)b * O + o) * NN + n];
    a1 += v; a2 += v * v;
  }
  s1[tid] = a1; s2[tid] = a2;
  __syncthreads();
  for (int st = 128; st > 0; st >>= 1) {
    if (tid < st) { s1[tid] += s1[tid + st]; s2[tid] += s2[tid + st]; }
    __syncthreads();
  }
  if (tid == 0) {
    float m = s1[0] / (BB * NN);
    float var = s2[0] / (BB * NN) - m * m;
    smv = m; srv = rsqrtf(var + 1e-5f);
  }
  __syncthreads();
  float m = smv, r = srv;
  for (int i = tid; i < BB * NN; i += 256) {
    int b = i >> 11, n = i & (NN - 1);
    float v = (z[((size_t)b * O + o) * NN + n] - m) * r;
    out[(size_t)b * outBS + o * NN + n] = v >= 0.f ? v : 0.2f * v;
  }
}

// ---------------------------------------------------------------- fused BN+LReLU+max/mean pool (conv5)
__global__ __launch_bounds__(256) void bn_pool_kernel(const float* __restrict__ z,
                                                      float* __restrict__ p) {
  int o = blockIdx.x;
  int tid = threadIdx.x;
  __shared__ float s1[256], s2[256];
  __shared__ float smv, srv;
  float a1 = 0.f, a2 = 0.f;
  for (int i = tid; i < BB * NN; i += 256) {
    int b = i >> 11, n = i & (NN - 1);
    float v = z[((size_t)b * 1024 + o) * NN + n];
    a1 += v; a2 += v * v;
  }
  s1[tid] = a1; s2[tid] = a2;
  __syncthreads();
  for (int st = 128; st > 0; st >>= 1) {
    if (tid < st) { s1[tid] += s1[tid + st]; s2[tid] += s2[tid + st]; }
    __syncthreads();
  }
  if (tid == 0) {
    float m = s1[0] / (BB * NN);
    float var = s2[0] / (BB * NN) - m * m;
    smv = m; srv = rsqrtf(var + 1e-5f);
  }
  __syncthreads();
  float m = smv, r = srv;
  int b = tid >> 5, l = tid & 31;
  const float* zp = z + ((size_t)b * 1024 + o) * NN;
  float mx = -INFINITY, sm = 0.f;
  for (int n = l; n < NN; n += 32) {
    float v = (zp[n] - m) * r;
    v = v >= 0.f ? v : 0.2f * v;
    mx = fmaxf(mx, v); sm += v;
  }
#pragma unroll
  for (int s = 16; s > 0; s >>= 1) {
    mx = fmaxf(mx, __shfl_xor(mx, s));
    sm += __shfl_xor(sm, s);
  }
  if (l == 0) {
    p[b * 2048 + o] = mx;
    p[b * 2048 + 1024 + o] = sm * (1.f / NN);
  }
}

__global__ __launch_bounds__(64) void linear_kernel(const float* __restrict__ in, int IN, int OUT,
                                                    const float* __restrict__ w,
                                                    const float* __restrict__ bias,
                                                    float* __restrict__ out) {
  int o = blockIdx.x;
  int b = o / OUT, f = o % OUT;
  const float* ip = in + (size_t)b * IN;
  const float* wp = w + (size_t)f * IN;
  float a = 0.f;
  for (int i = threadIdx.x; i < IN; i += 64) a += ip[i] * wp[i];
#pragma unroll
  for (int s = 32; s > 0; s >>= 1) a += __shfl_down(a, s);
  if (threadIdx.x == 0) out[o] = a + bias[f];
}

__global__ __launch_bounds__(256) void bnf_kernel(float* __restrict__ t, int F) {
  int f = blockIdx.x * blockDim.x + threadIdx.x;
  if (f >= F) return;
  float s = 0.f, s2 = 0.f;
  for (int b = 0; b < BB; ++b) { float v = t[b * F + f]; s += v; s2 += v * v; }
  float m = s * (1.f / BB);
  float var = s2 * (1.f / BB) - m * m;
  float r = rsqrtf(var + 1e-5f);
  for (int b = 0; b < BB; ++b) {
    float v = (t[b * F + f] - m) * r;
    t[b * F + f] = v >= 0.f ? v : 0.2f * v;
  }
}

// ---------------------------------------------------------------- host side

struct SAW { const float *wq, *wk, *wv, *wc; };

static inline void run_conv(const float* in, int inBS, int C, int O, const float* w,
                            float* z, hipStream_t st) {
  if (O % 128 == 0)
    conv_gemm128_db_kernel<<<dim3(NN / 128, O / 128, BB), 256, 0, st>>>(in, inBS, C, O, w, z);
  else
    conv_gemm_kernel<<<dim3(NN / 64, (O + 63) / 64, BB), 256, 0, st>>>(in, inBS, C, O, w, z);
}

// MFMA==true only valid for C multiple of 128; PDM (f16-split pd) for C%32==0.
template <int C, bool MFMA>
static inline void run_sa(const float* xin, int xbs, SAW w,
                          float* xT, float* U, float* UT, float* AGGt,
                          float* AGG, float* z, float* h, float* sq, int* idx,
                          float* M, float* WCV, unsigned short* Mb, unsigned short* wcvb,
                          unsigned short* xTb, unsigned short* AGGtb,
                          _Float16* xhi, _Float16* xlo,
                          float* D, int nbatch, hipStream_t st) {
  constexpr bool PDM = (C % 32 == 0);
  sq_kernel<<<BB * NN / 256, 256, 0, st>>>(xin, xbs, C, sq);
  transpose_kernel<<<dim3(NN / 32, (C + 31) / 32, BB), 256, 0, st>>>(xin, xbs, C, NN, xT);
  prep_mw_kernel<<<(2 * C * C + 3) / 4, 256, 0, st>>>(w.wq, w.wk, w.wv, w.wc, C,
                                                      M, WCV, Mb, wcvb, MFMA ? 1 : 0);
  if (PDM)
    transpose_f16split_kernel<<<dim3(NN / 32, (C + 31) / 32, BB), 256, 0, st>>>(
        xin, xbs, C, NN, xhi, xlo);
  if (MFMA)
    transpose_bf16_kernel<<<dim3(NN / 32, (C + 31) / 32, BB), 256, 0, st>>>(xin, xbs, C, NN, xTb);
  for (int bb = 0; bb < BB; bb += nbatch) {
    int nbc = (BB - bb) < nbatch ? (BB - bb) : nbatch;
    if (PDM)
      pd_mfma_kernel<<<dim3(16, 16, nbc), 256, 0, st>>>(xhi, xlo, C, sq, D, bb);
    else
      pd_gemm128_db_kernel<<<dim3(NN / 128, NN / 128, nbc), 256, 0, st>>>(xin, xbs, C, sq, D, bb);
    topk_bsort_kernel<<<dim3(NN / 4, nbc), 256, 0, st>>>(D, idx, bb);
  }
  if (MFMA)
    mfma_gemm_lds_kernel<<<dim3(NN / 128, C / 128, BB), 256, 0, st>>>(Mb, xTb, U, C, C);
  else
    run_conv(xin, xbs, C, C, M, U, st);                            // U = M . x  [C][N]
  transpose_kernel<<<dim3(NN / 32, (C + 31) / 32, BB), 256, 0, st>>>(U, C * NN, C, NN, UT);
  if (MFMA) {
    att_wave_kernel<C, true><<<BB * NN, 64, 0, st>>>(xT, UT, idx, AGGt, AGGtb);
    mfma_gemm_lds_kernel<<<dim3(NN / 128, C / 128, BB), 256, 0, st>>>(wcvb, AGGtb, z, C, C);
  } else {
    att_wave_kernel<C, false><<<BB * NN, 64, 0, st>>>(xT, UT, idx, AGGt, AGGtb);
    transpose_kernel<<<dim3((C + 31) / 32, NN / 32, BB), 256, 0, st>>>(AGGt, NN * C, NN, C, AGG);
    run_conv(AGG, C * NN, C, C, WCV, z, st);                       // Z = (wc.wv) . AGG
  }
  bn_copy_kernel<<<2 * C, 256, 0, st>>>(z, C, xin, xbs, h);
}

static inline void run_conv_bn(const float* in, int inBS, int Cin, int O, const float* w,
                               float* z, float* out, int outBS, int c0, hipStream_t st) {
  run_conv(in, inBS, Cin, O, w, z, st);
  bn_fused_kernel<<<O, 256, 0, st>>>(z, O, out, outBS, c0);
}

extern "C" void kernel_launch(void* const* d_in, const int* in_sizes, int n_in,
                              void* d_out, int out_size, void* d_ws, size_t ws_size,
                              hipStream_t stream) {
  const float* x = (const float*)d_in[0];
  SAW sa1{(const float*)d_in[1], (const float*)d_in[2], (const float*)d_in[3], (const float*)d_in[4]};
  SAW sa2{(const float*)d_in[5], (const float*)d_in[6], (const float*)d_in[7], (const float*)d_in[8]};
  SAW sa3{(const float*)d_in[9], (const float*)d_in[10], (const float*)d_in[11], (const float*)d_in[12]};
  SAW sa4{(const float*)d_in[13], (const float*)d_in[14], (const float*)d_in[15], (const float*)d_in[16]};
  const float* conv1_w = (const float*)d_in[17];
  const float* conv2_w = (const float*)d_in[18];
  const float* conv3_w = (const float*)d_in[19];
  const float* conv4_w = (const float*)d_in[20];
  const float* conv5_w = (const float*)d_in[21];
  const float* lin1_w = (const float*)d_in[22];
  const float* lin1_b = (const float*)d_in[23];
  const float* lin2_w = (const float*)d_in[24];
  const float* lin2_b = (const float*)d_in[25];
  const float* lin3_w = (const float*)d_in[26];
  const float* lin3_b = (const float*)d_in[27];

  char* ws = (char*)d_ws;
  size_t off = 0;
  auto take = [&](size_t bytes) -> void* {
    void* p = ws + off;
    off += (bytes + 255) & ~(size_t)255;
    return p;
  };
  float* sq   = (float*)take((size_t)BB * NN * 4);
  int*   idx  = (int*)take((size_t)BB * NN * KNB * 4);
  float* M    = (float*)take((size_t)128 * 128 * 4);
  float* WCV  = (float*)take((size_t)128 * 128 * 4);
  unsigned short* Mb   = (unsigned short*)take((size_t)128 * 128 * 2);
  unsigned short* wcvb = (unsigned short*)take((size_t)128 * 128 * 2);
  unsigned short* w4b  = (unsigned short*)take((size_t)256 * 256 * 2);
  unsigned short* w5b  = (unsigned short*)take((size_t)1024 * 512 * 2);
  float* U    = (float*)take((size_t)BB * 128 * NN * 4);  // contiguous with AGG
  float* AGG  = (float*)take((size_t)BB * 128 * NN * 4);  // also hosts xT
  float* h    = (float*)take((size_t)BB * 256 * NN * 4);  // overlays below
  float* z    = (float*)take((size_t)BB * 1024 * NN * 4); // hosts AGGt, AGGtb(+16MB), D-chunks
  float* xc   = (float*)take((size_t)BB * 512 * NN * 4);
  float* p    = (float*)take((size_t)BB * 2048 * 4);
  float* t1   = (float*)take((size_t)BB * 512 * 4);
  float* t2   = (float*)take((size_t)BB * 256 * 4);
  (void)n_in; (void)in_sizes; (void)out_size;

  // Overlays (phase-ordered lifetimes):
  float* xT = AGG;                                          // dead before AGG written
  float* UT = h;                                            // consumed before h written
  float* AGGt = z;                                          // first 8.4 MB of z
  unsigned short* xTb   = (unsigned short*)((char*)h + (size_t)BB * 128 * NN * 4);  // h 2nd half
  unsigned short* AGGtb = (unsigned short*)((char*)z + (size_t)16 * 1024 * 1024);   // z + 16 MB
  unsigned short* hTb   = (unsigned short*)U;               // conv4 phase (U dead)
  unsigned short* xcTb  = (unsigned short*)U;               // conv5 phase (U+AGG dead, 16.8 MB)
  _Float16* xhi = (_Float16*)h;                             // pd phase only (UT written after)
  _Float16* xlo = (_Float16*)((char*)h + (size_t)BB * NN * 128 * 2);

  size_t dfull = (size_t)BB * NN * NN * 4;
  bool fullD = (ws_size > off + dfull + 4096);
  float* D = fullD ? (float*)take(dfull) : z;               // !fullD: 4-batch chunks fill z exactly
  int nbatch = fullD ? BB : 4;

  // SA1 (C=3) -> h [B,6,N]  (fp32 pd; C=3 not MFMA-tileable)
  run_sa<3, false>(x, 3 * NN, sa1, xT, U, UT, AGGt, AGG, z, h, sq, idx,
                   M, WCV, Mb, wcvb, xTb, AGGtb, xhi, xlo, D, nbatch, stream);
  run_conv_bn(h, 6 * NN, 6, 64, conv1_w, z, xc, 512 * NN, 0, stream);
  // SA2 (C=64) on x1  (f16-split MFMA pd)
  run_sa<64, false>(xc + 0 * NN, 512 * NN, sa2, xT, U, UT, AGGt, AGG, z, h, sq, idx,
                    M, WCV, Mb, wcvb, xTb, AGGtb, xhi, xlo, D, nbatch, stream);
  run_conv_bn(h, 128 * NN, 128, 64, conv2_w, z, xc, 512 * NN, 64, stream);
  // SA3 (C=64) on x2
  run_sa<64, false>(xc + 64 * NN, 512 * NN, sa3, xT, U, UT, AGGt, AGG, z, h, sq, idx,
                    M, WCV, Mb, wcvb, xTb, AGGtb, xhi, xlo, D, nbatch, stream);
  run_conv_bn(h, 128 * NN, 128, 128, conv3_w, z, xc, 512 * NN, 128, stream);
  // SA4 (C=128) on x3 — bf16 MFMA for U and Z convs (no kNN downstream)
  run_sa<128, true>(xc + 128 * NN, 512 * NN, sa4, xT, U, UT, AGGt, AGG, z, h, sq, idx,
                    M, WCV, Mb, wcvb, xTb, AGGtb, xhi, xlo, D, nbatch, stream);
  // conv4 (bf16 MFMA): h [B,256,N] -> z [B,256,N]
  transpose_bf16_kernel<<<dim3(NN / 32, 8, BB), 256, 0, stream>>>(h, 256 * NN, 256, NN, hTb);
  convert_bf16_kernel<<<(256 * 256 + 255) / 256, 256, 0, stream>>>(conv4_w, w4b, 256 * 256);
  mfma_gemm_lds_kernel<<<dim3(NN / 128, 2, BB), 256, 0, stream>>>(w4b, hTb, z, 256, 256);
  bn_fused_kernel<<<256, 256, 0, stream>>>(z, 256, xc, 512 * NN, 256);
  // conv5 (bf16 MFMA): xc [B,512,N] -> z [B,1024,N]; BN+LReLU+pool -> p
  transpose_bf16_kernel<<<dim3(NN / 32, 16, BB), 256, 0, stream>>>(xc, 512 * NN, 512, NN, xcTb);
  convert_bf16_kernel<<<(1024 * 512 + 255) / 256, 256, 0, stream>>>(conv5_w, w5b, 1024 * 512);
  mfma_gemm_lds_kernel<<<dim3(NN / 128, 8, BB), 256, 0, stream>>>(w5b, xcTb, z, 1024, 512);
  bn_pool_kernel<<<1024, 256, 0, stream>>>(z, p);
  // FC head
  linear_kernel<<<BB * 512, 64, 0, stream>>>(p, 2048, 512, lin1_w, lin1_b, t1);
  bnf_kernel<<<2, 256, 0, stream>>>(t1, 512);
  linear_kernel<<<BB * 256, 64, 0, stream>>>(t1, 512, 256, lin2_w, lin2_b, t2);
  bnf_kernel<<<1, 256, 0, stream>>>(t2, 256);
  linear_kernel<<<BB * 40, 64, 0, stream>>>(t2, 256, 40, lin3_w, lin3_b, (float*)d_out);
}

// Round 17
// 1031.377 us; speedup vs baseline: 1.8524x; 1.1391x over previous
//
#include <hip/hip_runtime.h>
#include <math.h>

#define BB 8
#define NN 2048
#define KNB 20

typedef __attribute__((ext_vector_type(8))) short bf16x8;
typedef __attribute__((ext_vector_type(8))) _Float16 f16x8;
typedef __attribute__((ext_vector_type(4))) float f32x4;

__device__ inline unsigned short f2bf(float f) {
  union { float f; unsigned u; } v; v.f = f;
  unsigned r = v.u + 0x7FFF + ((v.u >> 16) & 1);  // RNE
  return (unsigned short)(r >> 16);
}

__device__ inline float lrelu(float v) { return v >= 0.f ? v : 0.2f * v; }

// ---------------------------------------------------------------- sq
__global__ __launch_bounds__(256) void sq_kernel(const float* __restrict__ x, int bs, int C,
                                                 float* __restrict__ sq) {
  int t = blockIdx.x * blockDim.x + threadIdx.x;
  int b = t / NN, n = t % NN;
  const float* xp = x + (size_t)b * bs + n;
  float s = 0.f;
  for (int c = 0; c < C; ++c) { float v = xp[c * NN]; s += v * v; }
  sq[t] = s;
}

// ---------------------------------------------------------------- fused weight prep
// wave-per-output with lane-split reduction (r15: serial-loop version was
// latency-bound at 47 us; this is ~3 us).
__global__ __launch_bounds__(256) void prep_mw_kernel(
    const float* __restrict__ wq, const float* __restrict__ wk,
    const float* __restrict__ wv, const float* __restrict__ wc, int C,
    float* __restrict__ M, float* __restrict__ WCV,
    unsigned short* __restrict__ Mb, unsigned short* __restrict__ wcvb, int emitBF) {
  int w = blockIdx.x * 4 + (threadIdx.x >> 6);
  int lane = threadIdx.x & 63;
  int total = 2 * C * C;
  if (w >= total) return;
  float a = 0.f;
  if (w < C * C) {
    int c = w / C, cp = w - c * C;
    for (int e = lane; e < C; e += 64) a += wk[e * C + c] * wq[e * C + cp];
  } else {
    int t = w - C * C;
    int o = t / C, c = t - o * C;
    for (int e = lane; e < C; e += 64) a += wc[o * C + e] * wv[e * C + c];
  }
#pragma unroll
  for (int s = 32; s > 0; s >>= 1) a += __shfl_down(a, s);
  if (lane == 0) {
    if (w < C * C) {
      M[w] = a;
      if (emitBF) Mb[w] = f2bf(a);
    } else {
      int t = w - C * C;
      WCV[t] = a;
      if (emitBF) wcvb[t] = f2bf(a);
    }
  }
}

// ---------------------------------------------------------------- converts (conv4/5 weights)
__global__ __launch_bounds__(256) void convert_bf16_kernel(const float* __restrict__ in,
                                                           unsigned short* __restrict__ out,
                                                           int count) {
  int i = blockIdx.x * 256 + threadIdx.x;
  if (i < count) out[i] = f2bf(in[i]);
}

// ---------------------------------------------------------------- transpose (fp32)
__global__ __launch_bounds__(256) void transpose_kernel(const float* __restrict__ in, int inBS,
                                                        int R, int Cl, float* __restrict__ out) {
  __shared__ float tile[32][33];
  int b = blockIdx.z;
  const float* ip = in + (size_t)b * inBS;
  float* op = out + (size_t)b * R * Cl;
  int c0 = blockIdx.x * 32, r0 = blockIdx.y * 32;
  int tx = threadIdx.x & 31, ty = threadIdx.x >> 5;
  for (int yy = ty; yy < 32; yy += 8) {
    int r = r0 + yy, c = c0 + tx;
    tile[yy][tx] = (r < R && c < Cl) ? ip[(size_t)r * Cl + c] : 0.f;
  }
  __syncthreads();
  for (int yy = ty; yy < 32; yy += 8) {
    int c = c0 + yy, r = r0 + tx;
    if (c < Cl && r < R) op[(size_t)c * R + r] = tile[tx][yy];
  }
}

// ---------------------------------------------------------------- transpose + bf16 convert
__global__ __launch_bounds__(256) void transpose_bf16_kernel(const float* __restrict__ in, int inBS,
                                                             int R, int Cl,
                                                             unsigned short* __restrict__ out) {
  __shared__ float tile[32][33];
  int b = blockIdx.z;
  const float* ip = in + (size_t)b * inBS;
  unsigned short* op = out + (size_t)b * R * Cl;
  int c0 = blockIdx.x * 32, r0 = blockIdx.y * 32;
  int tx = threadIdx.x & 31, ty = threadIdx.x >> 5;
  for (int yy = ty; yy < 32; yy += 8) {
    int r = r0 + yy, c = c0 + tx;
    tile[yy][tx] = (r < R && c < Cl) ? ip[(size_t)r * Cl + c] : 0.f;
  }
  __syncthreads();
  for (int yy = ty; yy < 32; yy += 8) {
    int c = c0 + yy, r = r0 + tx;
    if (c < Cl && r < R) op[(size_t)c * R + r] = f2bf(tile[tx][yy]);
  }
}

// ---------------------------------------------------------------- transpose + fp16 hi/lo split
__global__ __launch_bounds__(256) void transpose_f16split_kernel(
    const float* __restrict__ in, int inBS, int R, int Cl,
    _Float16* __restrict__ hi, _Float16* __restrict__ lo) {
  __shared__ float tile[32][33];
  int b = blockIdx.z;
  const float* ip = in + (size_t)b * inBS;
  _Float16* hp = hi + (size_t)b * R * Cl;
  _Float16* lp = lo + (size_t)b * R * Cl;
  int c0 = blockIdx.x * 32, r0 = blockIdx.y * 32;
  int tx = threadIdx.x & 31, ty = threadIdx.x >> 5;
  for (int yy = ty; yy < 32; yy += 8) {
    int r = r0 + yy, c = c0 + tx;
    tile[yy][tx] = (r < R && c < Cl) ? ip[(size_t)r * Cl + c] : 0.f;
  }
  __syncthreads();
  for (int yy = ty; yy < 32; yy += 8) {
    int c = c0 + yy, r = r0 + tx;
    if (c < Cl && r < R) {
      float v = tile[tx][yy];
      _Float16 hv = (_Float16)v;
      hp[(size_t)c * R + r] = hv;
      lp[(size_t)c * R + r] = (_Float16)(v - (float)hv);
    }
  }
}

// ---------------------------------------------------------------- MFMA GEMM, LDS double-buffered (bf16)
__global__ __launch_bounds__(256, 2) void mfma_gemm_lds_kernel(
    const unsigned short* __restrict__ A, const unsigned short* __restrict__ B,
    float* __restrict__ Z, int O, int K) {
  const int b = blockIdx.z;
  const int n0 = blockIdx.x * 128, o0 = blockIdx.y * 128;
  const int tid = threadIdx.x;
  const int wave = tid >> 6, lane = tid & 63;
  const int wo = wave >> 1, wn = wave & 1;
  const int l16 = lane & 15, q = lane >> 4;
  __shared__ unsigned short Al[2][4096];
  __shared__ unsigned short Bl[2][4096];
  const unsigned short* Ab = A + (size_t)o0 * K;
  const unsigned short* Bb = B + ((size_t)b * NN + n0) * K;

  const int p0 = tid, p1 = tid + 256;
  const int r0 = ((p0 >> 6) << 4) | (p0 & 15), c0 = ((p0 >> 4) & 3) * 8;
  const int r1 = ((p1 >> 6) << 4) | (p1 & 15), c1 = ((p1 >> 4) & 3) * 8;

  bf16x8 ar0, ar1, br0, br1;
  auto gload = [&](int k0) {
    ar0 = *(const bf16x8*)(Ab + (size_t)r0 * K + k0 + c0);
    ar1 = *(const bf16x8*)(Ab + (size_t)r1 * K + k0 + c1);
    br0 = *(const bf16x8*)(Bb + (size_t)r0 * K + k0 + c0);
    br1 = *(const bf16x8*)(Bb + (size_t)r1 * K + k0 + c1);
  };
  auto sstore = [&](int buf) {
    *(bf16x8*)&Al[buf][p0 * 8] = ar0;
    *(bf16x8*)&Al[buf][p1 * 8] = ar1;
    *(bf16x8*)&Bl[buf][p0 * 8] = br0;
    *(bf16x8*)&Bl[buf][p1 * 8] = br1;
  };

  f32x4 acc[4][4];
#pragma unroll
  for (int s = 0; s < 4; ++s)
#pragma unroll
    for (int t = 0; t < 4; ++t) acc[s][t] = (f32x4){0.f, 0.f, 0.f, 0.f};

  gload(0);
  sstore(0);
  int cur = 0;
  for (int k0 = 0; k0 < K; k0 += 32) {
    bool more = (k0 + 32) < K;
    if (more) gload(k0 + 32);
    __syncthreads();
    bf16x8 af[4], bfr[4];
#pragma unroll
    for (int s = 0; s < 4; ++s)
      af[s] = *(const bf16x8*)&Al[cur][((wo * 4 + s) * 64 + q * 16 + l16) * 8];
#pragma unroll
    for (int t = 0; t < 4; ++t)
      bfr[t] = *(const bf16x8*)&Bl[cur][((wn * 4 + t) * 64 + q * 16 + l16) * 8];
#pragma unroll
    for (int s = 0; s < 4; ++s)
#pragma unroll
      for (int t = 0; t < 4; ++t)
        acc[s][t] = __builtin_amdgcn_mfma_f32_16x16x32_bf16(af[s], bfr[t], acc[s][t], 0, 0, 0);
    if (more) sstore(cur ^ 1);
    cur ^= 1;
  }
#pragma unroll
  for (int s = 0; s < 4; ++s)
#pragma unroll
    for (int t = 0; t < 4; ++t) {
      float* zp = Z + ((size_t)b * O + o0 + wo * 64 + s * 16 + q * 4) * NN
                  + n0 + wn * 64 + t * 16 + l16;
#pragma unroll
      for (int r = 0; r < 4; ++r) zp[(size_t)r * NN] = acc[s][t][r];
    }
}

// ---------------------------------------------------------------- pd via f16 split MFMA
// hi.hi + hi.lo + lo.hi; rel err ~5e-7 (fp32-level) -> selection unchanged.
__global__ __launch_bounds__(256, 2) void pd_mfma_kernel(
    const _Float16* __restrict__ xhi, const _Float16* __restrict__ xlo, int C,
    const float* __restrict__ sq, float* __restrict__ P, int b_base) {
  const int bl = blockIdx.z;
  const int b = b_base + bl;
  const int n0 = blockIdx.x * 128, m0 = blockIdx.y * 128;
  const int tid = threadIdx.x;
  const int wave = tid >> 6, lane = tid & 63;
  const int wn_ = wave >> 1, wm_ = wave & 1;
  const int l16 = lane & 15, q = lane >> 4;
  __shared__ _Float16 Ah[4096], Al[4096], Bh[4096], Bl[4096];
  const _Float16* Ahg = xhi + ((size_t)b * NN + n0) * C;
  const _Float16* Alg = xlo + ((size_t)b * NN + n0) * C;
  const _Float16* Bhg = xhi + ((size_t)b * NN + m0) * C;
  const _Float16* Blg = xlo + ((size_t)b * NN + m0) * C;

  const int p0 = tid, p1 = tid + 256;
  const int r0 = ((p0 >> 6) << 4) | (p0 & 15), c0 = ((p0 >> 4) & 3) * 8;
  const int r1 = ((p1 >> 6) << 4) | (p1 & 15), c1 = ((p1 >> 4) & 3) * 8;

  f32x4 acc[4][4];
#pragma unroll
  for (int s = 0; s < 4; ++s)
#pragma unroll
    for (int t = 0; t < 4; ++t) acc[s][t] = (f32x4){0.f, 0.f, 0.f, 0.f};

  for (int k0 = 0; k0 < C; k0 += 32) {
    __syncthreads();
    *(f16x8*)&Ah[p0 * 8] = *(const f16x8*)(Ahg + (size_t)r0 * C + k0 + c0);
    *(f16x8*)&Ah[p1 * 8] = *(const f16x8*)(Ahg + (size_t)r1 * C + k0 + c1);
    *(f16x8*)&Al[p0 * 8] = *(const f16x8*)(Alg + (size_t)r0 * C + k0 + c0);
    *(f16x8*)&Al[p1 * 8] = *(const f16x8*)(Alg + (size_t)r1 * C + k0 + c1);
    *(f16x8*)&Bh[p0 * 8] = *(const f16x8*)(Bhg + (size_t)r0 * C + k0 + c0);
    *(f16x8*)&Bh[p1 * 8] = *(const f16x8*)(Bhg + (size_t)r1 * C + k0 + c1);
    *(f16x8*)&Bl[p0 * 8] = *(const f16x8*)(Blg + (size_t)r0 * C + k0 + c0);
    *(f16x8*)&Bl[p1 * 8] = *(const f16x8*)(Blg + (size_t)r1 * C + k0 + c1);
    __syncthreads();
    f16x8 ah[4], al[4], bh[4], blv[4];
#pragma unroll
    for (int s = 0; s < 4; ++s) {
      int pi = ((wn_ * 4 + s) * 64 + q * 16 + l16) * 8;
      ah[s] = *(const f16x8*)&Ah[pi];
      al[s] = *(const f16x8*)&Al[pi];
    }
#pragma unroll
    for (int t = 0; t < 4; ++t) {
      int pi = ((wm_ * 4 + t) * 64 + q * 16 + l16) * 8;
      bh[t] = *(const f16x8*)&Bh[pi];
      blv[t] = *(const f16x8*)&Bl[pi];
    }
#pragma unroll
    for (int s = 0; s < 4; ++s)
#pragma unroll
      for (int t = 0; t < 4; ++t) {
        acc[s][t] = __builtin_amdgcn_mfma_f32_16x16x32_f16(ah[s], bh[t], acc[s][t], 0, 0, 0);
        acc[s][t] = __builtin_amdgcn_mfma_f32_16x16x32_f16(ah[s], blv[t], acc[s][t], 0, 0, 0);
        acc[s][t] = __builtin_amdgcn_mfma_f32_16x16x32_f16(al[s], bh[t], acc[s][t], 0, 0, 0);
      }
  }
#pragma unroll
  for (int s = 0; s < 4; ++s)
#pragma unroll
    for (int t = 0; t < 4; ++t) {
      int col = m0 + wm_ * 64 + t * 16 + l16;
      float sqv = sq[b * NN + col];
      float* pp = P + ((size_t)bl * NN + n0 + wn_ * 64 + s * 16 + q * 4) * NN + col;
#pragma unroll
      for (int r = 0; r < 4; ++r) pp[(size_t)r * NN] = 2.f * acc[s][t][r] - sqv;
    }
}

// ---------------------------------------------------------------- pd GEMM 128-tile, fp32 (SA1, C=3)
__global__ __launch_bounds__(256, 2) void pd_gemm128_db_kernel(
    const float* __restrict__ x, int bs, int C, const float* __restrict__ sq,
    float* __restrict__ P, int b_base) {
  const int b = b_base + blockIdx.z;
  const int n0 = blockIdx.x * 128, m0 = blockIdx.y * 128;
  const int tid = threadIdx.x;
  const int tm = tid & 15, tn = tid >> 4;
  __shared__ float As[2][16][128], Bs[2][16][128];
  const float* xb = x + (size_t)b * bs;
  float acc[8][8];
#pragma unroll
  for (int i = 0; i < 8; ++i)
#pragma unroll
    for (int j = 0; j < 8; ++j) acc[i][j] = 0.f;

  float4 ara[2], arb[2];
  auto load_tile = [&](int k0) {
#pragma unroll
    for (int it = 0; it < 2; ++it) {
      int i = it * 256 + tid;
      int kc = i >> 5, c4 = i & 31;
      bool ok = (k0 + kc) < C;
      ara[it] = ok ? *(const float4*)&xb[(size_t)(k0 + kc) * NN + n0 + c4 * 4]
                   : make_float4(0.f, 0.f, 0.f, 0.f);
      arb[it] = ok ? *(const float4*)&xb[(size_t)(k0 + kc) * NN + m0 + c4 * 4]
                   : make_float4(0.f, 0.f, 0.f, 0.f);
    }
  };
  auto store_tile = [&](int buf) {
#pragma unroll
    for (int it = 0; it < 2; ++it) {
      int i = it * 256 + tid;
      int kc = i >> 5, c4 = i & 31;
      *(float4*)&As[buf][kc][c4 * 4] = ara[it];
      *(float4*)&Bs[buf][kc][c4 * 4] = arb[it];
    }
  };

  load_tile(0);
  store_tile(0);
  int cur = 0;
  for (int k0 = 0; k0 < C; k0 += 16) {
    bool more = (k0 + 16) < C;
    if (more) load_tile(k0 + 16);
    __syncthreads();
#pragma unroll
    for (int kc = 0; kc < 16; ++kc) {
      float4 a0 = *(const float4*)&As[cur][kc][tn * 4];
      float4 a1 = *(const float4*)&As[cur][kc][64 + tn * 4];
      float4 b0 = *(const float4*)&Bs[cur][kc][tm * 4];
      float4 b1 = *(const float4*)&Bs[cur][kc][64 + tm * 4];
      float ar[8] = {a0.x, a0.y, a0.z, a0.w, a1.x, a1.y, a1.z, a1.w};
      float br[8] = {b0.x, b0.y, b0.z, b0.w, b1.x, b1.y, b1.z, b1.w};
#pragma unroll
      for (int i = 0; i < 8; ++i)
#pragma unroll
        for (int j = 0; j < 8; ++j) acc[i][j] += ar[i] * br[j];
    }
    if (more) store_tile(cur ^ 1);
    cur ^= 1;
  }
  float4 sqa = *(const float4*)&sq[b * NN + m0 + tm * 4];
  float4 sqb = *(const float4*)&sq[b * NN + m0 + 64 + tm * 4];
#pragma unroll
  for (int h = 0; h < 2; ++h)
#pragma unroll
    for (int i = 0; i < 4; ++i) {
      int r = h * 4 + i;
      int nn = n0 + h * 64 + tn * 4 + i;
      float* prow = &P[((size_t)blockIdx.z * NN + nn) * NN + m0];
      float4 o0, o1;
      o0.x = 2.f * acc[r][0] - sqa.x; o0.y = 2.f * acc[r][1] - sqa.y;
      o0.z = 2.f * acc[r][2] - sqa.z; o0.w = 2.f * acc[r][3] - sqa.w;
      o1.x = 2.f * acc[r][4] - sqb.x; o1.y = 2.f * acc[r][5] - sqb.y;
      o1.z = 2.f * acc[r][6] - sqb.z; o1.w = 2.f * acc[r][7] - sqb.w;
      *(float4*)&prow[tm * 4] = o0;
      *(float4*)&prow[64 + tm * 4] = o1;
    }
}

// ---------------------------------------------------------------- top-20: EXACT-key bitonic + idx array
__global__ __launch_bounds__(256) void topk_bsort_kernel(const float* __restrict__ P,
                                                         int* __restrict__ idx_out, int b_base) {
  const int wave = threadIdx.x >> 6;
  const int lane = threadIdx.x & 63;
  const int n = blockIdx.x * 4 + wave;
  const int bl = blockIdx.y;
  const int b = b_base + bl;
  const float4* rp = (const float4*)(P + ((size_t)bl * NN + n) * NN);
  unsigned key[32], mv[32];
#pragma unroll
  for (int q = 0; q < 8; ++q) {
    float4 vv = rp[q * 64 + lane];
    int mb = q * 256 + lane * 4;
    float fv[4] = {vv.x, vv.y, vv.z, vv.w};
#pragma unroll
    for (int j = 0; j < 4; ++j) {
      unsigned u = __float_as_uint(fv[j]);
      unsigned mask = (unsigned)(((int)u) >> 31) | 0x80000000u;
      key[q * 4 + j] = (mb + j == n) ? 0u : (u ^ mask);
      mv[q * 4 + j] = (unsigned)(mb + j);
    }
  }
#pragma unroll
  for (int k = 2; k <= 32; k <<= 1) {
#pragma unroll
    for (int j = k >> 1; j > 0; j >>= 1) {
#pragma unroll
      for (int i = 0; i < 32; ++i) {
        int l = i ^ j;
        if (l > i) {
          unsigned ka = key[i], kb = key[l];
          unsigned ia = mv[i], ib = mv[l];
          bool agt = ka > kb;
          unsigned kmax = agt ? ka : kb, kmin = agt ? kb : ka;
          unsigned imax = agt ? ia : ib, imin = agt ? ib : ia;
          if ((i & k) == 0) { key[i] = kmax; mv[i] = imax; key[l] = kmin; mv[l] = imin; }
          else              { key[i] = kmin; mv[i] = imin; key[l] = kmax; mv[l] = imax; }
        }
      }
    }
  }
  int* op = idx_out + (size_t)(b * NN + n) * KNB;
  for (int k = 0; k < KNB; ++k) {
    unsigned best = key[0];
#pragma unroll
    for (int s = 32; s > 0; s >>= 1) {
      unsigned o = (unsigned)__shfl_xor((int)best, s);
      best = best > o ? best : o;
    }
    bool own = (key[0] == best);
    if (own) {
      op[k] = (int)mv[0];
#pragma unroll
      for (int j = 0; j < 20; ++j) { key[j] = key[j + 1]; mv[j] = mv[j + 1]; }
    }
  }
}

// ---------------------------------------------------------------- conv GEMM 64-tile (small O)
__global__ __launch_bounds__(256, 2) void conv_gemm_kernel(
    const float* __restrict__ in, int inBS, int C, int O,
    const float* __restrict__ w, float* __restrict__ z) {
  const int b = blockIdx.z;
  const int n0 = blockIdx.x * 64, o0 = blockIdx.y * 64;
  const int tid = threadIdx.x;
  const int tm = tid & 15, tn = tid >> 4;
  __shared__ float Ws[16][68];
  __shared__ float Xs[16][64];
  const float* ib = in + (size_t)b * inBS;
  float acc[4][4];
#pragma unroll
  for (int i = 0; i < 4; ++i)
#pragma unroll
    for (int j = 0; j < 4; ++j) acc[i][j] = 0.f;

  for (int k0 = 0; k0 < C; k0 += 16) {
    __syncthreads();
#pragma unroll
    for (int it = 0; it < 4; ++it) {
      int i = it * 256 + tid;
      int kc = i >> 6, nl = i & 63;
      Xs[kc][nl] = ((k0 + kc) < C) ? ib[(size_t)(k0 + kc) * NN + n0 + nl] : 0.f;
      int ol = i >> 4, kc2 = i & 15;
      Ws[kc2][ol] = ((o0 + ol) < O && (k0 + kc2) < C) ? w[(size_t)(o0 + ol) * C + k0 + kc2] : 0.f;
    }
    __syncthreads();
#pragma unroll
    for (int kc = 0; kc < 16; ++kc) {
      float4 a = *(const float4*)&Ws[kc][tn * 4];
      float4 bv = *(const float4*)&Xs[kc][tm * 4];
      acc[0][0] += a.x * bv.x; acc[0][1] += a.x * bv.y; acc[0][2] += a.x * bv.z; acc[0][3] += a.x * bv.w;
      acc[1][0] += a.y * bv.x; acc[1][1] += a.y * bv.y; acc[1][2] += a.y * bv.z; acc[1][3] += a.y * bv.w;
      acc[2][0] += a.z * bv.x; acc[2][1] += a.z * bv.y; acc[2][2] += a.z * bv.z; acc[2][3] += a.z * bv.w;
      acc[3][0] += a.w * bv.x; acc[3][1] += a.w * bv.y; acc[3][2] += a.w * bv.z; acc[3][3] += a.w * bv.w;
    }
  }
#pragma unroll
  for (int i = 0; i < 4; ++i) {
    int o = o0 + tn * 4 + i;
    if (o < O) {
      float4 ov;
      ov.x = acc[i][0]; ov.y = acc[i][1]; ov.z = acc[i][2]; ov.w = acc[i][3];
      *(float4*)&z[((size_t)b * O + o) * NN + n0 + tm * 4] = ov;
    }
  }
}

// ---------------------------------------------------------------- conv GEMM 128-tile, double-buffered (fp32)
__global__ __launch_bounds__(256, 2) void conv_gemm128_db_kernel(
    const float* __restrict__ in, int inBS, int C, int O,
    const float* __restrict__ w, float* __restrict__ z) {
  const int b = blockIdx.z;
  const int n0 = blockIdx.x * 128, o0 = blockIdx.y * 128;
  const int tid = threadIdx.x;
  const int tm = tid & 15, tn = tid >> 4;
  __shared__ float Xs[2][16][128];
  __shared__ float Ws[2][16][132];
  const float* ib = in + (size_t)b * inBS;
  float acc[8][8];
#pragma unroll
  for (int i = 0; i < 8; ++i)
#pragma unroll
    for (int j = 0; j < 8; ++j) acc[i][j] = 0.f;

  float4 xr[2], wr[2];
  auto load_tile = [&](int k0) {
#pragma unroll
    for (int it = 0; it < 2; ++it) {
      int i = it * 256 + tid;
      int kc = i >> 5, c4 = i & 31;
      xr[it] = ((k0 + kc) < C) ? *(const float4*)&ib[(size_t)(k0 + kc) * NN + n0 + c4 * 4]
                               : make_float4(0.f, 0.f, 0.f, 0.f);
      int ol = i >> 2, kq = i & 3;
      wr[it] = ((k0 + kq * 4) < C) ? *(const float4*)&w[(size_t)(o0 + ol) * C + k0 + kq * 4]
                                   : make_float4(0.f, 0.f, 0.f, 0.f);
    }
  };
  auto store_tile = [&](int buf) {
#pragma unroll
    for (int it = 0; it < 2; ++it) {
      int i = it * 256 + tid;
      int kc = i >> 5, c4 = i & 31;
      *(float4*)&Xs[buf][kc][c4 * 4] = xr[it];
      int ol = i >> 2, kq = i & 3;
      Ws[buf][kq * 4 + 0][ol] = wr[it].x;
      Ws[buf][kq * 4 + 1][ol] = wr[it].y;
      Ws[buf][kq * 4 + 2][ol] = wr[it].z;
      Ws[buf][kq * 4 + 3][ol] = wr[it].w;
    }
  };

  load_tile(0);
  store_tile(0);
  int cur = 0;
  for (int k0 = 0; k0 < C; k0 += 16) {
    bool more = (k0 + 16) < C;
    if (more) load_tile(k0 + 16);
    __syncthreads();
#pragma unroll
    for (int kc = 0; kc < 16; ++kc) {
      float4 a0 = *(const float4*)&Ws[cur][kc][tn * 4];
      float4 a1 = *(const float4*)&Ws[cur][kc][64 + tn * 4];
      float4 b0 = *(const float4*)&Xs[cur][kc][tm * 4];
      float4 b1 = *(const float4*)&Xs[cur][kc][64 + tm * 4];
      float ar[8] = {a0.x, a0.y, a0.z, a0.w, a1.x, a1.y, a1.z, a1.w};
      float br[8] = {b0.x, b0.y, b0.z, b0.w, b1.x, b1.y, b1.z, b1.w};
#pragma unroll
      for (int i = 0; i < 8; ++i)
#pragma unroll
        for (int j = 0; j < 8; ++j) acc[i][j] += ar[i] * br[j];
    }
    if (more) store_tile(cur ^ 1);
    cur ^= 1;
  }
#pragma unroll
  for (int h = 0; h < 2; ++h)
#pragma unroll
    for (int i = 0; i < 4; ++i) {
      int r = h * 4 + i;
      int o = o0 + h * 64 + tn * 4 + i;
      float* zrow = &z[((size_t)b * O + o) * NN + n0];
      float4 o0v, o1v;
      o0v.x = acc[r][0]; o0v.y = acc[r][1]; o0v.z = acc[r][2]; o0v.w = acc[r][3];
      o1v.x = acc[r][4]; o1v.y = acc[r][5]; o1v.z = acc[r][6]; o1v.w = acc[r][7];
      *(float4*)&zrow[tm * 4] = o0v;
      *(float4*)&zrow[64 + tm * 4] = o1v;
    }
}

// ---------------------------------------------------------------- attention (wave/point)
template <int C, bool BF16OUT>
__global__ __launch_bounds__(64) void att_wave_kernel(
    const float* __restrict__ xT, const float* __restrict__ UT,
    const int* __restrict__ idx, float* __restrict__ AGGt,
    unsigned short* __restrict__ AGGtb) {
  const int n = blockIdx.x & (NN - 1);
  const int b = blockIdx.x >> 11;
  const int lane = threadIdx.x;
  constexpr int CP = C + 1;
  __shared__ float nb[KNB][CP];
  __shared__ float sl[KNB];
  __shared__ int nidx[KNB];
  __shared__ float ul[C];
  const float* xTb = xT + (size_t)b * NN * C;
  if (lane < KNB) nidx[lane] = idx[(size_t)(b * NN + n) * KNB + lane];
  for (int c = lane; c < C; c += 64) ul[c] = UT[((size_t)b * NN + n) * C + c];
  __syncthreads();
  for (int i = lane; i < KNB * C; i += 64) {
    int k = i / C, c = i - k * C;
    nb[k][c] = xTb[(size_t)nidx[k] * C + c];
  }
  __syncthreads();
  float sv = -INFINITY;
  if (lane < KNB) {
    float a = 0.f;
#pragma unroll
    for (int c = 0; c < C; ++c) a += nb[lane][c] * ul[c];
    sv = a / sqrtf((float)C);
  }
  float mx = sv;
#pragma unroll
  for (int s = 32; s > 0; s >>= 1) mx = fmaxf(mx, __shfl_xor(mx, s));
  float e = (lane < KNB) ? expf(sv - mx) : 0.f;
  float sum = e;
#pragma unroll
  for (int s = 32; s > 0; s >>= 1) sum += __shfl_xor(sum, s);
  if (lane < KNB) sl[lane] = e / sum;
  __syncthreads();
  const float* xTn = xTb + (size_t)n * C;
  for (int c = lane; c < C; c += 64) {
    float a = 0.f;
#pragma unroll
    for (int k = 0; k < KNB; ++k) a += sl[k] * nb[k][c];
    float r = a - xTn[c];
    if (BF16OUT)
      AGGtb[((size_t)b * NN + n) * C + c] = f2bf(r);
    else
      AGGt[((size_t)b * NN + n) * C + c] = r;
  }
}

// ---------------------------------------------------------------- fused BN (+LReLU), float4
__global__ __launch_bounds__(256) void bn_fused_kernel(const float* __restrict__ z, int O,
                                                       float* __restrict__ out, int outBS, int c0) {
  int o = blockIdx.x;
  int tid = threadIdx.x;
  __shared__ float s1[256], s2[256];
  __shared__ float smv, srv;
  float a1 = 0.f, a2 = 0.f;
  // 512 float4 per (b) row; BB*512 = 4096 pieces
  for (int i = tid; i < BB * 512; i += 256) {
    int b = i >> 9, n4 = i & 511;
    float4 v = *(const float4*)&z[((size_t)b * O + o) * NN + n4 * 4];
    a1 += v.x + v.y + v.z + v.w;
    a2 += v.x * v.x + v.y * v.y + v.z * v.z + v.w * v.w;
  }
  s1[tid] = a1; s2[tid] = a2;
  __syncthreads();
  for (int st = 128; st > 0; st >>= 1) {
    if (tid < st) { s1[tid] += s1[tid + st]; s2[tid] += s2[tid + st]; }
    __syncthreads();
  }
  if (tid == 0) {
    float m = s1[0] / (BB * NN);
    float var = s2[0] / (BB * NN) - m * m;
    smv = m; srv = rsqrtf(var + 1e-5f);
  }
  __syncthreads();
  float m = smv, r = srv;
  for (int i = tid; i < BB * 512; i += 256) {
    int b = i >> 9, n4 = i & 511;
    float4 v = *(const float4*)&z[((size_t)b * O + o) * NN + n4 * 4];
    float4 ov;
    ov.x = lrelu((v.x - m) * r); ov.y = lrelu((v.y - m) * r);
    ov.z = lrelu((v.z - m) * r); ov.w = lrelu((v.w - m) * r);
    *(float4*)&out[(size_t)b * outBS + (size_t)(c0 + o) * NN + n4 * 4] = ov;
  }
}

// ---------------------------------------------------------------- BN+LReLU into h[:,0:O,:], copy xin into h[:,O:2O,:], float4
__global__ __launch_bounds__(256) void bn_copy_kernel(const float* __restrict__ z, int O,
                                                      const float* __restrict__ xin, int xbs,
                                                      float* __restrict__ out) {
  int o = blockIdx.x;  // 0..2O-1
  int tid = threadIdx.x;
  int outBS = 2 * O * NN;
  if (o >= O) {
    int c = o - O;
    for (int i = tid; i < BB * 512; i += 256) {
      int b = i >> 9, n4 = i & 511;
      *(float4*)&out[(size_t)b * outBS + (size_t)o * NN + n4 * 4] =
          *(const float4*)&xin[(size_t)b * xbs + (size_t)c * NN + n4 * 4];
    }
    return;
  }
  __shared__ float s1[256], s2[256];
  __shared__ float smv, srv;
  float a1 = 0.f, a2 = 0.f;
  for (int i = tid; i < BB * 512; i += 256) {
    int b = i >> 9, n4 = i & 511;
    float4 v = *(const float4*)&z[((size_t)b * O + o) * NN + n4 * 4];
    a1 += v.x + v.y + v.z + v.w;
    a2 += v.x * v.x + v.y * v.y + v.z * v.z + v.w * v.w;
  }
  s1[tid] = a1; s2[tid] = a2;
  __syncthreads();
  for (int st = 128; st > 0; st >>= 1) {
    if (tid < st) { s1[tid] += s1[tid + st]; s2[tid] += s2[tid + st]; }
    __syncthreads();
  }
  if (tid == 0) {
    float m = s1[0] / (BB * NN);
    float var = s2[0] / (BB * NN) - m * m;
    smv = m; srv = rsqrtf(var + 1e-5f);
  }
  __syncthreads();
  float m = smv, r = srv;
  for (int i = tid; i < BB * 512; i += 256) {
    int b = i >> 9, n4 = i & 511;
    float4 v = *(const float4*)&z[((size_t)b * O + o) * NN + n4 * 4];
    float4 ov;
    ov.x = lrelu((v.x - m) * r); ov.y = lrelu((v.y - m) * r);
    ov.z = lrelu((v.z - m) * r); ov.w = lrelu((v.w - m) * r);
    *(float4*)&out[(size_t)b * outBS + (size_t)o * NN + n4 * 4] = ov;
  }
}

// ---------------------------------------------------------------- fused BN+LReLU+max/mean pool (conv5), float4
__global__ __launch_bounds__(256) void bn_pool_kernel(const float* __restrict__ z,
                                                      float* __restrict__ p) {
  int o = blockIdx.x;
  int tid = threadIdx.x;
  __shared__ float s1[256], s2[256];
  __shared__ float smv, srv;
  float a1 = 0.f, a2 = 0.f;
  for (int i = tid; i < BB * 512; i += 256) {
    int b = i >> 9, n4 = i & 511;
    float4 v = *(const float4*)&z[((size_t)b * 1024 + o) * NN + n4 * 4];
    a1 += v.x + v.y + v.z + v.w;
    a2 += v.x * v.x + v.y * v.y + v.z * v.z + v.w * v.w;
  }
  s1[tid] = a1; s2[tid] = a2;
  __syncthreads();
  for (int st = 128; st > 0; st >>= 1) {
    if (tid < st) { s1[tid] += s1[tid + st]; s2[tid] += s2[tid + st]; }
    __syncthreads();
  }
  if (tid == 0) {
    float m = s1[0] / (BB * NN);
    float var = s2[0] / (BB * NN) - m * m;
    smv = m; srv = rsqrtf(var + 1e-5f);
  }
  __syncthreads();
  float m = smv, r = srv;
  int b = tid >> 5, l = tid & 31;
  const float* zp = z + ((size_t)b * 1024 + o) * NN;
  float mx = -INFINITY, sm = 0.f;
  for (int j = l; j < 512; j += 32) {
    float4 v = *(const float4*)&zp[j * 4];
    float vx = lrelu((v.x - m) * r), vy = lrelu((v.y - m) * r);
    float vz = lrelu((v.z - m) * r), vw = lrelu((v.w - m) * r);
    mx = fmaxf(mx, fmaxf(fmaxf(vx, vy), fmaxf(vz, vw)));
    sm += vx + vy + vz + vw;
  }
#pragma unroll
  for (int s = 16; s > 0; s >>= 1) {
    mx = fmaxf(mx, __shfl_xor(mx, s));
    sm += __shfl_xor(sm, s);
  }
  if (l == 0) {
    p[b * 2048 + o] = mx;
    p[b * 2048 + 1024 + o] = sm * (1.f / NN);
  }
}

__global__ __launch_bounds__(64) void linear_kernel(const float* __restrict__ in, int IN, int OUT,
                                                    const float* __restrict__ w,
                                                    const float* __restrict__ bias,
                                                    float* __restrict__ out) {
  int o = blockIdx.x;
  int b = o / OUT, f = o % OUT;
  const float* ip = in + (size_t)b * IN;
  const float* wp = w + (size_t)f * IN;
  float a = 0.f;
  for (int i = threadIdx.x; i < IN; i += 64) a += ip[i] * wp[i];
#pragma unroll
  for (int s = 32; s > 0; s >>= 1) a += __shfl_down(a, s);
  if (threadIdx.x == 0) out[o] = a + bias[f];
}

__global__ __launch_bounds__(256) void bnf_kernel(float* __restrict__ t, int F) {
  int f = blockIdx.x * blockDim.x + threadIdx.x;
  if (f >= F) return;
  float s = 0.f, s2 = 0.f;
  for (int b = 0; b < BB; ++b) { float v = t[b * F + f]; s += v; s2 += v * v; }
  float m = s * (1.f / BB);
  float var = s2 * (1.f / BB) - m * m;
  float r = rsqrtf(var + 1e-5f);
  for (int b = 0; b < BB; ++b) {
    float v = (t[b * F + f] - m) * r;
    t[b * F + f] = v >= 0.f ? v : 0.2f * v;
  }
}

// ---------------------------------------------------------------- host side

struct SAW { const float *wq, *wk, *wv, *wc; };

static inline void run_conv(const float* in, int inBS, int C, int O, const float* w,
                            float* z, hipStream_t st) {
  if (O % 128 == 0)
    conv_gemm128_db_kernel<<<dim3(NN / 128, O / 128, BB), 256, 0, st>>>(in, inBS, C, O, w, z);
  else
    conv_gemm_kernel<<<dim3(NN / 64, (O + 63) / 64, BB), 256, 0, st>>>(in, inBS, C, O, w, z);
}

// MFMA==true only valid for C multiple of 128; PDM (f16-split pd) for C%32==0.
template <int C, bool MFMA>
static inline void run_sa(const float* xin, int xbs, SAW w,
                          float* xT, float* U, float* UT, float* AGGt,
                          float* AGG, float* z, float* h, float* sq, int* idx,
                          float* M, float* WCV, unsigned short* Mb, unsigned short* wcvb,
                          unsigned short* xTb, unsigned short* AGGtb,
                          _Float16* xhi, _Float16* xlo,
                          float* D, int nbatch, hipStream_t st) {
  constexpr bool PDM = (C % 32 == 0);
  sq_kernel<<<BB * NN / 256, 256, 0, st>>>(xin, xbs, C, sq);
  transpose_kernel<<<dim3(NN / 32, (C + 31) / 32, BB), 256, 0, st>>>(xin, xbs, C, NN, xT);
  prep_mw_kernel<<<(2 * C * C + 3) / 4, 256, 0, st>>>(w.wq, w.wk, w.wv, w.wc, C,
                                                      M, WCV, Mb, wcvb, MFMA ? 1 : 0);
  if (PDM)
    transpose_f16split_kernel<<<dim3(NN / 32, (C + 31) / 32, BB), 256, 0, st>>>(
        xin, xbs, C, NN, xhi, xlo);
  if (MFMA)
    transpose_bf16_kernel<<<dim3(NN / 32, (C + 31) / 32, BB), 256, 0, st>>>(xin, xbs, C, NN, xTb);
  for (int bb = 0; bb < BB; bb += nbatch) {
    int nbc = (BB - bb) < nbatch ? (BB - bb) : nbatch;
    if (PDM)
      pd_mfma_kernel<<<dim3(16, 16, nbc), 256, 0, st>>>(xhi, xlo, C, sq, D, bb);
    else
      pd_gemm128_db_kernel<<<dim3(NN / 128, NN / 128, nbc), 256, 0, st>>>(xin, xbs, C, sq, D, bb);
    topk_bsort_kernel<<<dim3(NN / 4, nbc), 256, 0, st>>>(D, idx, bb);
  }
  if (MFMA)
    mfma_gemm_lds_kernel<<<dim3(NN / 128, C / 128, BB), 256, 0, st>>>(Mb, xTb, U, C, C);
  else
    run_conv(xin, xbs, C, C, M, U, st);                            // U = M . x  [C][N]
  transpose_kernel<<<dim3(NN / 32, (C + 31) / 32, BB), 256, 0, st>>>(U, C * NN, C, NN, UT);
  if (MFMA) {
    att_wave_kernel<C, true><<<BB * NN, 64, 0, st>>>(xT, UT, idx, AGGt, AGGtb);
    mfma_gemm_lds_kernel<<<dim3(NN / 128, C / 128, BB), 256, 0, st>>>(wcvb, AGGtb, z, C, C);
  } else {
    att_wave_kernel<C, false><<<BB * NN, 64, 0, st>>>(xT, UT, idx, AGGt, AGGtb);
    transpose_kernel<<<dim3((C + 31) / 32, NN / 32, BB), 256, 0, st>>>(AGGt, NN * C, NN, C, AGG);
    run_conv(AGG, C * NN, C, C, WCV, z, st);                       // Z = (wc.wv) . AGG
  }
  bn_copy_kernel<<<2 * C, 256, 0, st>>>(z, C, xin, xbs, h);
}

static inline void run_conv_bn(const float* in, int inBS, int Cin, int O, const float* w,
                               float* z, float* out, int outBS, int c0, hipStream_t st) {
  run_conv(in, inBS, Cin, O, w, z, st);
  bn_fused_kernel<<<O, 256, 0, st>>>(z, O, out, outBS, c0);
}

extern "C" void kernel_launch(void* const* d_in, const int* in_sizes, int n_in,
                              void* d_out, int out_size, void* d_ws, size_t ws_size,
                              hipStream_t stream) {
  const float* x = (const float*)d_in[0];
  SAW sa1{(const float*)d_in[1], (const float*)d_in[2], (const float*)d_in[3], (const float*)d_in[4]};
  SAW sa2{(const float*)d_in[5], (const float*)d_in[6], (const float*)d_in[7], (const float*)d_in[8]};
  SAW sa3{(const float*)d_in[9], (const float*)d_in[10], (const float*)d_in[11], (const float*)d_in[12]};
  SAW sa4{(const float*)d_in[13], (const float*)d_in[14], (const float*)d_in[15], (const float*)d_in[16]};
  const float* conv1_w = (const float*)d_in[17];
  const float* conv2_w = (const float*)d_in[18];
  const float* conv3_w = (const float*)d_in[19];
  const float* conv4_w = (const float*)d_in[20];
  const float* conv5_w = (const float*)d_in[21];
  const float* lin1_w = (const float*)d_in[22];
  const float* lin1_b = (const float*)d_in[23];
  const float* lin2_w = (const float*)d_in[24];
  const float* lin2_b = (const float*)d_in[25];
  const float* lin3_w = (const float*)d_in[26];
  const float* lin3_b = (const float*)d_in[27];

  char* ws = (char*)d_ws;
  size_t off = 0;
  auto take = [&](size_t bytes) -> void* {
    void* p = ws + off;
    off += (bytes + 255) & ~(size_t)255;
    return p;
  };
  float* sq   = (float*)take((size_t)BB * NN * 4);
  int*   idx  = (int*)take((size_t)BB * NN * KNB * 4);
  float* M    = (float*)take((size_t)128 * 128 * 4);
  float* WCV  = (float*)take((size_t)128 * 128 * 4);
  unsigned short* Mb   = (unsigned short*)take((size_t)128 * 128 * 2);
  unsigned short* wcvb = (unsigned short*)take((size_t)128 * 128 * 2);
  unsigned short* w4b  = (unsigned short*)take((size_t)256 * 256 * 2);
  unsigned short* w5b  = (unsigned short*)take((size_t)1024 * 512 * 2);
  float* U    = (float*)take((size_t)BB * 128 * NN * 4);  // contiguous with AGG
  float* AGG  = (float*)take((size_t)BB * 128 * NN * 4);  // also hosts xT
  float* h    = (float*)take((size_t)BB * 256 * NN * 4);  // overlays below
  float* z    = (float*)take((size_t)BB * 1024 * NN * 4); // hosts AGGt, AGGtb(+16MB), D-chunks
  float* xc   = (float*)take((size_t)BB * 512 * NN * 4);
  float* p    = (float*)take((size_t)BB * 2048 * 4);
  float* t1   = (float*)take((size_t)BB * 512 * 4);
  float* t2   = (float*)take((size_t)BB * 256 * 4);
  (void)n_in; (void)in_sizes; (void)out_size;

  // Overlays (phase-ordered lifetimes):
  float* xT = AGG;                                          // dead before AGG written
  float* UT = h;                                            // consumed before h written
  float* AGGt = z;                                          // first 8.4 MB of z
  unsigned short* xTb   = (unsigned short*)((char*)h + (size_t)BB * 128 * NN * 4);  // h 2nd half
  unsigned short* AGGtb = (unsigned short*)((char*)z + (size_t)16 * 1024 * 1024);   // z + 16 MB
  unsigned short* hTb   = (unsigned short*)U;               // conv4 phase (U dead)
  unsigned short* xcTb  = (unsigned short*)U;               // conv5 phase (U+AGG dead, 16.8 MB)
  _Float16* xhi = (_Float16*)h;                             // pd phase only (UT written after)
  _Float16* xlo = (_Float16*)((char*)h + (size_t)BB * NN * 128 * 2);

  size_t dfull = (size_t)BB * NN * NN * 4;
  bool fullD = (ws_size > off + dfull + 4096);
  float* D = fullD ? (float*)take(dfull) : z;               // !fullD: 4-batch chunks fill z exactly
  int nbatch = fullD ? BB : 4;

  // SA1 (C=3) -> h [B,6,N]  (fp32 pd; C=3 not MFMA-tileable)
  run_sa<3, false>(x, 3 * NN, sa1, xT, U, UT, AGGt, AGG, z, h, sq, idx,
                   M, WCV, Mb, wcvb, xTb, AGGtb, xhi, xlo, D, nbatch, stream);
  run_conv_bn(h, 6 * NN, 6, 64, conv1_w, z, xc, 512 * NN, 0, stream);
  // SA2 (C=64) on x1  (f16-split MFMA pd)
  run_sa<64, false>(xc + 0 * NN, 512 * NN, sa2, xT, U, UT, AGGt, AGG, z, h, sq, idx,
                    M, WCV, Mb, wcvb, xTb, AGGtb, xhi, xlo, D, nbatch, stream);
  run_conv_bn(h, 128 * NN, 128, 64, conv2_w, z, xc, 512 * NN, 64, stream);
  // SA3 (C=64) on x2
  run_sa<64, false>(xc + 64 * NN, 512 * NN, sa3, xT, U, UT, AGGt, AGG, z, h, sq, idx,
                    M, WCV, Mb, wcvb, xTb, AGGtb, xhi, xlo, D, nbatch, stream);
  run_conv_bn(h, 128 * NN, 128, 128, conv3_w, z, xc, 512 * NN, 128, stream);
  // SA4 (C=128) on x3 — bf16 MFMA for U and Z convs (no kNN downstream)
  run_sa<128, true>(xc + 128 * NN, 512 * NN, sa4, xT, U, UT, AGGt, AGG, z, h, sq, idx,
                    M, WCV, Mb, wcvb, xTb, AGGtb, xhi, xlo, D, nbatch, stream);
  // conv4 (bf16 MFMA): h [B,256,N] -> z [B,256,N]
  transpose_bf16_kernel<<<dim3(NN / 32, 8, BB), 256, 0, stream>>>(h, 256 * NN, 256, NN, hTb);
  convert_bf16_kernel<<<(256 * 256 + 255) / 256, 256, 0, stream>>>(conv4_w, w4b, 256 * 256);
  mfma_gemm_lds_kernel<<<dim3(NN / 128, 2, BB), 256, 0, stream>>>(w4b, hTb, z, 256, 256);
  bn_fused_kernel<<<256, 256, 0, stream>>>(z, 256, xc, 512 * NN, 256);
  // conv5 (bf16 MFMA): xc [B,512,N] -> z [B,1024,N]; BN+LReLU+pool -> p
  transpose_bf16_kernel<<<dim3(NN / 32, 16, BB), 256, 0, stream>>>(xc, 512 * NN, 512, NN, xcTb);
  convert_bf16_kernel<<<(1024 * 512 + 255) / 256, 256, 0, stream>>>(conv5_w, w5b, 1024 * 512);
  mfma_gemm_lds_kernel<<<dim3(NN / 128, 8, BB), 256, 0, stream>>>(w5b, xcTb, z, 1024, 512);
  bn_pool_kernel<<<1024, 256, 0, stream>>>(z, p);
  // FC head
  linear_kernel<<<BB * 512, 64, 0, stream>>>(p, 2048, 512, lin1_w, lin1_b, t1);
  bnf_kernel<<<2, 256, 0, stream>>>(t1, 512);
  linear_kernel<<<BB * 256, 64, 0, stream>>>(t1, 512, 256, lin2_w, lin2_b, t2);
  bnf_kernel<<<1, 256, 0, stream>>>(t2, 256);
  linear_kernel<<<BB * 40, 64, 0, stream>>>(t2, 256, 40, lin3_w, lin3_b, (float*)d_out);
}

// Round 18
// 966.554 us; speedup vs baseline: 1.9766x; 1.0671x over previous
//
#include <hip/hip_runtime.h>
#include <math.h>

#define BB 8
#define NN 2048
#define KNB 20

typedef __attribute__((ext_vector_type(8))) short bf16x8;
typedef __attribute__((ext_vector_type(8))) _Float16 f16x8;
typedef __attribute__((ext_vector_type(4))) float f32x4;

__device__ inline unsigned short f2bf(float f) {
  union { float f; unsigned u; } v; v.f = f;
  unsigned r = v.u + 0x7FFF + ((v.u >> 16) & 1);  // RNE
  return (unsigned short)(r >> 16);
}

__device__ inline float lrelu(float v) { return v >= 0.f ? v : 0.2f * v; }

// ---------------------------------------------------------------- fused x-prep
// One pass over x per SA: transpose to xT [n][C] (fp32), optional f16 hi/lo
// split (pd), optional bf16 copy (SA4 MFMA convs), and sq[b][n] partial sums
// via per-column block reduction + one atomicAdd per column (sq pre-zeroed by
// hipMemsetAsync). Replaces sq_kernel (r17 diagnosis: 64-block serial-C loop,
// same latency-bound pathology as r15's mprep) + up to 3 transpose passes.
template <bool F16SPLIT, bool BF16>
__global__ __launch_bounds__(256) void xprep_kernel(
    const float* __restrict__ in, int inBS, int C,
    float* __restrict__ xT, _Float16* __restrict__ hi, _Float16* __restrict__ lo,
    unsigned short* __restrict__ bf, float* __restrict__ sq) {
  __shared__ float tile[32][33];
  __shared__ float ps[8][33];
  int b = blockIdx.z;
  const float* ip = in + (size_t)b * inBS;
  int c0 = blockIdx.x * 32;   // point index n
  int r0 = blockIdx.y * 32;   // channel index
  int tx = threadIdx.x & 31, ty = threadIdx.x >> 5;
  float s = 0.f;
  for (int yy = ty; yy < 32; yy += 8) {
    int r = r0 + yy;
    float v = (r < C) ? ip[(size_t)r * NN + c0 + tx] : 0.f;
    tile[yy][tx] = v;
    s += v * v;
  }
  ps[ty][tx] = s;
  __syncthreads();
  if (ty == 0) {
    float a = ps[0][tx];
#pragma unroll
    for (int u = 1; u < 8; ++u) a += ps[u][tx];
    atomicAdd(&sq[b * NN + c0 + tx], a);
  }
  for (int yy = ty; yy < 32; yy += 8) {
    int c = c0 + yy, r = r0 + tx;   // c = n, r = channel
    if (r < C) {
      float v = tile[tx][yy];
      size_t o = (size_t)b * NN * C + (size_t)c * C + r;
      xT[o] = v;
      if (F16SPLIT) {
        _Float16 hv = (_Float16)v;
        hi[o] = hv;
        lo[o] = (_Float16)(v - (float)hv);
      }
      if (BF16) bf[o] = f2bf(v);
    }
  }
}

// ---------------------------------------------------------------- fused weight prep
// wave-per-output with lane-split reduction (r15: serial-loop version was
// latency-bound at 47 us; this is ~3 us).
__global__ __launch_bounds__(256) void prep_mw_kernel(
    const float* __restrict__ wq, const float* __restrict__ wk,
    const float* __restrict__ wv, const float* __restrict__ wc, int C,
    float* __restrict__ M, float* __restrict__ WCV,
    unsigned short* __restrict__ Mb, unsigned short* __restrict__ wcvb, int emitBF) {
  int w = blockIdx.x * 4 + (threadIdx.x >> 6);
  int lane = threadIdx.x & 63;
  int total = 2 * C * C;
  if (w >= total) return;
  float a = 0.f;
  if (w < C * C) {
    int c = w / C, cp = w - c * C;
    for (int e = lane; e < C; e += 64) a += wk[e * C + c] * wq[e * C + cp];
  } else {
    int t = w - C * C;
    int o = t / C, c = t - o * C;
    for (int e = lane; e < C; e += 64) a += wc[o * C + e] * wv[e * C + c];
  }
#pragma unroll
  for (int s = 32; s > 0; s >>= 1) a += __shfl_down(a, s);
  if (lane == 0) {
    if (w < C * C) {
      M[w] = a;
      if (emitBF) Mb[w] = f2bf(a);
    } else {
      int t = w - C * C;
      WCV[t] = a;
      if (emitBF) wcvb[t] = f2bf(a);
    }
  }
}

// ---------------------------------------------------------------- converts (conv4/5 weights)
__global__ __launch_bounds__(256) void convert_bf16_kernel(const float* __restrict__ in,
                                                           unsigned short* __restrict__ out,
                                                           int count) {
  int i = blockIdx.x * 256 + threadIdx.x;
  if (i < count) out[i] = f2bf(in[i]);
}

// ---------------------------------------------------------------- transpose (fp32) — UT only
__global__ __launch_bounds__(256) void transpose_kernel(const float* __restrict__ in, int inBS,
                                                        int R, int Cl, float* __restrict__ out) {
  __shared__ float tile[32][33];
  int b = blockIdx.z;
  const float* ip = in + (size_t)b * inBS;
  float* op = out + (size_t)b * R * Cl;
  int c0 = blockIdx.x * 32, r0 = blockIdx.y * 32;
  int tx = threadIdx.x & 31, ty = threadIdx.x >> 5;
  for (int yy = ty; yy < 32; yy += 8) {
    int r = r0 + yy, c = c0 + tx;
    tile[yy][tx] = (r < R && c < Cl) ? ip[(size_t)r * Cl + c] : 0.f;
  }
  __syncthreads();
  for (int yy = ty; yy < 32; yy += 8) {
    int c = c0 + yy, r = r0 + tx;
    if (c < Cl && r < R) op[(size_t)c * R + r] = tile[tx][yy];
  }
}

// ---------------------------------------------------------------- transpose + bf16 convert (conv4/5 activations)
__global__ __launch_bounds__(256) void transpose_bf16_kernel(const float* __restrict__ in, int inBS,
                                                             int R, int Cl,
                                                             unsigned short* __restrict__ out) {
  __shared__ float tile[32][33];
  int b = blockIdx.z;
  const float* ip = in + (size_t)b * inBS;
  unsigned short* op = out + (size_t)b * R * Cl;
  int c0 = blockIdx.x * 32, r0 = blockIdx.y * 32;
  int tx = threadIdx.x & 31, ty = threadIdx.x >> 5;
  for (int yy = ty; yy < 32; yy += 8) {
    int r = r0 + yy, c = c0 + tx;
    tile[yy][tx] = (r < R && c < Cl) ? ip[(size_t)r * Cl + c] : 0.f;
  }
  __syncthreads();
  for (int yy = ty; yy < 32; yy += 8) {
    int c = c0 + yy, r = r0 + tx;
    if (c < Cl && r < R) op[(size_t)c * R + r] = f2bf(tile[tx][yy]);
  }
}

// ---------------------------------------------------------------- MFMA GEMM, LDS double-buffered (bf16)
__global__ __launch_bounds__(256, 2) void mfma_gemm_lds_kernel(
    const unsigned short* __restrict__ A, const unsigned short* __restrict__ B,
    float* __restrict__ Z, int O, int K) {
  const int b = blockIdx.z;
  const int n0 = blockIdx.x * 128, o0 = blockIdx.y * 128;
  const int tid = threadIdx.x;
  const int wave = tid >> 6, lane = tid & 63;
  const int wo = wave >> 1, wn = wave & 1;
  const int l16 = lane & 15, q = lane >> 4;
  __shared__ unsigned short Al[2][4096];
  __shared__ unsigned short Bl[2][4096];
  const unsigned short* Ab = A + (size_t)o0 * K;
  const unsigned short* Bb = B + ((size_t)b * NN + n0) * K;

  const int p0 = tid, p1 = tid + 256;
  const int r0 = ((p0 >> 6) << 4) | (p0 & 15), c0 = ((p0 >> 4) & 3) * 8;
  const int r1 = ((p1 >> 6) << 4) | (p1 & 15), c1 = ((p1 >> 4) & 3) * 8;

  bf16x8 ar0, ar1, br0, br1;
  auto gload = [&](int k0) {
    ar0 = *(const bf16x8*)(Ab + (size_t)r0 * K + k0 + c0);
    ar1 = *(const bf16x8*)(Ab + (size_t)r1 * K + k0 + c1);
    br0 = *(const bf16x8*)(Bb + (size_t)r0 * K + k0 + c0);
    br1 = *(const bf16x8*)(Bb + (size_t)r1 * K + k0 + c1);
  };
  auto sstore = [&](int buf) {
    *(bf16x8*)&Al[buf][p0 * 8] = ar0;
    *(bf16x8*)&Al[buf][p1 * 8] = ar1;
    *(bf16x8*)&Bl[buf][p0 * 8] = br0;
    *(bf16x8*)&Bl[buf][p1 * 8] = br1;
  };

  f32x4 acc[4][4];
#pragma unroll
  for (int s = 0; s < 4; ++s)
#pragma unroll
    for (int t = 0; t < 4; ++t) acc[s][t] = (f32x4){0.f, 0.f, 0.f, 0.f};

  gload(0);
  sstore(0);
  int cur = 0;
  for (int k0 = 0; k0 < K; k0 += 32) {
    bool more = (k0 + 32) < K;
    if (more) gload(k0 + 32);
    __syncthreads();
    bf16x8 af[4], bfr[4];
#pragma unroll
    for (int s = 0; s < 4; ++s)
      af[s] = *(const bf16x8*)&Al[cur][((wo * 4 + s) * 64 + q * 16 + l16) * 8];
#pragma unroll
    for (int t = 0; t < 4; ++t)
      bfr[t] = *(const bf16x8*)&Bl[cur][((wn * 4 + t) * 64 + q * 16 + l16) * 8];
#pragma unroll
    for (int s = 0; s < 4; ++s)
#pragma unroll
      for (int t = 0; t < 4; ++t)
        acc[s][t] = __builtin_amdgcn_mfma_f32_16x16x32_bf16(af[s], bfr[t], acc[s][t], 0, 0, 0);
    if (more) sstore(cur ^ 1);
    cur ^= 1;
  }
#pragma unroll
  for (int s = 0; s < 4; ++s)
#pragma unroll
    for (int t = 0; t < 4; ++t) {
      float* zp = Z + ((size_t)b * O + o0 + wo * 64 + s * 16 + q * 4) * NN
                  + n0 + wn * 64 + t * 16 + l16;
#pragma unroll
      for (int r = 0; r < 4; ++r) zp[(size_t)r * NN] = acc[s][t][r];
    }
}

// ---------------------------------------------------------------- pd via f16 split MFMA
// hi.hi + hi.lo + lo.hi; rel err ~5e-7 (fp32-level) -> selection unchanged.
__global__ __launch_bounds__(256, 2) void pd_mfma_kernel(
    const _Float16* __restrict__ xhi, const _Float16* __restrict__ xlo, int C,
    const float* __restrict__ sq, float* __restrict__ P, int b_base) {
  const int bl = blockIdx.z;
  const int b = b_base + bl;
  const int n0 = blockIdx.x * 128, m0 = blockIdx.y * 128;
  const int tid = threadIdx.x;
  const int wave = tid >> 6, lane = tid & 63;
  const int wn_ = wave >> 1, wm_ = wave & 1;
  const int l16 = lane & 15, q = lane >> 4;
  __shared__ _Float16 Ah[4096], Al[4096], Bh[4096], Bl[4096];
  const _Float16* Ahg = xhi + ((size_t)b * NN + n0) * C;
  const _Float16* Alg = xlo + ((size_t)b * NN + n0) * C;
  const _Float16* Bhg = xhi + ((size_t)b * NN + m0) * C;
  const _Float16* Blg = xlo + ((size_t)b * NN + m0) * C;

  const int p0 = tid, p1 = tid + 256;
  const int r0 = ((p0 >> 6) << 4) | (p0 & 15), c0 = ((p0 >> 4) & 3) * 8;
  const int r1 = ((p1 >> 6) << 4) | (p1 & 15), c1 = ((p1 >> 4) & 3) * 8;

  f32x4 acc[4][4];
#pragma unroll
  for (int s = 0; s < 4; ++s)
#pragma unroll
    for (int t = 0; t < 4; ++t) acc[s][t] = (f32x4){0.f, 0.f, 0.f, 0.f};

  for (int k0 = 0; k0 < C; k0 += 32) {
    __syncthreads();
    *(f16x8*)&Ah[p0 * 8] = *(const f16x8*)(Ahg + (size_t)r0 * C + k0 + c0);
    *(f16x8*)&Ah[p1 * 8] = *(const f16x8*)(Ahg + (size_t)r1 * C + k0 + c1);
    *(f16x8*)&Al[p0 * 8] = *(const f16x8*)(Alg + (size_t)r0 * C + k0 + c0);
    *(f16x8*)&Al[p1 * 8] = *(const f16x8*)(Alg + (size_t)r1 * C + k0 + c1);
    *(f16x8*)&Bh[p0 * 8] = *(const f16x8*)(Bhg + (size_t)r0 * C + k0 + c0);
    *(f16x8*)&Bh[p1 * 8] = *(const f16x8*)(Bhg + (size_t)r1 * C + k0 + c1);
    *(f16x8*)&Bl[p0 * 8] = *(const f16x8*)(Blg + (size_t)r0 * C + k0 + c0);
    *(f16x8*)&Bl[p1 * 8] = *(const f16x8*)(Blg + (size_t)r1 * C + k0 + c1);
    __syncthreads();
    f16x8 ah[4], al[4], bh[4], blv[4];
#pragma unroll
    for (int s = 0; s < 4; ++s) {
      int pi = ((wn_ * 4 + s) * 64 + q * 16 + l16) * 8;
      ah[s] = *(const f16x8*)&Ah[pi];
      al[s] = *(const f16x8*)&Al[pi];
    }
#pragma unroll
    for (int t = 0; t < 4; ++t) {
      int pi = ((wm_ * 4 + t) * 64 + q * 16 + l16) * 8;
      bh[t] = *(const f16x8*)&Bh[pi];
      blv[t] = *(const f16x8*)&Bl[pi];
    }
#pragma unroll
    for (int s = 0; s < 4; ++s)
#pragma unroll
      for (int t = 0; t < 4; ++t) {
        acc[s][t] = __builtin_amdgcn_mfma_f32_16x16x32_f16(ah[s], bh[t], acc[s][t], 0, 0, 0);
        acc[s][t] = __builtin_amdgcn_mfma_f32_16x16x32_f16(ah[s], blv[t], acc[s][t], 0, 0, 0);
        acc[s][t] = __builtin_amdgcn_mfma_f32_16x16x32_f16(al[s], bh[t], acc[s][t], 0, 0, 0);
      }
  }
#pragma unroll
  for (int s = 0; s < 4; ++s)
#pragma unroll
    for (int t = 0; t < 4; ++t) {
      int col = m0 + wm_ * 64 + t * 16 + l16;
      float sqv = sq[b * NN + col];
      float* pp = P + ((size_t)bl * NN + n0 + wn_ * 64 + s * 16 + q * 4) * NN + col;
#pragma unroll
      for (int r = 0; r < 4; ++r) pp[(size_t)r * NN] = 2.f * acc[s][t][r] - sqv;
    }
}

// ---------------------------------------------------------------- pd GEMM 128-tile, fp32 (SA1, C=3)
__global__ __launch_bounds__(256, 2) void pd_gemm128_db_kernel(
    const float* __restrict__ x, int bs, int C, const float* __restrict__ sq,
    float* __restrict__ P, int b_base) {
  const int b = b_base + blockIdx.z;
  const int n0 = blockIdx.x * 128, m0 = blockIdx.y * 128;
  const int tid = threadIdx.x;
  const int tm = tid & 15, tn = tid >> 4;
  __shared__ float As[2][16][128], Bs[2][16][128];
  const float* xb = x + (size_t)b * bs;
  float acc[8][8];
#pragma unroll
  for (int i = 0; i < 8; ++i)
#pragma unroll
    for (int j = 0; j < 8; ++j) acc[i][j] = 0.f;

  float4 ara[2], arb[2];
  auto load_tile = [&](int k0) {
#pragma unroll
    for (int it = 0; it < 2; ++it) {
      int i = it * 256 + tid;
      int kc = i >> 5, c4 = i & 31;
      bool ok = (k0 + kc) < C;
      ara[it] = ok ? *(const float4*)&xb[(size_t)(k0 + kc) * NN + n0 + c4 * 4]
                   : make_float4(0.f, 0.f, 0.f, 0.f);
      arb[it] = ok ? *(const float4*)&xb[(size_t)(k0 + kc) * NN + m0 + c4 * 4]
                   : make_float4(0.f, 0.f, 0.f, 0.f);
    }
  };
  auto store_tile = [&](int buf) {
#pragma unroll
    for (int it = 0; it < 2; ++it) {
      int i = it * 256 + tid;
      int kc = i >> 5, c4 = i & 31;
      *(float4*)&As[buf][kc][c4 * 4] = ara[it];
      *(float4*)&Bs[buf][kc][c4 * 4] = arb[it];
    }
  };

  load_tile(0);
  store_tile(0);
  int cur = 0;
  for (int k0 = 0; k0 < C; k0 += 16) {
    bool more = (k0 + 16) < C;
    if (more) load_tile(k0 + 16);
    __syncthreads();
#pragma unroll
    for (int kc = 0; kc < 16; ++kc) {
      float4 a0 = *(const float4*)&As[cur][kc][tn * 4];
      float4 a1 = *(const float4*)&As[cur][kc][64 + tn * 4];
      float4 b0 = *(const float4*)&Bs[cur][kc][tm * 4];
      float4 b1 = *(const float4*)&Bs[cur][kc][64 + tm * 4];
      float ar[8] = {a0.x, a0.y, a0.z, a0.w, a1.x, a1.y, a1.z, a1.w};
      float br[8] = {b0.x, b0.y, b0.z, b0.w, b1.x, b1.y, b1.z, b1.w};
#pragma unroll
      for (int i = 0; i < 8; ++i)
#pragma unroll
        for (int j = 0; j < 8; ++j) acc[i][j] += ar[i] * br[j];
    }
    if (more) store_tile(cur ^ 1);
    cur ^= 1;
  }
  float4 sqa = *(const float4*)&sq[b * NN + m0 + tm * 4];
  float4 sqb = *(const float4*)&sq[b * NN + m0 + 64 + tm * 4];
#pragma unroll
  for (int h = 0; h < 2; ++h)
#pragma unroll
    for (int i = 0; i < 4; ++i) {
      int r = h * 4 + i;
      int nn = n0 + h * 64 + tn * 4 + i;
      float* prow = &P[((size_t)blockIdx.z * NN + nn) * NN + m0];
      float4 o0, o1;
      o0.x = 2.f * acc[r][0] - sqa.x; o0.y = 2.f * acc[r][1] - sqa.y;
      o0.z = 2.f * acc[r][2] - sqa.z; o0.w = 2.f * acc[r][3] - sqa.w;
      o1.x = 2.f * acc[r][4] - sqb.x; o1.y = 2.f * acc[r][5] - sqb.y;
      o1.z = 2.f * acc[r][6] - sqb.z; o1.w = 2.f * acc[r][7] - sqb.w;
      *(float4*)&prow[tm * 4] = o0;
      *(float4*)&prow[64 + tm * 4] = o1;
    }
}

// ---------------------------------------------------------------- top-20: EXACT-key bitonic + idx array
__global__ __launch_bounds__(256) void topk_bsort_kernel(const float* __restrict__ P,
                                                         int* __restrict__ idx_out, int b_base) {
  const int wave = threadIdx.x >> 6;
  const int lane = threadIdx.x & 63;
  const int n = blockIdx.x * 4 + wave;
  const int bl = blockIdx.y;
  const int b = b_base + bl;
  const float4* rp = (const float4*)(P + ((size_t)bl * NN + n) * NN);
  unsigned key[32], mv[32];
#pragma unroll
  for (int q = 0; q < 8; ++q) {
    float4 vv = rp[q * 64 + lane];
    int mb = q * 256 + lane * 4;
    float fv[4] = {vv.x, vv.y, vv.z, vv.w};
#pragma unroll
    for (int j = 0; j < 4; ++j) {
      unsigned u = __float_as_uint(fv[j]);
      unsigned mask = (unsigned)(((int)u) >> 31) | 0x80000000u;
      key[q * 4 + j] = (mb + j == n) ? 0u : (u ^ mask);
      mv[q * 4 + j] = (unsigned)(mb + j);
    }
  }
#pragma unroll
  for (int k = 2; k <= 32; k <<= 1) {
#pragma unroll
    for (int j = k >> 1; j > 0; j >>= 1) {
#pragma unroll
      for (int i = 0; i < 32; ++i) {
        int l = i ^ j;
        if (l > i) {
          unsigned ka = key[i], kb = key[l];
          unsigned ia = mv[i], ib = mv[l];
          bool agt = ka > kb;
          unsigned kmax = agt ? ka : kb, kmin = agt ? kb : ka;
          unsigned imax = agt ? ia : ib, imin = agt ? ib : ia;
          if ((i & k) == 0) { key[i] = kmax; mv[i] = imax; key[l] = kmin; mv[l] = imin; }
          else              { key[i] = kmin; mv[i] = imin; key[l] = kmax; mv[l] = imax; }
        }
      }
    }
  }
  int* op = idx_out + (size_t)(b * NN + n) * KNB;
  for (int k = 0; k < KNB; ++k) {
    unsigned best = key[0];
#pragma unroll
    for (int s = 32; s > 0; s >>= 1) {
      unsigned o = (unsigned)__shfl_xor((int)best, s);
      best = best > o ? best : o;
    }
    bool own = (key[0] == best);
    if (own) {
      op[k] = (int)mv[0];
#pragma unroll
      for (int j = 0; j < 20; ++j) { key[j] = key[j + 1]; mv[j] = mv[j + 1]; }
    }
  }
}

// ---------------------------------------------------------------- conv GEMM 64-tile (small O)
__global__ __launch_bounds__(256, 2) void conv_gemm_kernel(
    const float* __restrict__ in, int inBS, int C, int O,
    const float* __restrict__ w, float* __restrict__ z) {
  const int b = blockIdx.z;
  const int n0 = blockIdx.x * 64, o0 = blockIdx.y * 64;
  const int tid = threadIdx.x;
  const int tm = tid & 15, tn = tid >> 4;
  __shared__ float Ws[16][68];
  __shared__ float Xs[16][64];
  const float* ib = in + (size_t)b * inBS;
  float acc[4][4];
#pragma unroll
  for (int i = 0; i < 4; ++i)
#pragma unroll
    for (int j = 0; j < 4; ++j) acc[i][j] = 0.f;

  for (int k0 = 0; k0 < C; k0 += 16) {
    __syncthreads();
#pragma unroll
    for (int it = 0; it < 4; ++it) {
      int i = it * 256 + tid;
      int kc = i >> 6, nl = i & 63;
      Xs[kc][nl] = ((k0 + kc) < C) ? ib[(size_t)(k0 + kc) * NN + n0 + nl] : 0.f;
      int ol = i >> 4, kc2 = i & 15;
      Ws[kc2][ol] = ((o0 + ol) < O && (k0 + kc2) < C) ? w[(size_t)(o0 + ol) * C + k0 + kc2] : 0.f;
    }
    __syncthreads();
#pragma unroll
    for (int kc = 0; kc < 16; ++kc) {
      float4 a = *(const float4*)&Ws[kc][tn * 4];
      float4 bv = *(const float4*)&Xs[kc][tm * 4];
      acc[0][0] += a.x * bv.x; acc[0][1] += a.x * bv.y; acc[0][2] += a.x * bv.z; acc[0][3] += a.x * bv.w;
      acc[1][0] += a.y * bv.x; acc[1][1] += a.y * bv.y; acc[1][2] += a.y * bv.z; acc[1][3] += a.y * bv.w;
      acc[2][0] += a.z * bv.x; acc[2][1] += a.z * bv.y; acc[2][2] += a.z * bv.z; acc[2][3] += a.z * bv.w;
      acc[3][0] += a.w * bv.x; acc[3][1] += a.w * bv.y; acc[3][2] += a.w * bv.z; acc[3][3] += a.w * bv.w;
    }
  }
#pragma unroll
  for (int i = 0; i < 4; ++i) {
    int o = o0 + tn * 4 + i;
    if (o < O) {
      float4 ov;
      ov.x = acc[i][0]; ov.y = acc[i][1]; ov.z = acc[i][2]; ov.w = acc[i][3];
      *(float4*)&z[((size_t)b * O + o) * NN + n0 + tm * 4] = ov;
    }
  }
}

// ---------------------------------------------------------------- conv GEMM 128-tile, double-buffered (fp32)
__global__ __launch_bounds__(256, 2) void conv_gemm128_db_kernel(
    const float* __restrict__ in, int inBS, int C, int O,
    const float* __restrict__ w, float* __restrict__ z) {
  const int b = blockIdx.z;
  const int n0 = blockIdx.x * 128, o0 = blockIdx.y * 128;
  const int tid = threadIdx.x;
  const int tm = tid & 15, tn = tid >> 4;
  __shared__ float Xs[2][16][128];
  __shared__ float Ws[2][16][132];
  const float* ib = in + (size_t)b * inBS;
  float acc[8][8];
#pragma unroll
  for (int i = 0; i < 8; ++i)
#pragma unroll
    for (int j = 0; j < 8; ++j) acc[i][j] = 0.f;

  float4 xr[2], wr[2];
  auto load_tile = [&](int k0) {
#pragma unroll
    for (int it = 0; it < 2; ++it) {
      int i = it * 256 + tid;
      int kc = i >> 5, c4 = i & 31;
      xr[it] = ((k0 + kc) < C) ? *(const float4*)&ib[(size_t)(k0 + kc) * NN + n0 + c4 * 4]
                               : make_float4(0.f, 0.f, 0.f, 0.f);
      int ol = i >> 2, kq = i & 3;
      wr[it] = ((k0 + kq * 4) < C) ? *(const float4*)&w[(size_t)(o0 + ol) * C + k0 + kq * 4]
                                   : make_float4(0.f, 0.f, 0.f, 0.f);
    }
  };
  auto store_tile = [&](int buf) {
#pragma unroll
    for (int it = 0; it < 2; ++it) {
      int i = it * 256 + tid;
      int kc = i >> 5, c4 = i & 31;
      *(float4*)&Xs[buf][kc][c4 * 4] = xr[it];
      int ol = i >> 2, kq = i & 3;
      Ws[buf][kq * 4 + 0][ol] = wr[it].x;
      Ws[buf][kq * 4 + 1][ol] = wr[it].y;
      Ws[buf][kq * 4 + 2][ol] = wr[it].z;
      Ws[buf][kq * 4 + 3][ol] = wr[it].w;
    }
  };

  load_tile(0);
  store_tile(0);
  int cur = 0;
  for (int k0 = 0; k0 < C; k0 += 16) {
    bool more = (k0 + 16) < C;
    if (more) load_tile(k0 + 16);
    __syncthreads();
#pragma unroll
    for (int kc = 0; kc < 16; ++kc) {
      float4 a0 = *(const float4*)&Ws[cur][kc][tn * 4];
      float4 a1 = *(const float4*)&Ws[cur][kc][64 + tn * 4];
      float4 b0 = *(const float4*)&Xs[cur][kc][tm * 4];
      float4 b1 = *(const float4*)&Xs[cur][kc][64 + tm * 4];
      float ar[8] = {a0.x, a0.y, a0.z, a0.w, a1.x, a1.y, a1.z, a1.w};
      float br[8] = {b0.x, b0.y, b0.z, b0.w, b1.x, b1.y, b1.z, b1.w};
#pragma unroll
      for (int i = 0; i < 8; ++i)
#pragma unroll
        for (int j = 0; j < 8; ++j) acc[i][j] += ar[i] * br[j];
    }
    if (more) store_tile(cur ^ 1);
    cur ^= 1;
  }
#pragma unroll
  for (int h = 0; h < 2; ++h)
#pragma unroll
    for (int i = 0; i < 4; ++i) {
      int r = h * 4 + i;
      int o = o0 + h * 64 + tn * 4 + i;
      float* zrow = &z[((size_t)b * O + o) * NN + n0];
      float4 o0v, o1v;
      o0v.x = acc[r][0]; o0v.y = acc[r][1]; o0v.z = acc[r][2]; o0v.w = acc[r][3];
      o1v.x = acc[r][4]; o1v.y = acc[r][5]; o1v.z = acc[r][6]; o1v.w = acc[r][7];
      *(float4*)&zrow[tm * 4] = o0v;
      *(float4*)&zrow[64 + tm * 4] = o1v;
    }
}

// ---------------------------------------------------------------- attention (wave/point)
template <int C, bool BF16OUT>
__global__ __launch_bounds__(64) void att_wave_kernel(
    const float* __restrict__ xT, const float* __restrict__ UT,
    const int* __restrict__ idx, float* __restrict__ AGGt,
    unsigned short* __restrict__ AGGtb) {
  const int n = blockIdx.x & (NN - 1);
  const int b = blockIdx.x >> 11;
  const int lane = threadIdx.x;
  constexpr int CP = C + 1;
  __shared__ float nb[KNB][CP];
  __shared__ float sl[KNB];
  __shared__ int nidx[KNB];
  __shared__ float ul[C];
  const float* xTb = xT + (size_t)b * NN * C;
  if (lane < KNB) nidx[lane] = idx[(size_t)(b * NN + n) * KNB + lane];
  for (int c = lane; c < C; c += 64) ul[c] = UT[((size_t)b * NN + n) * C + c];
  __syncthreads();
  for (int i = lane; i < KNB * C; i += 64) {
    int k = i / C, c = i - k * C;
    nb[k][c] = xTb[(size_t)nidx[k] * C + c];
  }
  __syncthreads();
  float sv = -INFINITY;
  if (lane < KNB) {
    float a = 0.f;
#pragma unroll
    for (int c = 0; c < C; ++c) a += nb[lane][c] * ul[c];
    sv = a / sqrtf((float)C);
  }
  float mx = sv;
#pragma unroll
  for (int s = 32; s > 0; s >>= 1) mx = fmaxf(mx, __shfl_xor(mx, s));
  float e = (lane < KNB) ? expf(sv - mx) : 0.f;
  float sum = e;
#pragma unroll
  for (int s = 32; s > 0; s >>= 1) sum += __shfl_xor(sum, s);
  if (lane < KNB) sl[lane] = e / sum;
  __syncthreads();
  const float* xTn = xTb + (size_t)n * C;
  for (int c = lane; c < C; c += 64) {
    float a = 0.f;
#pragma unroll
    for (int k = 0; k < KNB; ++k) a += sl[k] * nb[k][c];
    float r = a - xTn[c];
    if (BF16OUT)
      AGGtb[((size_t)b * NN + n) * C + c] = f2bf(r);
    else
      AGGt[((size_t)b * NN + n) * C + c] = r;
  }
}

// ---------------------------------------------------------------- fused BN (+LReLU), float4
__global__ __launch_bounds__(256) void bn_fused_kernel(const float* __restrict__ z, int O,
                                                       float* __restrict__ out, int outBS, int c0) {
  int o = blockIdx.x;
  int tid = threadIdx.x;
  __shared__ float s1[256], s2[256];
  __shared__ float smv, srv;
  float a1 = 0.f, a2 = 0.f;
  for (int i = tid; i < BB * 512; i += 256) {
    int b = i >> 9, n4 = i & 511;
    float4 v = *(const float4*)&z[((size_t)b * O + o) * NN + n4 * 4];
    a1 += v.x + v.y + v.z + v.w;
    a2 += v.x * v.x + v.y * v.y + v.z * v.z + v.w * v.w;
  }
  s1[tid] = a1; s2[tid] = a2;
  __syncthreads();
  for (int st = 128; st > 0; st >>= 1) {
    if (tid < st) { s1[tid] += s1[tid + st]; s2[tid] += s2[tid + st]; }
    __syncthreads();
  }
  if (tid == 0) {
    float m = s1[0] / (BB * NN);
    float var = s2[0] / (BB * NN) - m * m;
    smv = m; srv = rsqrtf(var + 1e-5f);
  }
  __syncthreads();
  float m = smv, r = srv;
  for (int i = tid; i < BB * 512; i += 256) {
    int b = i >> 9, n4 = i & 511;
    float4 v = *(const float4*)&z[((size_t)b * O + o) * NN + n4 * 4];
    float4 ov;
    ov.x = lrelu((v.x - m) * r); ov.y = lrelu((v.y - m) * r);
    ov.z = lrelu((v.z - m) * r); ov.w = lrelu((v.w - m) * r);
    *(float4*)&out[(size_t)b * outBS + (size_t)(c0 + o) * NN + n4 * 4] = ov;
  }
}

// ---------------------------------------------------------------- BN+LReLU into h[:,0:O,:], copy xin into h[:,O:2O,:], float4
__global__ __launch_bounds__(256) void bn_copy_kernel(const float* __restrict__ z, int O,
                                                      const float* __restrict__ xin, int xbs,
                                                      float* __restrict__ out) {
  int o = blockIdx.x;  // 0..2O-1
  int tid = threadIdx.x;
  int outBS = 2 * O * NN;
  if (o >= O) {
    int c = o - O;
    for (int i = tid; i < BB * 512; i += 256) {
      int b = i >> 9, n4 = i & 511;
      *(float4*)&out[(size_t)b * outBS + (size_t)o * NN + n4 * 4] =
          *(const float4*)&xin[(size_t)b * xbs + (size_t)c * NN + n4 * 4];
    }
    return;
  }
  __shared__ float s1[256], s2[256];
  __shared__ float smv, srv;
  float a1 = 0.f, a2 = 0.f;
  for (int i = tid; i < BB * 512; i += 256) {
    int b = i >> 9, n4 = i & 511;
    float4 v = *(const float4*)&z[((size_t)b * O + o) * NN + n4 * 4];
    a1 += v.x + v.y + v.z + v.w;
    a2 += v.x * v.x + v.y * v.y + v.z * v.z + v.w * v.w;
  }
  s1[tid] = a1; s2[tid] = a2;
  __syncthreads();
  for (int st = 128; st > 0; st >>= 1) {
    if (tid < st) { s1[tid] += s1[tid + st]; s2[tid] += s2[tid + st]; }
    __syncthreads();
  }
  if (tid == 0) {
    float m = s1[0] / (BB * NN);
    float var = s2[0] / (BB * NN) - m * m;
    smv = m; srv = rsqrtf(var + 1e-5f);
  }
  __syncthreads();
  float m = smv, r = srv;
  for (int i = tid; i < BB * 512; i += 256) {
    int b = i >> 9, n4 = i & 511;
    float4 v = *(const float4*)&z[((size_t)b * O + o) * NN + n4 * 4];
    float4 ov;
    ov.x = lrelu((v.x - m) * r); ov.y = lrelu((v.y - m) * r);
    ov.z = lrelu((v.z - m) * r); ov.w = lrelu((v.w - m) * r);
    *(float4*)&out[(size_t)b * outBS + (size_t)o * NN + n4 * 4] = ov;
  }
}

// ---------------------------------------------------------------- fused BN+LReLU+max/mean pool (conv5), float4
__global__ __launch_bounds__(256) void bn_pool_kernel(const float* __restrict__ z,
                                                      float* __restrict__ p) {
  int o = blockIdx.x;
  int tid = threadIdx.x;
  __shared__ float s1[256], s2[256];
  __shared__ float smv, srv;
  float a1 = 0.f, a2 = 0.f;
  for (int i = tid; i < BB * 512; i += 256) {
    int b = i >> 9, n4 = i & 511;
    float4 v = *(const float4*)&z[((size_t)b * 1024 + o) * NN + n4 * 4];
    a1 += v.x + v.y + v.z + v.w;
    a2 += v.x * v.x + v.y * v.y + v.z * v.z + v.w * v.w;
  }
  s1[tid] = a1; s2[tid] = a2;
  __syncthreads();
  for (int st = 128; st > 0; st >>= 1) {
    if (tid < st) { s1[tid] += s1[tid + st]; s2[tid] += s2[tid + st]; }
    __syncthreads();
  }
  if (tid == 0) {
    float m = s1[0] / (BB * NN);
    float var = s2[0] / (BB * NN) - m * m;
    smv = m; srv = rsqrtf(var + 1e-5f);
  }
  __syncthreads();
  float m = smv, r = srv;
  int b = tid >> 5, l = tid & 31;
  const float* zp = z + ((size_t)b * 1024 + o) * NN;
  float mx = -INFINITY, sm = 0.f;
  for (int j = l; j < 512; j += 32) {
    float4 v = *(const float4*)&zp[j * 4];
    float vx = lrelu((v.x - m) * r), vy = lrelu((v.y - m) * r);
    float vz = lrelu((v.z - m) * r), vw = lrelu((v.w - m) * r);
    mx = fmaxf(mx, fmaxf(fmaxf(vx, vy), fmaxf(vz, vw)));
    sm += vx + vy + vz + vw;
  }
#pragma unroll
  for (int s = 16; s > 0; s >>= 1) {
    mx = fmaxf(mx, __shfl_xor(mx, s));
    sm += __shfl_xor(sm, s);
  }
  if (l == 0) {
    p[b * 2048 + o] = mx;
    p[b * 2048 + 1024 + o] = sm * (1.f / NN);
  }
}

__global__ __launch_bounds__(64) void linear_kernel(const float* __restrict__ in, int IN, int OUT,
                                                    const float* __restrict__ w,
                                                    const float* __restrict__ bias,
                                                    float* __restrict__ out) {
  int o = blockIdx.x;
  int b = o / OUT, f = o % OUT;
  const float* ip = in + (size_t)b * IN;
  const float* wp = w + (size_t)f * IN;
  float a = 0.f;
  for (int i = threadIdx.x; i < IN; i += 64) a += ip[i] * wp[i];
#pragma unroll
  for (int s = 32; s > 0; s >>= 1) a += __shfl_down(a, s);
  if (threadIdx.x == 0) out[o] = a + bias[f];
}

__global__ __launch_bounds__(256) void bnf_kernel(float* __restrict__ t, int F) {
  int f = blockIdx.x * blockDim.x + threadIdx.x;
  if (f >= F) return;
  float s = 0.f, s2 = 0.f;
  for (int b = 0; b < BB; ++b) { float v = t[b * F + f]; s += v; s2 += v * v; }
  float m = s * (1.f / BB);
  float var = s2 * (1.f / BB) - m * m;
  float r = rsqrtf(var + 1e-5f);
  for (int b = 0; b < BB; ++b) {
    float v = (t[b * F + f] - m) * r;
    t[b * F + f] = v >= 0.f ? v : 0.2f * v;
  }
}

// ---------------------------------------------------------------- host side

struct SAW { const float *wq, *wk, *wv, *wc; };

static inline void run_conv(const float* in, int inBS, int C, int O, const float* w,
                            float* z, hipStream_t st) {
  if (O % 128 == 0)
    conv_gemm128_db_kernel<<<dim3(NN / 128, O / 128, BB), 256, 0, st>>>(in, inBS, C, O, w, z);
  else
    conv_gemm_kernel<<<dim3(NN / 64, (O + 63) / 64, BB), 256, 0, st>>>(in, inBS, C, O, w, z);
}

// MFMA==true only valid for C multiple of 128; PDM (f16-split pd) for C%32==0.
template <int C, bool MFMA>
static inline void run_sa(const float* xin, int xbs, SAW w,
                          float* xT, float* U, float* UT, float* AGGt,
                          float* AGG, float* z, float* h, float* sq, int* idx,
                          float* M, float* WCV, unsigned short* Mb, unsigned short* wcvb,
                          unsigned short* xTb, unsigned short* AGGtb,
                          _Float16* xhi, _Float16* xlo,
                          float* D, int nbatch, hipStream_t st) {
  constexpr bool PDM = (C % 32 == 0);
  hipMemsetAsync(sq, 0, (size_t)BB * NN * 4, st);
  xprep_kernel<PDM, MFMA><<<dim3(NN / 32, (C + 31) / 32, BB), 256, 0, st>>>(
      xin, xbs, C, xT, xhi, xlo, xTb, sq);
  prep_mw_kernel<<<(2 * C * C + 3) / 4, 256, 0, st>>>(w.wq, w.wk, w.wv, w.wc, C,
                                                      M, WCV, Mb, wcvb, MFMA ? 1 : 0);
  for (int bb = 0; bb < BB; bb += nbatch) {
    int nbc = (BB - bb) < nbatch ? (BB - bb) : nbatch;
    if (PDM)
      pd_mfma_kernel<<<dim3(16, 16, nbc), 256, 0, st>>>(xhi, xlo, C, sq, D, bb);
    else
      pd_gemm128_db_kernel<<<dim3(NN / 128, NN / 128, nbc), 256, 0, st>>>(xin, xbs, C, sq, D, bb);
    topk_bsort_kernel<<<dim3(NN / 4, nbc), 256, 0, st>>>(D, idx, bb);
  }
  if (MFMA)
    mfma_gemm_lds_kernel<<<dim3(NN / 128, C / 128, BB), 256, 0, st>>>(Mb, xTb, U, C, C);
  else
    run_conv(xin, xbs, C, C, M, U, st);                            // U = M . x  [C][N]
  transpose_kernel<<<dim3(NN / 32, (C + 31) / 32, BB), 256, 0, st>>>(U, C * NN, C, NN, UT);
  if (MFMA) {
    att_wave_kernel<C, true><<<BB * NN, 64, 0, st>>>(xT, UT, idx, AGGt, AGGtb);
    mfma_gemm_lds_kernel<<<dim3(NN / 128, C / 128, BB), 256, 0, st>>>(wcvb, AGGtb, z, C, C);
  } else {
    att_wave_kernel<C, false><<<BB * NN, 64, 0, st>>>(xT, UT, idx, AGGt, AGGtb);
    transpose_kernel<<<dim3((C + 31) / 32, NN / 32, BB), 256, 0, st>>>(AGGt, NN * C, NN, C, AGG);
    run_conv(AGG, C * NN, C, C, WCV, z, st);                       // Z = (wc.wv) . AGG
  }
  bn_copy_kernel<<<2 * C, 256, 0, st>>>(z, C, xin, xbs, h);
}

static inline void run_conv_bn(const float* in, int inBS, int Cin, int O, const float* w,
                               float* z, float* out, int outBS, int c0, hipStream_t st) {
  run_conv(in, inBS, Cin, O, w, z, st);
  bn_fused_kernel<<<O, 256, 0, st>>>(z, O, out, outBS, c0);
}

extern "C" void kernel_launch(void* const* d_in, const int* in_sizes, int n_in,
                              void* d_out, int out_size, void* d_ws, size_t ws_size,
                              hipStream_t stream) {
  const float* x = (const float*)d_in[0];
  SAW sa1{(const float*)d_in[1], (const float*)d_in[2], (const float*)d_in[3], (const float*)d_in[4]};
  SAW sa2{(const float*)d_in[5], (const float*)d_in[6], (const float*)d_in[7], (const float*)d_in[8]};
  SAW sa3{(const float*)d_in[9], (const float*)d_in[10], (const float*)d_in[11], (const float*)d_in[12]};
  SAW sa4{(const float*)d_in[13], (const float*)d_in[14], (const float*)d_in[15], (const float*)d_in[16]};
  const float* conv1_w = (const float*)d_in[17];
  const float* conv2_w = (const float*)d_in[18];
  const float* conv3_w = (const float*)d_in[19];
  const float* conv4_w = (const float*)d_in[20];
  const float* conv5_w = (const float*)d_in[21];
  const float* lin1_w = (const float*)d_in[22];
  const float* lin1_b = (const float*)d_in[23];
  const float* lin2_w = (const float*)d_in[24];
  const float* lin2_b = (const float*)d_in[25];
  const float* lin3_w = (const float*)d_in[26];
  const float* lin3_b = (const float*)d_in[27];

  char* ws = (char*)d_ws;
  size_t off = 0;
  auto take = [&](size_t bytes) -> void* {
    void* p = ws + off;
    off += (bytes + 255) & ~(size_t)255;
    return p;
  };
  float* sq   = (float*)take((size_t)BB * NN * 4);
  int*   idx  = (int*)take((size_t)BB * NN * KNB * 4);
  float* M    = (float*)take((size_t)128 * 128 * 4);
  float* WCV  = (float*)take((size_t)128 * 128 * 4);
  unsigned short* Mb   = (unsigned short*)take((size_t)128 * 128 * 2);
  unsigned short* wcvb = (unsigned short*)take((size_t)128 * 128 * 2);
  unsigned short* w4b  = (unsigned short*)take((size_t)256 * 256 * 2);
  unsigned short* w5b  = (unsigned short*)take((size_t)1024 * 512 * 2);
  float* U    = (float*)take((size_t)BB * 128 * NN * 4);  // contiguous with AGG
  float* AGG  = (float*)take((size_t)BB * 128 * NN * 4);  // also hosts xT
  float* h    = (float*)take((size_t)BB * 256 * NN * 4);  // overlays below
  float* z    = (float*)take((size_t)BB * 1024 * NN * 4); // hosts AGGt, AGGtb(+16MB), D-chunks
  float* xc   = (float*)take((size_t)BB * 512 * NN * 4);
  float* p    = (float*)take((size_t)BB * 2048 * 4);
  float* t1   = (float*)take((size_t)BB * 512 * 4);
  float* t2   = (float*)take((size_t)BB * 256 * 4);
  (void)n_in; (void)in_sizes; (void)out_size;

  // Overlays (phase-ordered lifetimes):
  float* xT = AGG;                                          // dead before AGG written
  float* UT = h;                                            // consumed before h written
  float* AGGt = z;                                          // first 8.4 MB of z
  unsigned short* xTb   = (unsigned short*)((char*)h + (size_t)BB * 128 * NN * 4);  // h 2nd half
  unsigned short* AGGtb = (unsigned short*)((char*)z + (size_t)16 * 1024 * 1024);   // z + 16 MB
  unsigned short* hTb   = (unsigned short*)U;               // conv4 phase (U dead)
  unsigned short* xcTb  = (unsigned short*)U;               // conv5 phase (U+AGG dead, 16.8 MB)
  _Float16* xhi = (_Float16*)h;                             // pd phase only (UT written after)
  _Float16* xlo = (_Float16*)((char*)h + (size_t)BB * NN * 128 * 2);

  size_t dfull = (size_t)BB * NN * NN * 4;
  bool fullD = (ws_size > off + dfull + 4096);
  float* D = fullD ? (float*)take(dfull) : z;               // !fullD: 4-batch chunks fill z exactly
  int nbatch = fullD ? BB : 4;

  // SA1 (C=3) -> h [B,6,N]  (fp32 pd; C=3 not MFMA-tileable)
  run_sa<3, false>(x, 3 * NN, sa1, xT, U, UT, AGGt, AGG, z, h, sq, idx,
                   M, WCV, Mb, wcvb, xTb, AGGtb, xhi, xlo, D, nbatch, stream);
  run_conv_bn(h, 6 * NN, 6, 64, conv1_w, z, xc, 512 * NN, 0, stream);
  // SA2 (C=64) on x1  (f16-split MFMA pd)
  run_sa<64, false>(xc + 0 * NN, 512 * NN, sa2, xT, U, UT, AGGt, AGG, z, h, sq, idx,
                    M, WCV, Mb, wcvb, xTb, AGGtb, xhi, xlo, D, nbatch, stream);
  run_conv_bn(h, 128 * NN, 128, 64, conv2_w, z, xc, 512 * NN, 64, stream);
  // SA3 (C=64) on x2
  run_sa<64, false>(xc + 64 * NN, 512 * NN, sa3, xT, U, UT, AGGt, AGG, z, h, sq, idx,
                    M, WCV, Mb, wcvb, xTb, AGGtb, xhi, xlo, D, nbatch, stream);
  run_conv_bn(h, 128 * NN, 128, 128, conv3_w, z, xc, 512 * NN, 128, stream);
  // SA4 (C=128) on x3 — bf16 MFMA for U and Z convs (no kNN downstream)
  run_sa<128, true>(xc + 128 * NN, 512 * NN, sa4, xT, U, UT, AGGt, AGG, z, h, sq, idx,
                    M, WCV, Mb, wcvb, xTb, AGGtb, xhi, xlo, D, nbatch, stream);
  // conv4 (bf16 MFMA): h [B,256,N] -> z [B,256,N]
  transpose_bf16_kernel<<<dim3(NN / 32, 8, BB), 256, 0, stream>>>(h, 256 * NN, 256, NN, hTb);
  convert_bf16_kernel<<<(256 * 256 + 255) / 256, 256, 0, stream>>>(conv4_w, w4b, 256 * 256);
  mfma_gemm_lds_kernel<<<dim3(NN / 128, 2, BB), 256, 0, stream>>>(w4b, hTb, z, 256, 256);
  bn_fused_kernel<<<256, 256, 0, stream>>>(z, 256, xc, 512 * NN, 256);
  // conv5 (bf16 MFMA): xc [B,512,N] -> z [B,1024,N]; BN+LReLU+pool -> p
  transpose_bf16_kernel<<<dim3(NN / 32, 16, BB), 256, 0, stream>>>(xc, 512 * NN, 512, NN, xcTb);
  convert_bf16_kernel<<<(1024 * 512 + 255) / 256, 256, 0, stream>>>(conv5_w, w5b, 1024 * 512);
  mfma_gemm_lds_kernel<<<dim3(NN / 128, 8, BB), 256, 0, stream>>>(w5b, xcTb, z, 1024, 512);
  bn_pool_kernel<<<1024, 256, 0, stream>>>(z, p);
  // FC head
  linear_kernel<<<BB * 512, 64, 0, stream>>>(p, 2048, 512, lin1_w, lin1_b, t1);
  bnf_kernel<<<2, 256, 0, stream>>>(t1, 512);
  linear_kernel<<<BB * 256, 64, 0, stream>>>(t1, 512, 256, lin2_w, lin2_b, t2);
  bnf_kernel<<<1, 256, 0, stream>>>(t2, 256);
  linear_kernel<<<BB * 40, 64, 0, stream>>>(t2, 256, 40, lin3_w, lin3_b, (float*)d_out);
}